// Round 12
// baseline (2773.475 us; speedup 1.0000x reference)
//
#include <hip/hip_runtime.h>
#include <stdint.h>

// ---------- types / helpers ----------
typedef short s16x8 __attribute__((ext_vector_type(8)));
typedef short s16x4 __attribute__((ext_vector_type(4)));
typedef float f32x4 __attribute__((ext_vector_type(4)));
typedef unsigned short u16;
typedef unsigned int u32;

#define DEV __device__ __forceinline__

DEV float bf2f(u16 v){ union{float f; unsigned u;} x; x.u = ((unsigned)v)<<16; return x.f; }
DEV u16 f2bf(float f){ union{float f; unsigned u;} x; x.f = f; unsigned r = x.u + 0x7fffu + ((x.u>>16)&1u); return (u16)(r>>16); }
DEV float sigm(float x){ return 1.f/(1.f + __expf(-x)); }

// coherence-point (L2-bypassing) accessors: RELAXED atomics at agent scope
DEV u32  aL(const u32* p){ return __hip_atomic_load(p, __ATOMIC_RELAXED, __HIP_MEMORY_SCOPE_AGENT); }
DEV void aS(u32* p, u32 v){ __hip_atomic_store(p, v, __ATOMIC_RELAXED, __HIP_MEMORY_SCOPE_AGENT); }
DEV float aLf(const float* p){ return __hip_atomic_load(p, __ATOMIC_RELAXED, __HIP_MEMORY_SCOPE_AGENT); }
DEV void aSf(float* p, float v){ __hip_atomic_store(p, v, __ATOMIC_RELAXED, __HIP_MEMORY_SCOPE_AGENT); }

// B=64, P=196, D=2048, E=512, H=512, A=512, V=32000, S=22, T=20

enum { EPI_F32=0, EPI_BF16=1, EPI_H0C0=2, EPI_PREDS=3 };

struct EpiParams {
  float* out0; long ldo;
  u16* outb;
  const float* bias0;
  const int* declen;
  float* c; u16* xh;
};

// ---------- generic MFMA GEMM: C[M][N] = A[M][K](bf16) * B[N][K](bf16)^T ----------
template<int BM, int BN, int EPI, bool SWAPXY, int SWZM>
__global__ __launch_bounds__(256) void gemm_bt(
    const u16* __restrict__ A, long lda,
    const u16* __restrict__ B, long ldb,
    int K, EpiParams ep)
{
  constexpr int MF = BM/64;
  constexpr int NF = BN/16;
  constexpr int CHA = BM*8, CH = CHA + BN*8;
  constexpr int NST = CH/256;
  __shared__ char smem[(BM+BN)*128];
  const int tid = threadIdx.x;
  const int w = tid>>6, lane = tid&63;

  long arow0, brow0;
  if constexpr (SWZM > 0) {
    int id = blockIdx.x, tot = gridDim.x;
    int q = tot>>3, r = tot&7, xcd = id&7, idx = id>>3;
    int cid = (xcd<r) ? xcd*(q+1)+idx : r*(q+1)+(xcd-r)*q+idx;
    arow0 = (long)(cid % SWZM)*BM; brow0 = (long)(cid / SWZM)*BN;
  } else if constexpr (SWAPXY) { arow0 = (long)blockIdx.x*BM; brow0 = (long)blockIdx.y*BN; }
  else { arow0 = (long)blockIdx.y*BM; brow0 = (long)blockIdx.x*BN; }

  const u16* gsrc[NST]; int ldst[NST];
  #pragma unroll
  for (int i=0;i<NST;++i){
    int c = i*256 + tid;
    if (i*256 < CHA){
      int row = c>>3, k16 = c&7;
      gsrc[i] = A + (arow0+row)*lda + k16*8;
      ldst[i] = row*128 + ((k16*16) ^ ((row&7)<<4));
    } else {
      int cb = c - CHA; int row = cb>>3, k16 = cb&7;
      gsrc[i] = B + (brow0+row)*ldb + k16*8;
      ldst[i] = BM*128 + row*128 + ((k16*16) ^ ((row&7)<<4));
    }
  }

  f32x4 acc[MF][NF];
  #pragma unroll
  for (int i=0;i<MF;++i)
    #pragma unroll
    for (int j=0;j<NF;++j) acc[i][j] = (f32x4){0.f,0.f,0.f,0.f};

  const int KT = K >> 6;
  s16x8 st[NST];
  #pragma unroll
  for (int i=0;i<NST;++i) st[i] = *(const s16x8*)(gsrc[i]);

  char* Al = smem;
  for (int kk=0; kk<KT; ++kk){
    #pragma unroll
    for (int i=0;i<NST;++i) *(s16x8*)(smem + ldst[i]) = st[i];
    __syncthreads();
    if (kk+1 < KT){
      long kb = (long)(kk+1)*64;
      #pragma unroll
      for (int i=0;i<NST;++i) st[i] = *(const s16x8*)(gsrc[i] + kb);
    }
    #pragma unroll
    for (int ks = 0; ks < 2; ++ks) {
      s16x8 af[MF], bfr[NF];
      const int kboff = ks*64 + ((lane>>4)<<4);
      #pragma unroll
      for (int mf=0; mf<MF; ++mf) {
        int r = w*(16*MF) + mf*16 + (lane&15);
        af[mf] = *(const s16x8*)(Al + r*128 + (kboff ^ ((r&7)<<4)));
      }
      #pragma unroll
      for (int nf=0; nf<NF; ++nf) {
        int r = nf*16 + (lane&15);
        bfr[nf] = *(const s16x8*)(Al + BM*128 + r*128 + (kboff ^ ((r&7)<<4)));
      }
      #pragma unroll
      for (int mf=0; mf<MF; ++mf)
        #pragma unroll
        for (int nf=0; nf<NF; ++nf)
          acc[mf][nf] = __builtin_amdgcn_mfma_f32_16x16x32_bf16(bfr[nf], af[mf], acc[mf][nf], 0,0,0);
    }
    __syncthreads();
  }

  #pragma unroll
  for (int mf=0; mf<MF; ++mf)
    #pragma unroll
    for (int nf=0; nf<NF; ++nf){
      long m = arow0 + w*(16*MF) + mf*16 + (lane&15);
      long n0 = brow0 + nf*16 + ((lane>>4)<<2);
      f32x4 bv = *(const f32x4*)&ep.bias0[n0];
      f32x4 v = acc[mf][nf] + bv;
      if constexpr (EPI == EPI_F32) {
        *(f32x4*)&ep.out0[m*ep.ldo + n0] = v;
      } else if constexpr (EPI == EPI_BF16) {
        u16 o[4];
        #pragma unroll
        for (int r=0;r<4;++r) o[r] = f2bf(v[r]);
        *(s16x4*)&ep.outb[m*ep.ldo + n0] = *(s16x4*)o;
      } else if constexpr (EPI == EPI_H0C0) {
        if (n0 < 512){
          u16 o[4];
          #pragma unroll
          for (int r=0;r<4;++r) o[r] = f2bf(v[r]);
          *(s16x4*)&ep.xh[m*2560 + 2048 + n0] = *(s16x4*)o;
        } else {
          // c layout [j][64 b]
          #pragma unroll
          for (int r=0;r<4;++r) ep.c[(long)(n0-512+r)*64 + m] = v[r];
        }
      } else { // EPI_PREDS: skip masked rows entirely
        int tt = (int)(m>>6), b = (int)(m&63);
        if (ep.declen[b] > tt)
          *(f32x4*)&ep.out0[(long)b*640000 + (long)tt*32000 + n0] = v;
      }
    }
}

// ---------- fence-free grid barrier (256 blocks) ----------
DEV void gsync(u32* flags, u32* epochw, u32 ep, int blk, int tid){
  __syncthreads();
  if (blk == 0){
    if (tid == 0) aS(flags, ep);
    if (tid < 256){
      while (aL(flags + tid*16) < ep) __builtin_amdgcn_s_sleep(4);
    }
    __syncthreads();
    if (tid == 0) aS(epochw, ep);
  } else {
    if (tid == 0){
      aS(flags + blk*16, ep);
      while (aL(epochw) < ep) __builtin_amdgcn_s_sleep(8);
    }
    __syncthreads();
  }
}

// ---------- fused 20-step decoder loop (cooperative, 256 blocks x 512 thr) ----------
// 2 phases/step, 2 barriers/step.
// xh20: 21 per-step [64][2560] bf16 buffers; producers bypass-write, consumers
// cached-read (first-touch-per-step). part: [4][2048 n][64 b] f32 (coalesced).
// c: [512 j][64 b] f32 (bypass, reused addresses).
struct FusedArgs {
  const u16* att1; const u16* enc;
  const u32* wmt; const u16* wcat2;
  const float* gst; const float* wf; const float* bfp;
  const int* declen; const float* bmisc; const int* nact;
  u16* xh20;
  float* part; int* cnt; float* c; u16* hall;
  float* alph; u32* bar;
};

__global__ __launch_bounds__(512) void steps_fused(FusedArgs fa)
{
  __shared__ char smem[61440];
  __shared__ float wred[8];
  __shared__ int lastf;
  const int blk = blockIdx.x, tid = threadIdx.x;
  const int w = tid>>6, lane = tid&63;
  const int mstrip = w>>1, nhalf = w&1;
  u32* flags = fa.bar;
  u32* epochw = fa.bar + 4096;
  u32 ep = 0;

  for (int t=0; t<20; ++t){
    u16* cur = fa.xh20 + (long)t*163840;
    u16* nxt = cur + 163840;
    u32* cur32 = (u32*)cur;
    u32* nxt32 = (u32*)nxt;

    // ==== Phase A: GEMV(att2,gate) + scores + softmax + awe + gate*awe -> x ====
    {
      const int b = blk & 63, s = blk >> 6;
      const int na = fa.nact[t];
      if (b >= na){
        if (s == 0){
          for (int i=tid; i<196; i+=512)
            fa.alph[((long)b*20 + t)*196 + i] = 0.f;
        }
      } else {
      float* att2p = (float*)smem;           // 576
      float* wfp   = att2p + 576;            // 576
      float* alps  = wfp + 576;              // 208
      float* awe_p = alps + 208;             // 4096
      float* hs    = awe_p + 4096;           // 512
      float* garr  = hs + 512;               // 512
      if (tid < 256){
        u32 hp = *(const u32*)(cur32 + (long)b*1280 + 1024 + tid);   // cached
        hs[2*tid]   = bf2f((u16)(hp & 0xffffu));
        hs[2*tid+1] = bf2f((u16)(hp >> 16));
      }
      { int kg0 = tid>>6, j2 = tid&63; wfp[kg0*72 + j2] = fa.wf[tid]; }
      __syncthreads();
      // GEMV: att2 col tid, gate col s*512+tid (wmt: [256 kp][2560 n] u32 k-pairs)
      {
        float aacc = 0.f, gacc = 0.f;
        const u32* wa = fa.wmt + 2048 + tid;
        const u32* wg = fa.wmt + s*512 + tid;
        #pragma unroll 4
        for (int kp = 0; kp < 256; ++kp){
          u32 pa = wa[(long)kp*2560];
          u32 pg = wg[(long)kp*2560];
          float h0 = hs[2*kp], h1 = hs[2*kp+1];
          aacc += h0*bf2f((u16)(pa&0xffffu)) + h1*bf2f((u16)(pa>>16));
          gacc += h0*bf2f((u16)(pg&0xffffu)) + h1*bf2f((u16)(pg>>16));
        }
        att2p[(tid>>6)*72 + (tid&63)] = aacc + fa.bmisc[2048 + tid];
        garr[tid] = sigm(gacc + fa.bmisc[s*512 + tid]);
      }
      __syncthreads();
      const float bfv = fa.bfp[0];
      const int pg2 = lane>>3, kg = lane&7;
      #pragma unroll
      for (int pass=0; pass<4; ++pass){
        int p = pass*64 + w*8 + pg2;
        if (p < 196){
          const u16* ap = fa.att1 + (((long)(b*196 + p))<<9) + kg*64;
          float sa = 0.f;
          #pragma unroll
          for (int i=0;i<8;++i){
            s16x8 v = *(const s16x8*)(ap + i*8);
            #pragma unroll
            for (int q=0;q<8;++q){
              float x = bf2f((u16)v[q]) + att2p[kg*72 + i*8 + q];
              x = fmaxf(x, 0.f);
              sa += x * wfp[kg*72 + i*8 + q];
            }
          }
          sa += __shfl_xor(sa, 1);
          sa += __shfl_xor(sa, 2);
          sa += __shfl_xor(sa, 4);
          if (kg == 0) alps[p] = sa + bfv;
        }
      }
      __syncthreads();
      float v = (tid < 196) ? alps[tid] : -3.4e38f;
      float m8 = v;
      #pragma unroll
      for (int off=32; off; off>>=1) m8 = fmaxf(m8, __shfl_xor(m8, off));
      if (lane == 0) wred[w] = m8;
      __syncthreads();
      float mx = wred[0];
      #pragma unroll
      for (int i=1;i<8;++i) mx = fmaxf(mx, wred[i]);
      float e = (tid < 196) ? __expf(v - mx) : 0.f;
      float s8 = e;
      #pragma unroll
      for (int off=32; off; off>>=1) s8 += __shfl_xor(s8, off);
      __syncthreads();
      if (lane == 0) wred[w] = s8;
      __syncthreads();
      float den = wred[0]+wred[1]+wred[2]+wred[3]+wred[4]+wred[5]+wred[6]+wred[7];
      float inv = 1.f/den;
      if (tid < 196){
        float a = e*inv;
        alps[tid] = a;
        if (s==0) fa.alph[((long)b*20 + t)*196 + tid] = a;
      }
      __syncthreads();
      // awe: 4-deep pipelined, non-temporal enc loads
      const int d0 = s*512 + lane*8;
      const u16* ebase = fa.enc + (((long)b*196)<<11) + d0;
      float a8[8] = {0,0,0,0,0,0,0,0};
      int p = w;
      for (; p+24 < 196; p += 32){
        s16x8 e0 = __builtin_nontemporal_load((const s16x8*)(ebase + ((long)p<<11)));
        s16x8 e1 = __builtin_nontemporal_load((const s16x8*)(ebase + ((long)(p+8)<<11)));
        s16x8 e2 = __builtin_nontemporal_load((const s16x8*)(ebase + ((long)(p+16)<<11)));
        s16x8 e3 = __builtin_nontemporal_load((const s16x8*)(ebase + ((long)(p+24)<<11)));
        float a0 = alps[p], a1 = alps[p+8], a2 = alps[p+16], a3 = alps[p+24];
        #pragma unroll
        for (int q=0;q<8;++q) a8[q] += a0*bf2f((u16)e0[q]);
        #pragma unroll
        for (int q=0;q<8;++q) a8[q] += a1*bf2f((u16)e1[q]);
        #pragma unroll
        for (int q=0;q<8;++q) a8[q] += a2*bf2f((u16)e2[q]);
        #pragma unroll
        for (int q=0;q<8;++q) a8[q] += a3*bf2f((u16)e3[q]);
      }
      for (; p < 196; p += 8){
        s16x8 ev = __builtin_nontemporal_load((const s16x8*)(ebase + ((long)p<<11)));
        float a = alps[p];
        #pragma unroll
        for (int q=0;q<8;++q) a8[q] += a*bf2f((u16)ev[q]);
      }
      *(f32x4*)&awe_p[w*512 + lane*8]     = (f32x4){a8[0],a8[1],a8[2],a8[3]};
      *(f32x4*)&awe_p[w*512 + lane*8 + 4] = (f32x4){a8[4],a8[5],a8[6],a8[7]};
      __syncthreads();
      if (tid < 256){
        int c0 = 2*tid;
        float s0 = 0.f, s1 = 0.f;
        #pragma unroll
        for (int g=0; g<8; ++g){ s0 += awe_p[g*512 + c0]; s1 += awe_p[g*512 + c0 + 1]; }
        u32 pk = (u32)f2bf(garr[c0]*s0) | ((u32)f2bf(garr[c0+1]*s1) << 16);
        aS(cur32 + (long)b*1280 + s*256 + tid, pk);
      }
      __syncthreads();
      }
    }
    gsync(flags, epochw, ++ep, blk, tid);

    // ==== Phase B: gates = [x|h] @ wcat2^T (+gst), split-K 4, fused LSTM ====
    {
      const int ntile = blk & 63, split = blk >> 6;
      f32x4 acc = {0,0,0,0};
      #pragma unroll
      for (int r=0; r<2; ++r){
        const int kbw = split*640 + r*320;     // u16 col base
        const int kbd = split*320 + r*160;     // u32 col base
        u32 sa[20];
        #pragma unroll
        for (int i=0;i<20;++i){
          int c = i*512 + tid;
          int row = c/160, kp = c%160;
          sa[i] = *(const u32*)(cur32 + (long)row*1280 + kbd + kp);   // cached
        }
        s16x8 sb[3];
        #pragma unroll
        for (int i=0;i<3;++i){
          int c = i*512 + tid;
          if (c < 1280){
            int row = c/40, k16 = c%40;
            sb[i] = *(const s16x8*)(fa.wcat2 + (long)(ntile*32+row)*2560 + kbw + k16*8);
          }
        }
        #pragma unroll
        for (int i=0;i<20;++i){
          int c = i*512 + tid;
          int row = c/160, kp = c%160;
          *(u32*)(smem + row*640 + ((kp*4) ^ ((row&7)<<4))) = sa[i];
        }
        #pragma unroll
        for (int i=0;i<3;++i){
          int c = i*512 + tid;
          if (c < 1280){
            int row = c/40, k16 = c%40;
            *(s16x8*)(smem + 40960 + row*640 + ((k16*16) ^ ((row&7)<<4))) = sb[i];
          }
        }
        __syncthreads();
        #pragma unroll
        for (int ks=0; ks<10; ++ks){
          int kboff = ks*64 + ((lane>>4)<<4);
          int ra = mstrip*16 + (lane&15);
          s16x8 af = *(const s16x8*)(smem + ra*640 + (kboff ^ ((ra&7)<<4)));
          int rb = nhalf*16 + (lane&15);
          s16x8 bf = *(const s16x8*)(smem + 40960 + rb*640 + (kboff ^ ((rb&7)<<4)));
          acc = __builtin_amdgcn_mfma_f32_16x16x32_bf16(bf, af, acc, 0,0,0);
        }
        __syncthreads();
      }
      {
        // part[split][2048 n][64 b]; lanes 0-15 -> consecutive m (coalesced)
        float* PS = fa.part + (long)split*131072;
        int m = mstrip*16 + (lane&15);
        int nl = ntile*32 + nhalf*16 + ((lane>>4)<<2);
        #pragma unroll
        for (int j=0;j<4;++j) aSf(PS + (long)(nl + j)*64 + m, acc[j]);
      }
      __syncthreads();   // drains vmcnt per wave -> part stores globally visible
      if (tid==0){
        int v = __hip_atomic_fetch_add(fa.cnt + t*64 + ntile, 1,
                                       __ATOMIC_RELAXED, __HIP_MEMORY_SCOPE_AGENT);
        lastf = (v == 3);
      }
      __syncthreads();
      if (lastf && tid < 256){
        int b2 = tid & 63, jpair = tid >> 6;   // b-major: coalesced part/c access
        u16 h2[2];
        #pragma unroll
        for (int jj=0; jj<2; ++jj){
          int jl = jpair*2 + jj;
          int j = ntile*8 + jl;
          float g4[4];
          #pragma unroll
          for (int gi=0; gi<4; ++gi){
            int nl = ntile*32 + jl*4 + gi;
            float sg = fa.gst[((long)t*64 + b2)*2048 + nl];
            #pragma unroll
            for (int sp=0; sp<4; ++sp)
              sg += aLf(fa.part + (long)sp*131072 + (long)nl*64 + b2);
            g4[gi] = sg;
          }
          float cc = aLf(fa.c + (long)j*64 + b2);
          float cn = sigm(g4[1])*cc + sigm(g4[0])*tanhf(g4[2]);
          float hn = sigm(g4[3])*tanhf(cn);
          aSf(fa.c + (long)j*64 + b2, cn);
          h2[jj] = f2bf(hn);
        }
        u32 pk = (u32)h2[0] | ((u32)h2[1] << 16);
        aS(nxt32 + (long)b2*1280 + 1024 + ntile*4 + jpair, pk);
        *(u32*)&fa.hall[((long)t*64 + b2)*512 + ntile*8 + jpair*2] = pk;
      }
    }
    if (t < 19) gsync(flags, epochw, ++ep, blk, tid);
  }
}

// ---------- transpose f32[R][C] -> bf16[C][R] ----------
__global__ __launch_bounds__(256) void transpose_bf16(
    const float* __restrict__ in, u16* __restrict__ out, int R, int C)
{
  __shared__ float t[64][65];
  const int bx = blockIdx.x*64, by = blockIdx.y*64;
  const int tx = threadIdx.x & 63, ty = threadIdx.x >> 6;
  #pragma unroll
  for (int i=0;i<16;++i){ int r = i*4+ty; t[r][tx] = in[(long)(by+r)*C + bx+tx]; }
  __syncthreads();
  #pragma unroll
  for (int i=0;i<16;++i){ int cc = i*4+ty; out[(long)(bx+cc)*R + by+tx] = f2bf(t[tx][cc]); }
}

// ---------- sort + small outputs + counter/barrier/nact init ----------
__global__ void sort_k(const int* __restrict__ cl, const int* __restrict__ captions,
                       int* __restrict__ sidx, int* __restrict__ declen,
                       float* __restrict__ outCaps, float* __restrict__ outLens,
                       float* __restrict__ outSidx, int* __restrict__ cnt,
                       u32* __restrict__ bar, int* __restrict__ nact)
{
  __shared__ int s_idx[64];
  __shared__ int s_dl[64];
  int i = threadIdx.x;
  int li = cl[i];
  int rank = 0;
  for (int j=0;j<64;++j){ int lj = cl[j]; rank += (lj>li) || (lj==li && j<i); }
  s_idx[rank] = i;
  __syncthreads();
  int src = s_idx[i];
  sidx[i] = src;
  int L = cl[src];
  declen[i] = L - 1;
  s_dl[i] = L - 1;
  outLens[i] = (float)L;
  outSidx[i] = (float)src;
  for (int s=0;s<22;++s) outCaps[i*22+s] = (float)captions[s*64 + src];
  for (int s=0;s<20;++s) cnt[s*64 + i] = 0;
  for (int s=i; s<4160; s+=64) bar[s] = 0u;
  __syncthreads();
  if (i < 20){
    int c = 0;
    for (int j=0;j<64;++j) c += (s_dl[j] > i);
    nact[i] = c;
  }
}

// ---------- gather sorted enc -> bf16 + mean (512 blocks) ----------
__global__ __launch_bounds__(256) void prep_enc(
    const float* __restrict__ features, const int* __restrict__ sidx,
    u16* __restrict__ enc, u16* __restrict__ meanb)
{
  __shared__ float red[4][256];
  int b = blockIdx.x >> 3, oct = blockIdx.x & 7;
  int lv = threadIdx.x & 63, g = threadIdx.x >> 6;
  int d0 = oct*256 + lv*4;
  const float* src = features + (long)sidx[b]*(196*2048) + d0;
  float acc[4] = {0.f,0.f,0.f,0.f};
  for (int p=g; p<196; p+=4){
    f32x4 v = *(const f32x4*)(src + (long)p*2048);
    u16 o[4];
    #pragma unroll
    for (int q=0;q<4;++q){ acc[q] += v[q]; o[q] = f2bf(v[q]); }
    *(s16x4*)(enc + ((long)b*196 + p)*2048 + d0) = *(s16x4*)o;
  }
  #pragma unroll
  for (int q=0;q<4;++q) red[g][lv*4+q] = acc[q];
  __syncthreads();
  if (threadIdx.x < 64){
    u16 mo[4];
    #pragma unroll
    for (int q=0;q<4;++q){
      float s = red[0][threadIdx.x*4+q] + red[1][threadIdx.x*4+q]
              + red[2][threadIdx.x*4+q] + red[3][threadIdx.x*4+q];
      mo[q] = f2bf(s*(1.f/196.f));
    }
    *(s16x4*)(meanb + b*2048 + oct*256 + threadIdx.x*4) = *(s16x4*)mo;
  }
}

// ---------- gather embeddings for t<20 -> bf16 [t*64+b][512] ----------
__global__ void emb_gather(const int* __restrict__ captions, const int* __restrict__ sidx,
                           const float* __restrict__ embW, u16* __restrict__ out)
{
  int idx = blockIdx.x*256 + threadIdx.x;      // 1280*64
  int row = idx >> 6; int e0 = (idx & 63)*8;
  int t = row >> 6, b = row & 63;
  int tok = captions[t*64 + sidx[b]];
  const float* s = embW + (long)tok*512 + e0;
  f32x4 v0 = *(const f32x4*)s, v1 = *(const f32x4*)(s+4);
  u16 o[8];
  #pragma unroll
  for (int q=0;q<4;++q){ o[q] = f2bf(v0[q]); o[4+q] = f2bf(v1[q]); }
  *(s16x8*)(out + (long)row*512 + e0) = *(s16x8*)o;
}

// ---------- weight packers ----------
__global__ void build_wcat2(const float* __restrict__ Wih, const float* __restrict__ Whh,
                            u16* __restrict__ out)
{
  long idx = (long)blockIdx.x*256 + threadIdx.x;   // 2048*320
  int r = (int)(idx / 320);
  int kc = (int)(idx % 320) * 8;
  int j = r>>2, g = r&3;
  int orow = g*512 + j;
  const float* s = (kc < 2048) ? (Wih + (long)orow*2560 + 512 + kc)
                               : (Whh + (long)orow*512 + (kc - 2048));
  f32x4 v0 = *(const f32x4*)s, v1 = *(const f32x4*)(s+4);
  u16 o[8];
  #pragma unroll
  for (int q=0;q<4;++q){ o[q] = f2bf(v0[q]); o[4+q] = f2bf(v1[q]); }
  *(s16x8*)(out + (long)r*2560 + kc) = *(s16x8*)o;
}

// wmt[kp][n] u32 = pack(W[2kp][n], W[2kp+1][n]); W = [Wbeta | Wd] k-major
__global__ void build_wmt(const float* __restrict__ Wbeta, const float* __restrict__ Wd,
                          u32* __restrict__ out)
{
  long idx = (long)blockIdx.x*256 + threadIdx.x;   // 256*2560 -> 2560 blocks
  int kp = (int)(idx / 2560), n = (int)(idx % 2560);
  float v0, v1;
  if (n < 2048){
    v0 = Wbeta[(long)(2*kp)*2048 + n];
    v1 = Wbeta[(long)(2*kp+1)*2048 + n];
  } else {
    v0 = Wd[(long)(2*kp)*512 + (n-2048)];
    v1 = Wd[(long)(2*kp+1)*512 + (n-2048)];
  }
  out[idx] = (u32)f2bf(v0) | ((u32)f2bf(v1) << 16);
}

__global__ void build_wihe(const float* __restrict__ Wih, u16* __restrict__ out)
{
  int idx = blockIdx.x*256 + threadIdx.x;          // 2048*64
  int r = idx >> 6; int kc = (idx & 63)*8;
  int j = r>>2, g = r&3;
  const float* s = Wih + (long)(g*512+j)*2560 + kc;
  f32x4 v0 = *(const f32x4*)s, v1 = *(const f32x4*)(s+4);
  u16 o[8];
  #pragma unroll
  for (int q=0;q<4;++q){ o[q] = f2bf(v0[q]); o[4+q] = f2bf(v1[q]); }
  *(s16x8*)(out + (long)r*512 + kc) = *(s16x8*)o;
}

__global__ void build_bias(const float* bih, const float* bhh, const float* bbeta,
                           const float* bd, const float* bh0, const float* bc0,
                           float* bstat, float* bmisc, float* bhc)
{
  int idx = blockIdx.x*256 + threadIdx.x;
  if (idx < 2048){ int j = idx>>2, g = idx&3; bstat[idx] = bih[g*512+j] + bhh[g*512+j]; }
  else if (idx < 4608){ int k = idx-2048; bmisc[k] = (k<2048) ? bbeta[k] : bd[k-2048]; }
  else if (idx < 5632){ int k = idx-4608; bhc[k] = (k<512) ? bh0[k] : bc0[k-512]; }
}

// ---------- workspace layout (bytes) ----------
static constexpr long OFF_ENC   = 0;                 // 64*196*2048 bf16
static constexpr long OFF_ATT1  = 51380224;          // 12544*512 bf16
static constexpr long OFF_WOUTT = 64225280;          // 32000*512 bf16
static constexpr long OFF_WET   = 96993280;          // 512*2048 bf16
static constexpr long OFF_WMT   = 99090432;          // 256*2560 u32 (2.62 MB)
static constexpr long OFF_WHC   = 101711872;         // 1024*2048 bf16 -- REUSED as PART
static constexpr long OFF_WCAT2 = 105906176;         // 2048*2560 bf16 (perm [Wih_a|Whh])
static constexpr long OFF_WIHE  = 116391936;         // 2048*512 bf16 (perm Wih_e)
static constexpr long OFF_EMBB  = 118489088;         // 1280*512 bf16
static constexpr long OFF_GST   = 119799808;         // 1280*2048 f32
static constexpr long OFF_HALL  = 130285568;         // 1280*512 bf16
static constexpr long OFF_MEANB = 131596288;         // 64*2048 bf16
static constexpr long OFF_C     = 132513792;         // 512*64 f32 ([j][b])
static constexpr long OFF_BSTAT = 133955584;         // 2048 f32
static constexpr long OFF_BMISC = 133963776;         // 2560 f32
static constexpr long OFF_BHC   = 133974016;         // 1024 f32
static constexpr long OFF_SIDX  = 133978112;         // 64 int
static constexpr long OFF_DECL  = 133978368;         // 64 int
static constexpr long OFF_CNT   = 133978624;         // 20*64 int
static constexpr long OFF_BAR   = 133983744;         // 4160 u32
static constexpr long OFF_NACT  = 134000384;         // 20 int
static constexpr long OFF_XH20  = 134017024;         // 21 * 64*2560 bf16 (6.88 MB)
static constexpr long OFF_PART  = OFF_WHC;           // 4*2048*64 f32 (2 MB, after setup)

extern "C" void kernel_launch(void* const* d_in, const int* in_sizes, int n_in,
                              void* d_out, int out_size, void* d_ws, size_t ws_size,
                              hipStream_t stream)
{
  (void)in_sizes; (void)n_in; (void)out_size; (void)ws_size;
  const float* features = (const float*)d_in[0];
  const int*   captions = (const int*)d_in[1];
  const int*   caplen   = (const int*)d_in[2];
  const float* embW     = (const float*)d_in[3];
  const float* We       = (const float*)d_in[4];
  const float* be       = (const float*)d_in[5];
  const float* Wd       = (const float*)d_in[6];
  const float* bd       = (const float*)d_in[7];
  const float* wf       = (const float*)d_in[8];
  const float* bfp      = (const float*)d_in[9];
  const float* Wih      = (const float*)d_in[10];
  const float* Whh      = (const float*)d_in[11];
  const float* bih      = (const float*)d_in[12];
  const float* bhh      = (const float*)d_in[13];
  const float* Wh0      = (const float*)d_in[14];
  const float* bh0      = (const float*)d_in[15];
  const float* Wc0      = (const float*)d_in[16];
  const float* bc0      = (const float*)d_in[17];
  const float* Wbeta    = (const float*)d_in[18];
  const float* bbeta    = (const float*)d_in[19];
  const float* Wout     = (const float*)d_in[20];
  const float* bout     = (const float*)d_in[21];

  char* ws = (char*)d_ws;
  u16*   enc   = (u16*)(ws + OFF_ENC);
  u16*   att1  = (u16*)(ws + OFF_ATT1);
  u16*   woutt = (u16*)(ws + OFF_WOUTT);
  u16*   wet   = (u16*)(ws + OFF_WET);
  u32*   wmt   = (u32*)(ws + OFF_WMT);
  u16*   whc   = (u16*)(ws + OFF_WHC);
  u16*   wcat2 = (u16*)(ws + OFF_WCAT2);
  u16*   wihe  = (u16*)(ws + OFF_WIHE);
  u16*   embb  = (u16*)(ws + OFF_EMBB);
  float* gst   = (float*)(ws + OFF_GST);
  u16*   hall  = (u16*)(ws + OFF_HALL);
  u16*   meanb = (u16*)(ws + OFF_MEANB);
  float* cbuf  = (float*)(ws + OFF_C);
  float* bstat = (float*)(ws + OFF_BSTAT);
  float* bmisc = (float*)(ws + OFF_BMISC);
  float* bhc   = (float*)(ws + OFF_BHC);
  int*   sidx  = (int*)(ws + OFF_SIDX);
  int*   declen= (int*)(ws + OFF_DECL);
  int*   cnt   = (int*)(ws + OFF_CNT);
  u32*   bar   = (u32*)(ws + OFF_BAR);
  int*   nact  = (int*)(ws + OFF_NACT);
  u16*   xh20  = (u16*)(ws + OFF_XH20);
  float* part  = (float*)(ws + OFF_PART);

  float* outP    = (float*)d_out;            // [64][20][32000]
  float* outCaps = outP + 40960000;          // [64][22]
  float* outLens = outCaps + 1408;           // [64]
  float* outAlph = outLens + 64;             // [64][20][196]
  float* outSidx = outAlph + 250880;         // [64]

  // ---- setup ----
  sort_k<<<1,64,0,stream>>>(caplen, captions, sidx, declen, outCaps, outLens, outSidx, cnt, bar, nact);
  prep_enc<<<512,256,0,stream>>>(features, sidx, enc, meanb);
  emb_gather<<<320,256,0,stream>>>(captions, sidx, embW, embb);
  transpose_bf16<<<dim3(8,32),256,0,stream>>>(We,  wet, 2048, 512);
  transpose_bf16<<<dim3(8,32),256,0,stream>>>(Wh0, whc, 2048, 512);
  transpose_bf16<<<dim3(8,32),256,0,stream>>>(Wc0, whc + 512*2048, 2048, 512);
  transpose_bf16<<<dim3(500,8),256,0,stream>>>(Wout, woutt, 512, 32000);
  build_wcat2<<<2560,256,0,stream>>>(Wih, Whh, wcat2);
  build_wmt<<<2560,256,0,stream>>>(Wbeta, Wd, wmt);
  build_wihe<<<512,256,0,stream>>>(Wih, wihe);
  build_bias<<<22,256,0,stream>>>(bih,bhh,bbeta,bd,bh0,bc0,bstat,bmisc,bhc);

  // h0/c0 : mean @ [Wh0|Wc0] -> xh20[0] h-half + c[j][b]
  { EpiParams ep{}; ep.bias0 = bhc; ep.xh = xh20; ep.c = cbuf;
    gemm_bt<64,64,EPI_H0C0,false,0><<<dim3(16,1),256,0,stream>>>(meanb, 2048, whc, 2048, 2048, ep); }
  // att1 = enc @ We + be  (bf16 out)
  { EpiParams ep{}; ep.outb = att1; ep.ldo = 512; ep.bias0 = be;
    gemm_bt<128,128,EPI_BF16,true,0><<<dim3(98,4),256,0,stream>>>(enc, 2048, wet, 2048, 2048, ep); }
  // g_static = emb @ Wih_e^T + bih + bhh (permuted cols)
  { EpiParams ep{}; ep.out0 = gst; ep.ldo = 2048; ep.bias0 = bstat;
    gemm_bt<128,64,EPI_F32,false,0><<<dim3(32,10),256,0,stream>>>(embb, 512, wihe, 512, 512, ep); }

  // ---- 20 fused sequential steps (cooperative, 256 blocks x 512 thr) ----
  {
    FusedArgs fa;
    fa.att1 = att1; fa.enc = enc; fa.wmt = wmt; fa.wcat2 = wcat2;
    fa.gst = gst; fa.wf = wf; fa.bfp = bfp; fa.declen = declen; fa.bmisc = bmisc;
    fa.nact = nact;
    fa.xh20 = xh20;
    fa.part = part; fa.cnt = cnt; fa.c = cbuf; fa.hall = hall;
    fa.alph = outAlph; fa.bar = bar;
    void* kargs[1] = { &fa };
    hipLaunchCooperativeKernel((const void*)steps_fused, dim3(256), dim3(512),
                               kargs, 0, stream);
  }

  // ---- batched predictions: h_all @ Wout + bout, masked rows skipped ----
  { EpiParams ep{}; ep.out0 = outP; ep.bias0 = bout; ep.declen = declen;
    gemm_bt<128,128,EPI_PREDS,false,10><<<2500,256,0,stream>>>(hall, 512, woutt, 512, 512, ep); }
}

// Round 13
// 1589.824 us; speedup vs baseline: 1.7445x; 1.7445x over previous
//
#include <hip/hip_runtime.h>
#include <stdint.h>

// ---------- types / helpers ----------
typedef short s16x8 __attribute__((ext_vector_type(8)));
typedef short s16x4 __attribute__((ext_vector_type(4)));
typedef float f32x4 __attribute__((ext_vector_type(4)));
typedef unsigned short u16;
typedef unsigned int u32;

#define DEV __device__ __forceinline__

DEV float bf2f(u16 v){ union{float f; unsigned u;} x; x.u = ((unsigned)v)<<16; return x.f; }
DEV u16 f2bf(float f){ union{float f; unsigned u;} x; x.f = f; unsigned r = x.u + 0x7fffu + ((x.u>>16)&1u); return (u16)(r>>16); }
DEV float sigm(float x){ return 1.f/(1.f + __expf(-x)); }

// coherence-point (L2-bypassing) accessors: RELAXED atomics at agent scope
DEV u32  aL(const u32* p){ return __hip_atomic_load(p, __ATOMIC_RELAXED, __HIP_MEMORY_SCOPE_AGENT); }
DEV void aS(u32* p, u32 v){ __hip_atomic_store(p, v, __ATOMIC_RELAXED, __HIP_MEMORY_SCOPE_AGENT); }
DEV float aLf(const float* p){ return __hip_atomic_load(p, __ATOMIC_RELAXED, __HIP_MEMORY_SCOPE_AGENT); }
DEV void aSf(float* p, float v){ __hip_atomic_store(p, v, __ATOMIC_RELAXED, __HIP_MEMORY_SCOPE_AGENT); }

// B=64, P=196, D=2048, E=512, H=512, A=512, V=32000, S=22, T=20

enum { EPI_F32=0, EPI_BF16=1, EPI_H0C0=2, EPI_PREDS=3 };

struct EpiParams {
  float* out0; long ldo;
  u16* outb;
  const float* bias0;
  const int* declen;
  float* c; u16* xh;
};

// ---------- generic MFMA GEMM: C[M][N] = A[M][K](bf16) * B[N][K](bf16)^T ----------
template<int BM, int BN, int EPI, bool SWAPXY, int SWZM>
__global__ __launch_bounds__(256) void gemm_bt(
    const u16* __restrict__ A, long lda,
    const u16* __restrict__ B, long ldb,
    int K, EpiParams ep)
{
  constexpr int MF = BM/64;
  constexpr int NF = BN/16;
  constexpr int CHA = BM*8, CH = CHA + BN*8;
  constexpr int NST = CH/256;
  __shared__ char smem[(BM+BN)*128];
  const int tid = threadIdx.x;
  const int w = tid>>6, lane = tid&63;

  long arow0, brow0;
  if constexpr (SWZM > 0) {
    int id = blockIdx.x, tot = gridDim.x;
    int q = tot>>3, r = tot&7, xcd = id&7, idx = id>>3;
    int cid = (xcd<r) ? xcd*(q+1)+idx : r*(q+1)+(xcd-r)*q+idx;
    arow0 = (long)(cid % SWZM)*BM; brow0 = (long)(cid / SWZM)*BN;
  } else if constexpr (SWAPXY) { arow0 = (long)blockIdx.x*BM; brow0 = (long)blockIdx.y*BN; }
  else { arow0 = (long)blockIdx.y*BM; brow0 = (long)blockIdx.x*BN; }

  const u16* gsrc[NST]; int ldst[NST];
  #pragma unroll
  for (int i=0;i<NST;++i){
    int c = i*256 + tid;
    if (i*256 < CHA){
      int row = c>>3, k16 = c&7;
      gsrc[i] = A + (arow0+row)*lda + k16*8;
      ldst[i] = row*128 + ((k16*16) ^ ((row&7)<<4));
    } else {
      int cb = c - CHA; int row = cb>>3, k16 = cb&7;
      gsrc[i] = B + (brow0+row)*ldb + k16*8;
      ldst[i] = BM*128 + row*128 + ((k16*16) ^ ((row&7)<<4));
    }
  }

  f32x4 acc[MF][NF];
  #pragma unroll
  for (int i=0;i<MF;++i)
    #pragma unroll
    for (int j=0;j<NF;++j) acc[i][j] = (f32x4){0.f,0.f,0.f,0.f};

  const int KT = K >> 6;
  s16x8 st[NST];
  #pragma unroll
  for (int i=0;i<NST;++i) st[i] = *(const s16x8*)(gsrc[i]);

  char* Al = smem;
  for (int kk=0; kk<KT; ++kk){
    #pragma unroll
    for (int i=0;i<NST;++i) *(s16x8*)(smem + ldst[i]) = st[i];
    __syncthreads();
    if (kk+1 < KT){
      long kb = (long)(kk+1)*64;
      #pragma unroll
      for (int i=0;i<NST;++i) st[i] = *(const s16x8*)(gsrc[i] + kb);
    }
    #pragma unroll
    for (int ks = 0; ks < 2; ++ks) {
      s16x8 af[MF], bfr[NF];
      const int kboff = ks*64 + ((lane>>4)<<4);
      #pragma unroll
      for (int mf=0; mf<MF; ++mf) {
        int r = w*(16*MF) + mf*16 + (lane&15);
        af[mf] = *(const s16x8*)(Al + r*128 + (kboff ^ ((r&7)<<4)));
      }
      #pragma unroll
      for (int nf=0; nf<NF; ++nf) {
        int r = nf*16 + (lane&15);
        bfr[nf] = *(const s16x8*)(Al + BM*128 + r*128 + (kboff ^ ((r&7)<<4)));
      }
      #pragma unroll
      for (int mf=0; mf<MF; ++mf)
        #pragma unroll
        for (int nf=0; nf<NF; ++nf)
          acc[mf][nf] = __builtin_amdgcn_mfma_f32_16x16x32_bf16(bfr[nf], af[mf], acc[mf][nf], 0,0,0);
    }
    __syncthreads();
  }

  #pragma unroll
  for (int mf=0; mf<MF; ++mf)
    #pragma unroll
    for (int nf=0; nf<NF; ++nf){
      long m = arow0 + w*(16*MF) + mf*16 + (lane&15);
      long n0 = brow0 + nf*16 + ((lane>>4)<<2);
      f32x4 bv = *(const f32x4*)&ep.bias0[n0];
      f32x4 v = acc[mf][nf] + bv;
      if constexpr (EPI == EPI_F32) {
        *(f32x4*)&ep.out0[m*ep.ldo + n0] = v;
      } else if constexpr (EPI == EPI_BF16) {
        u16 o[4];
        #pragma unroll
        for (int r=0;r<4;++r) o[r] = f2bf(v[r]);
        *(s16x4*)&ep.outb[m*ep.ldo + n0] = *(s16x4*)o;
      } else if constexpr (EPI == EPI_H0C0) {
        if (n0 < 512){
          u16 o[4];
          #pragma unroll
          for (int r=0;r<4;++r) o[r] = f2bf(v[r]);
          *(s16x4*)&ep.xh[m*2560 + 2048 + n0] = *(s16x4*)o;
        } else {
          *(f32x4*)&ep.c[m*512 + (n0-512)] = v;
        }
      } else { // EPI_PREDS: skip masked rows entirely
        int tt = (int)(m>>6), b = (int)(m&63);
        if (ep.declen[b] > tt)
          *(f32x4*)&ep.out0[(long)b*640000 + (long)tt*32000 + n0] = v;
      }
    }
}

// ---------- fence-free grid barrier (256 blocks) ----------
DEV void gsync(u32* flags, u32* epochw, u32 ep, int blk, int tid){
  __syncthreads();
  if (blk == 0){
    if (tid == 0) aS(flags, ep);
    if (tid < 256){
      while (aL(flags + tid*16) < ep) __builtin_amdgcn_s_sleep(4);
    }
    __syncthreads();
    if (tid == 0) aS(epochw, ep);
  } else {
    if (tid == 0){
      aS(flags + blk*16, ep);
      while (aL(epochw) < ep) __builtin_amdgcn_s_sleep(8);
    }
    __syncthreads();
  }
}

// ---------- fused 20-step decoder loop (cooperative, 256 blocks x 512 thr) ----------
// xh20: 21 per-step dedicated [64][2560] bf16 buffers. Producers bypass-write,
// consumers CACHED-read (first-touch-per-step addresses -> no stale L2/L1 lines).
struct FusedArgs {
  const u16* att1; const u16* enc;
  const u16* wmisc; const u16* wcat2;
  const float* gst; const float* wf; const float* bfp;
  const int* declen; const float* bmisc; const int* nact;
  u16* xh20; float* y0p;
  float* part; int* cnt; float* c; u16* hall;
  float* alph; u32* bar;
};

__global__ __launch_bounds__(512) void steps_fused(FusedArgs fa)
{
  __shared__ char smem[61440];
  __shared__ float wred[8];
  __shared__ int lastf;
  const int blk = blockIdx.x, tid = threadIdx.x;
  const int w = tid>>6, lane = tid&63;
  const int mstrip = w>>1, nhalf = w&1;
  u32* flags = fa.bar;
  u32* epochw = fa.bar + 4096;
  u32 ep = 0;

  for (int t=0; t<20; ++t){
    u16* cur = fa.xh20 + (long)t*163840;
    u16* nxt = cur + 163840;
    u32* cur32 = (u32*)cur;
    u32* nxt32 = (u32*)nxt;

    // ---- P1: y0 = h @ [Wbeta^T|Wd^T] : 80 blocks, 64x32 tile, K=512 (2 rounds) ----
    if (blk < 80){
      const int brow0 = blk*32;
      f32x4 acc = {0,0,0,0};
      #pragma unroll
      for (int r=0; r<2; ++r){
        u32 sa[16];
        #pragma unroll
        for (int i=0;i<16;++i){
          int c = i*512 + tid;
          int row = c>>7, kp = c&127;
          sa[i] = *(const u32*)(cur32 + (long)row*1280 + 1024 + r*128 + kp);  // cached
        }
        s16x8 sb[2];
        #pragma unroll
        for (int i=0;i<2;++i){
          int c = i*512 + tid;
          int row = c>>5, k16 = c&31;
          sb[i] = *(const s16x8*)(fa.wmisc + (long)(brow0+row)*512 + r*256 + k16*8);
        }
        #pragma unroll
        for (int i=0;i<16;++i){
          int c = i*512 + tid;
          int row = c>>7, kp = c&127;
          *(u32*)(smem + row*512 + ((kp*4) ^ ((row&7)<<4))) = sa[i];
        }
        #pragma unroll
        for (int i=0;i<2;++i){
          int c = i*512 + tid;
          int row = c>>5, k16 = c&31;
          *(s16x8*)(smem + 32768 + row*512 + ((k16*16) ^ ((row&7)<<4))) = sb[i];
        }
        __syncthreads();
        #pragma unroll
        for (int ks=0; ks<8; ++ks){
          int kboff = ks*64 + ((lane>>4)<<4);
          int ra = mstrip*16 + (lane&15);
          s16x8 af = *(const s16x8*)(smem + ra*512 + (kboff ^ ((ra&7)<<4)));
          int rb = nhalf*16 + (lane&15);
          s16x8 bf = *(const s16x8*)(smem + 32768 + rb*512 + (kboff ^ ((rb&7)<<4)));
          acc = __builtin_amdgcn_mfma_f32_16x16x32_bf16(bf, af, acc, 0,0,0);
        }
        __syncthreads();
      }
      int m = mstrip*16 + (lane&15);
      int n0 = brow0 + nhalf*16 + ((lane>>4)<<2);
      #pragma unroll
      for (int j=0;j<4;++j)
        aSf(fa.y0p + (long)m*2560 + n0 + j, acc[j] + fa.bmisc[n0+j]);
    }
    gsync(flags, epochw, ++ep, blk, tid);

    // ---- P23: b = blk&63 (XCD-consistent), s = blk>>6 ; pruned by nact[t] ----
    {
      const int b = blk & 63, s = blk >> 6;
      const int na = fa.nact[t];
      if (b >= na){
        if (s == 0){
          for (int i=tid; i<196; i+=512)
            fa.alph[((long)b*20 + t)*196 + i] = 0.f;
        }
      } else {
      float* att2p = (float*)smem;           // 8*72
      float* wfp   = att2p + 576;            // 8*72
      float* alps  = wfp + 576;              // 208
      float* awe_p = alps + 208;             // 8*512
      {
        int kg0 = tid>>6, j = tid&63;
        att2p[kg0*72 + j] = aLf(fa.y0p + (long)b*2560 + 2048 + tid);
        wfp[kg0*72 + j]   = fa.wf[tid];
      }
      __syncthreads();
      const float bfv = fa.bfp[0];
      const int pg = lane>>3, kg = lane&7;
      #pragma unroll
      for (int pass=0; pass<4; ++pass){
        int p = pass*64 + w*8 + pg;
        if (p < 196){
          const u16* ap = fa.att1 + (((long)(b*196 + p))<<9) + kg*64;
          float sa = 0.f;
          #pragma unroll
          for (int i=0;i<8;++i){
            s16x8 v = *(const s16x8*)(ap + i*8);
            #pragma unroll
            for (int q=0;q<8;++q){
              float x = bf2f((u16)v[q]) + att2p[kg*72 + i*8 + q];
              x = fmaxf(x, 0.f);
              sa += x * wfp[kg*72 + i*8 + q];
            }
          }
          sa += __shfl_xor(sa, 1);
          sa += __shfl_xor(sa, 2);
          sa += __shfl_xor(sa, 4);
          if (kg == 0) alps[p] = sa + bfv;
        }
      }
      __syncthreads();
      float v = (tid < 196) ? alps[tid] : -3.4e38f;
      float m8 = v;
      #pragma unroll
      for (int off=32; off; off>>=1) m8 = fmaxf(m8, __shfl_xor(m8, off));
      if (lane == 0) wred[w] = m8;
      __syncthreads();
      float mx = wred[0];
      #pragma unroll
      for (int i=1;i<8;++i) mx = fmaxf(mx, wred[i]);
      float e = (tid < 196) ? __expf(v - mx) : 0.f;
      float s8 = e;
      #pragma unroll
      for (int off=32; off; off>>=1) s8 += __shfl_xor(s8, off);
      __syncthreads();
      if (lane == 0) wred[w] = s8;
      __syncthreads();
      float den = wred[0]+wred[1]+wred[2]+wred[3]+wred[4]+wred[5]+wred[6]+wred[7];
      float inv = 1.f/den;
      if (tid < 196){
        float a = e*inv;
        alps[tid] = a;
        if (s==0) fa.alph[((long)b*20 + t)*196 + tid] = (fa.declen[b] > t) ? a : 0.f;
      }
      __syncthreads();
      // awe: software-pipelined NT loads, two named 8-register groups (~16 in flight)
      const int d0 = s*512 + lane*8;
      const u16* ebase = fa.enc + (((long)b*196)<<11) + d0;
      float a8[8] = {0,0,0,0,0,0,0,0};
#define ELD(PP) __builtin_nontemporal_load((const s16x8*)(ebase + ((long)(PP)<<11)))
#define ACC8(REG, PP) do { float aa_ = alps[PP]; \
  a8[0]+=aa_*bf2f((u16)REG[0]); a8[1]+=aa_*bf2f((u16)REG[1]); \
  a8[2]+=aa_*bf2f((u16)REG[2]); a8[3]+=aa_*bf2f((u16)REG[3]); \
  a8[4]+=aa_*bf2f((u16)REG[4]); a8[5]+=aa_*bf2f((u16)REG[5]); \
  a8[6]+=aa_*bf2f((u16)REG[6]); a8[7]+=aa_*bf2f((u16)REG[7]); } while(0)
      {
        // p-values for wave w: w + 8k, k=0..23 (+k=24 iff w<4: 192+w <196)
        s16x8 c0=ELD(w),      c1=ELD(w+8),   c2=ELD(w+16),  c3=ELD(w+24),
              c4=ELD(w+32),   c5=ELD(w+40),  c6=ELD(w+48),  c7=ELD(w+56);
        s16x8 n0=ELD(w+64),   n1=ELD(w+72),  n2=ELD(w+80),  n3=ELD(w+88),
              n4=ELD(w+96),   n5=ELD(w+104), n6=ELD(w+112), n7=ELD(w+120);
        ACC8(c0,w);     ACC8(c1,w+8);   ACC8(c2,w+16);  ACC8(c3,w+24);
        ACC8(c4,w+32);  ACC8(c5,w+40);  ACC8(c6,w+48);  ACC8(c7,w+56);
        c0=ELD(w+128); c1=ELD(w+136); c2=ELD(w+144); c3=ELD(w+152);
        c4=ELD(w+160); c5=ELD(w+168); c6=ELD(w+176); c7=ELD(w+184);
        ACC8(n0,w+64);  ACC8(n1,w+72);  ACC8(n2,w+80);  ACC8(n3,w+88);
        ACC8(n4,w+96);  ACC8(n5,w+104); ACC8(n6,w+112); ACC8(n7,w+120);
        const bool tail = (w < 4);
        s16x8 t0;
        if (tail) t0 = ELD(192+w);
        ACC8(c0,w+128); ACC8(c1,w+136); ACC8(c2,w+144); ACC8(c3,w+152);
        ACC8(c4,w+160); ACC8(c5,w+168); ACC8(c6,w+176); ACC8(c7,w+184);
        if (tail) ACC8(t0,192+w);
      }
#undef ELD
#undef ACC8
      *(f32x4*)&awe_p[w*512 + lane*8]     = (f32x4){a8[0],a8[1],a8[2],a8[3]};
      *(f32x4*)&awe_p[w*512 + lane*8 + 4] = (f32x4){a8[4],a8[5],a8[6],a8[7]};
      __syncthreads();
      if (tid < 256){
        int c0 = 2*tid;
        float s0 = 0.f, s1 = 0.f;
        #pragma unroll
        for (int g=0; g<8; ++g){ s0 += awe_p[g*512 + c0]; s1 += awe_p[g*512 + c0 + 1]; }
        float g0 = sigm(aLf(fa.y0p + (long)b*2560 + s*512 + c0));
        float g1 = sigm(aLf(fa.y0p + (long)b*2560 + s*512 + c0 + 1));
        u32 pk = (u32)f2bf(g0*s0) | ((u32)f2bf(g1*s1) << 16);
        aS(cur32 + (long)b*1280 + s*256 + tid, pk);
      }
      __syncthreads();
      }
    }
    gsync(flags, epochw, ++ep, blk, tid);

    // ---- P4: ntile = blk&63 (XCD-consistent), split = blk>>6 ; cached x|h reads ----
    {
      const int ntile = blk & 63, split = blk >> 6;
      f32x4 acc = {0,0,0,0};
      #pragma unroll
      for (int r=0; r<2; ++r){
        const int kbw = split*640 + r*320;     // u16 col base
        const int kbd = split*320 + r*160;     // u32 col base
        u32 sa[20];
        #pragma unroll
        for (int i=0;i<20;++i){
          int c = i*512 + tid;
          int row = c/160, kp = c%160;
          sa[i] = *(const u32*)(cur32 + (long)row*1280 + kbd + kp);   // cached
        }
        s16x8 sb[3];
        #pragma unroll
        for (int i=0;i<3;++i){
          int c = i*512 + tid;
          if (c < 1280){
            int row = c/40, k16 = c%40;
            sb[i] = *(const s16x8*)(fa.wcat2 + (long)(ntile*32+row)*2560 + kbw + k16*8);
          }
        }
        #pragma unroll
        for (int i=0;i<20;++i){
          int c = i*512 + tid;
          int row = c/160, kp = c%160;
          *(u32*)(smem + row*640 + ((kp*4) ^ ((row&7)<<4))) = sa[i];
        }
        #pragma unroll
        for (int i=0;i<3;++i){
          int c = i*512 + tid;
          if (c < 1280){
            int row = c/40, k16 = c%40;
            *(s16x8*)(smem + 40960 + row*640 + ((k16*16) ^ ((row&7)<<4))) = sb[i];
          }
        }
        __syncthreads();
        #pragma unroll
        for (int ks=0; ks<10; ++ks){
          int kboff = ks*64 + ((lane>>4)<<4);
          int ra = mstrip*16 + (lane&15);
          s16x8 af = *(const s16x8*)(smem + ra*640 + (kboff ^ ((ra&7)<<4)));
          int rb = nhalf*16 + (lane&15);
          s16x8 bf = *(const s16x8*)(smem + 40960 + rb*640 + (kboff ^ ((rb&7)<<4)));
          acc = __builtin_amdgcn_mfma_f32_16x16x32_bf16(bf, af, acc, 0,0,0);
        }
        __syncthreads();
      }
      {
        float* PS = fa.part + (long)split*(64*2048);
        int m = mstrip*16 + (lane&15);
        int n0 = ntile*32 + nhalf*16 + ((lane>>4)<<2);
        #pragma unroll
        for (int j=0;j<4;++j) aSf(PS + (long)m*2048 + n0 + j, acc[j]);
      }
      __syncthreads();   // drains vmcnt per wave -> part stores globally visible
      if (tid==0){
        int v = __hip_atomic_fetch_add(fa.cnt + t*64 + ntile, 1,
                                       __ATOMIC_RELAXED, __HIP_MEMORY_SCOPE_AGENT);
        lastf = (v == 3);
      }
      __syncthreads();
      if (lastf && tid < 256){
        int b = tid>>2, jp = tid&3;
        u16 h2[2];
        #pragma unroll
        for (int jj=0; jj<2; ++jj){
          int jl = jp*2 + jj;
          int j = ntile*8 + jl;
          float g4[4];
          #pragma unroll
          for (int gi=0; gi<4; ++gi){
            long n = (long)ntile*32 + jl*4 + gi;
            float sg = fa.gst[((long)t*64 + b)*2048 + n];
            #pragma unroll
            for (int sp=0; sp<4; ++sp)
              sg += aLf(fa.part + (long)sp*(64*2048) + (long)b*2048 + n);
            g4[gi] = sg;
          }
          float cc = aLf(fa.c + b*512 + j);
          float cn = sigm(g4[1])*cc + sigm(g4[0])*tanhf(g4[2]);
          float hn = sigm(g4[3])*tanhf(cn);
          aSf(fa.c + b*512 + j, cn);
          h2[jj] = f2bf(hn);
        }
        u32 pk = (u32)h2[0] | ((u32)h2[1] << 16);
        aS(nxt32 + (long)b*1280 + 1024 + ntile*4 + jp, pk);
        *(u32*)&fa.hall[((long)t*64 + b)*512 + ntile*8 + jp*2] = pk;
      }
    }
    if (t < 19) gsync(flags, epochw, ++ep, blk, tid);
  }
}

// ---------- transpose f32[R][C] -> bf16[C][R] ----------
__global__ __launch_bounds__(256) void transpose_bf16(
    const float* __restrict__ in, u16* __restrict__ out, int R, int C)
{
  __shared__ float t[64][65];
  const int bx = blockIdx.x*64, by = blockIdx.y*64;
  const int tx = threadIdx.x & 63, ty = threadIdx.x >> 6;
  #pragma unroll
  for (int i=0;i<16;++i){ int r = i*4+ty; t[r][tx] = in[(long)(by+r)*C + bx+tx]; }
  __syncthreads();
  #pragma unroll
  for (int i=0;i<16;++i){ int cc = i*4+ty; out[(long)(bx+cc)*R + by+tx] = f2bf(t[tx][cc]); }
}

// ---------- sort + small outputs + counter/barrier/nact init ----------
__global__ void sort_k(const int* __restrict__ cl, const int* __restrict__ captions,
                       int* __restrict__ sidx, int* __restrict__ declen,
                       float* __restrict__ outCaps, float* __restrict__ outLens,
                       float* __restrict__ outSidx, int* __restrict__ cnt,
                       u32* __restrict__ bar, int* __restrict__ nact)
{
  __shared__ int s_idx[64];
  __shared__ int s_dl[64];
  int i = threadIdx.x;
  int li = cl[i];
  int rank = 0;
  for (int j=0;j<64;++j){ int lj = cl[j]; rank += (lj>li) || (lj==li && j<i); }
  s_idx[rank] = i;
  __syncthreads();
  int src = s_idx[i];
  sidx[i] = src;
  int L = cl[src];
  declen[i] = L - 1;
  s_dl[i] = L - 1;
  outLens[i] = (float)L;
  outSidx[i] = (float)src;
  for (int s=0;s<22;++s) outCaps[i*22+s] = (float)captions[s*64 + src];
  for (int s=0;s<20;++s) cnt[s*64 + i] = 0;
  for (int s=i; s<4160; s+=64) bar[s] = 0u;
  __syncthreads();
  if (i < 20){
    int c = 0;
    for (int j=0;j<64;++j) c += (s_dl[j] > i);
    nact[i] = c;
  }
}

// ---------- gather sorted enc -> bf16 + mean (512 blocks) ----------
__global__ __launch_bounds__(256) void prep_enc(
    const float* __restrict__ features, const int* __restrict__ sidx,
    u16* __restrict__ enc, u16* __restrict__ meanb)
{
  __shared__ float red[4][256];
  int b = blockIdx.x >> 3, oct = blockIdx.x & 7;
  int lv = threadIdx.x & 63, g = threadIdx.x >> 6;
  int d0 = oct*256 + lv*4;
  const float* src = features + (long)sidx[b]*(196*2048) + d0;
  float acc[4] = {0.f,0.f,0.f,0.f};
  for (int p=g; p<196; p+=4){
    f32x4 v = *(const f32x4*)(src + (long)p*2048);
    u16 o[4];
    #pragma unroll
    for (int q=0;q<4;++q){ acc[q] += v[q]; o[q] = f2bf(v[q]); }
    *(s16x4*)(enc + ((long)b*196 + p)*2048 + d0) = *(s16x4*)o;
  }
  #pragma unroll
  for (int q=0;q<4;++q) red[g][lv*4+q] = acc[q];
  __syncthreads();
  if (threadIdx.x < 64){
    u16 mo[4];
    #pragma unroll
    for (int q=0;q<4;++q){
      float s = red[0][threadIdx.x*4+q] + red[1][threadIdx.x*4+q]
              + red[2][threadIdx.x*4+q] + red[3][threadIdx.x*4+q];
      mo[q] = f2bf(s*(1.f/196.f));
    }
    *(s16x4*)(meanb + b*2048 + oct*256 + threadIdx.x*4) = *(s16x4*)mo;
  }
}

// ---------- gather embeddings for t<20 -> bf16 [t*64+b][512] ----------
__global__ void emb_gather(const int* __restrict__ captions, const int* __restrict__ sidx,
                           const float* __restrict__ embW, u16* __restrict__ out)
{
  int idx = blockIdx.x*256 + threadIdx.x;      // 1280*64
  int row = idx >> 6; int e0 = (idx & 63)*8;
  int t = row >> 6, b = row & 63;
  int tok = captions[t*64 + sidx[b]];
  const float* s = embW + (long)tok*512 + e0;
  f32x4 v0 = *(const f32x4*)s, v1 = *(const f32x4*)(s+4);
  u16 o[8];
  #pragma unroll
  for (int q=0;q<4;++q){ o[q] = f2bf(v0[q]); o[4+q] = f2bf(v1[q]); }
  *(s16x8*)(out + (long)row*512 + e0) = *(s16x8*)o;
}

// ---------- weight packers ----------
__global__ void build_wcat2(const float* __restrict__ Wih, const float* __restrict__ Whh,
                            u16* __restrict__ out)
{
  long idx = (long)blockIdx.x*256 + threadIdx.x;   // 2048*320
  int r = (int)(idx / 320);
  int kc = (int)(idx % 320) * 8;
  int j = r>>2, g = r&3;
  int orow = g*512 + j;
  const float* s = (kc < 2048) ? (Wih + (long)orow*2560 + 512 + kc)
                               : (Whh + (long)orow*512 + (kc - 2048));
  f32x4 v0 = *(const f32x4*)s, v1 = *(const f32x4*)(s+4);
  u16 o[8];
  #pragma unroll
  for (int q=0;q<4;++q){ o[q] = f2bf(v0[q]); o[4+q] = f2bf(v1[q]); }
  *(s16x8*)(out + (long)r*2560 + kc) = *(s16x8*)o;
}

__global__ void build_wihe(const float* __restrict__ Wih, u16* __restrict__ out)
{
  int idx = blockIdx.x*256 + threadIdx.x;          // 2048*64
  int r = idx >> 6; int kc = (idx & 63)*8;
  int j = r>>2, g = r&3;
  const float* s = Wih + (long)(g*512+j)*2560 + kc;
  f32x4 v0 = *(const f32x4*)s, v1 = *(const f32x4*)(s+4);
  u16 o[8];
  #pragma unroll
  for (int q=0;q<4;++q){ o[q] = f2bf(v0[q]); o[4+q] = f2bf(v1[q]); }
  *(s16x8*)(out + (long)r*512 + kc) = *(s16x8*)o;
}

__global__ void build_bias(const float* bih, const float* bhh, const float* bbeta,
                           const float* bd, const float* bh0, const float* bc0,
                           float* bstat, float* bmisc, float* bhc)
{
  int idx = blockIdx.x*256 + threadIdx.x;
  if (idx < 2048){ int j = idx>>2, g = idx&3; bstat[idx] = bih[g*512+j] + bhh[g*512+j]; }
  else if (idx < 4608){ int k = idx-2048; bmisc[k] = (k<2048) ? bbeta[k] : bd[k-2048]; }
  else if (idx < 5632){ int k = idx-4608; bhc[k] = (k<512) ? bh0[k] : bc0[k-512]; }
}

// ---------- workspace layout (bytes) ----------
static constexpr long OFF_ENC   = 0;                 // 64*196*2048 bf16
static constexpr long OFF_ATT1  = 51380224;          // 12544*512 bf16
static constexpr long OFF_WOUTT = 64225280;          // 32000*512 bf16
static constexpr long OFF_WET   = 96993280;          // 512*2048 bf16
static constexpr long OFF_WMISC = 99090432;          // 2560*512 bf16 (Wbeta^T ; Wd^T)
static constexpr long OFF_WHC   = 101711872;         // 1024*2048 bf16 -- REUSED as PART
static constexpr long OFF_WCAT2 = 105906176;         // 2048*2560 bf16 (perm [Wih_a|Whh])
static constexpr long OFF_WIHE  = 116391936;         // 2048*512 bf16 (perm Wih_e)
static constexpr long OFF_EMBB  = 118489088;         // 1280*512 bf16
static constexpr long OFF_GST   = 119799808;         // 1280*2048 f32
static constexpr long OFF_HALL  = 130285568;         // 1280*512 bf16
static constexpr long OFF_MEANB = 131596288;         // 64*2048 bf16
static constexpr long OFF_C     = 132513792;         // 64*512 f32
static constexpr long OFF_Y0P   = 132644864;         // 64*2560 f32
static constexpr long OFF_BSTAT = 133955584;         // 2048 f32
static constexpr long OFF_BMISC = 133963776;         // 2560 f32
static constexpr long OFF_BHC   = 133974016;         // 1024 f32
static constexpr long OFF_SIDX  = 133978112;         // 64 int
static constexpr long OFF_DECL  = 133978368;         // 64 int
static constexpr long OFF_CNT   = 133978624;         // 20*64 int
static constexpr long OFF_BAR   = 133983744;         // 4160 u32
static constexpr long OFF_NACT  = 134000384;         // 20 int
static constexpr long OFF_XH20  = 134017024;         // 21 * 64*2560 bf16 (6.88 MB)
static constexpr long OFF_PART  = OFF_WHC;           // 4*64*2048 f32 (2 MB, after setup)

extern "C" void kernel_launch(void* const* d_in, const int* in_sizes, int n_in,
                              void* d_out, int out_size, void* d_ws, size_t ws_size,
                              hipStream_t stream)
{
  (void)in_sizes; (void)n_in; (void)out_size; (void)ws_size;
  const float* features = (const float*)d_in[0];
  const int*   captions = (const int*)d_in[1];
  const int*   caplen   = (const int*)d_in[2];
  const float* embW     = (const float*)d_in[3];
  const float* We       = (const float*)d_in[4];
  const float* be       = (const float*)d_in[5];
  const float* Wd       = (const float*)d_in[6];
  const float* bd       = (const float*)d_in[7];
  const float* wf       = (const float*)d_in[8];
  const float* bfp      = (const float*)d_in[9];
  const float* Wih      = (const float*)d_in[10];
  const float* Whh      = (const float*)d_in[11];
  const float* bih      = (const float*)d_in[12];
  const float* bhh      = (const float*)d_in[13];
  const float* Wh0      = (const float*)d_in[14];
  const float* bh0      = (const float*)d_in[15];
  const float* Wc0      = (const float*)d_in[16];
  const float* bc0      = (const float*)d_in[17];
  const float* Wbeta    = (const float*)d_in[18];
  const float* bbeta    = (const float*)d_in[19];
  const float* Wout     = (const float*)d_in[20];
  const float* bout     = (const float*)d_in[21];

  char* ws = (char*)d_ws;
  u16*   enc   = (u16*)(ws + OFF_ENC);
  u16*   att1  = (u16*)(ws + OFF_ATT1);
  u16*   woutt = (u16*)(ws + OFF_WOUTT);
  u16*   wet   = (u16*)(ws + OFF_WET);
  u16*   wmisc = (u16*)(ws + OFF_WMISC);
  u16*   whc   = (u16*)(ws + OFF_WHC);
  u16*   wcat2 = (u16*)(ws + OFF_WCAT2);
  u16*   wihe  = (u16*)(ws + OFF_WIHE);
  u16*   embb  = (u16*)(ws + OFF_EMBB);
  float* gst   = (float*)(ws + OFF_GST);
  u16*   hall  = (u16*)(ws + OFF_HALL);
  u16*   meanb = (u16*)(ws + OFF_MEANB);
  float* cbuf  = (float*)(ws + OFF_C);
  float* y0p   = (float*)(ws + OFF_Y0P);
  float* bstat = (float*)(ws + OFF_BSTAT);
  float* bmisc = (float*)(ws + OFF_BMISC);
  float* bhc   = (float*)(ws + OFF_BHC);
  int*   sidx  = (int*)(ws + OFF_SIDX);
  int*   declen= (int*)(ws + OFF_DECL);
  int*   cnt   = (int*)(ws + OFF_CNT);
  u32*   bar   = (u32*)(ws + OFF_BAR);
  int*   nact  = (int*)(ws + OFF_NACT);
  u16*   xh20  = (u16*)(ws + OFF_XH20);
  float* part  = (float*)(ws + OFF_PART);

  float* outP    = (float*)d_out;            // [64][20][32000]
  float* outCaps = outP + 40960000;          // [64][22]
  float* outLens = outCaps + 1408;           // [64]
  float* outAlph = outLens + 64;             // [64][20][196]
  float* outSidx = outAlph + 250880;         // [64]

  // ---- setup ----
  sort_k<<<1,64,0,stream>>>(caplen, captions, sidx, declen, outCaps, outLens, outSidx, cnt, bar, nact);
  prep_enc<<<512,256,0,stream>>>(features, sidx, enc, meanb);
  emb_gather<<<320,256,0,stream>>>(captions, sidx, embW, embb);
  transpose_bf16<<<dim3(8,32),256,0,stream>>>(We,    wet,              2048, 512);
  transpose_bf16<<<dim3(32,8),256,0,stream>>>(Wbeta, wmisc,            512, 2048);
  transpose_bf16<<<dim3(8,8), 256,0,stream>>>(Wd,    wmisc + 2048*512, 512, 512);
  transpose_bf16<<<dim3(8,32),256,0,stream>>>(Wh0,   whc,              2048, 512);
  transpose_bf16<<<dim3(8,32),256,0,stream>>>(Wc0,   whc + 512*2048,   2048, 512);
  transpose_bf16<<<dim3(500,8),256,0,stream>>>(Wout, woutt,            512, 32000);
  build_wcat2<<<2560,256,0,stream>>>(Wih, Whh, wcat2);
  build_wihe<<<512,256,0,stream>>>(Wih, wihe);
  build_bias<<<22,256,0,stream>>>(bih,bhh,bbeta,bd,bh0,bc0,bstat,bmisc,bhc);

  // h0/c0 : mean @ [Wh0|Wc0] -> xh20[0] h-half + c (cached stores; kernel-end flush)
  { EpiParams ep{}; ep.bias0 = bhc; ep.xh = xh20; ep.c = cbuf;
    gemm_bt<64,64,EPI_H0C0,false,0><<<dim3(16,1),256,0,stream>>>(meanb, 2048, whc, 2048, 2048, ep); }
  // att1 = enc @ We + be  (bf16 out)
  { EpiParams ep{}; ep.outb = att1; ep.ldo = 512; ep.bias0 = be;
    gemm_bt<128,128,EPI_BF16,true,0><<<dim3(98,4),256,0,stream>>>(enc, 2048, wet, 2048, 2048, ep); }
  // g_static = emb @ Wih_e^T + bih + bhh (permuted cols)
  { EpiParams ep{}; ep.out0 = gst; ep.ldo = 2048; ep.bias0 = bstat;
    gemm_bt<128,64,EPI_F32,false,0><<<dim3(32,10),256,0,stream>>>(embb, 512, wihe, 512, 512, ep); }

  // ---- 20 fused sequential steps (cooperative, 256 blocks x 512 thr) ----
  {
    FusedArgs fa;
    fa.att1 = att1; fa.enc = enc; fa.wmisc = wmisc; fa.wcat2 = wcat2;
    fa.gst = gst; fa.wf = wf; fa.bfp = bfp; fa.declen = declen; fa.bmisc = bmisc;
    fa.nact = nact;
    fa.xh20 = xh20; fa.y0p = y0p;
    fa.part = part; fa.cnt = cnt; fa.c = cbuf; fa.hall = hall;
    fa.alph = outAlph; fa.bar = bar;
    void* kargs[1] = { &fa };
    hipLaunchCooperativeKernel((const void*)steps_fused, dim3(256), dim3(512),
                               kargs, 0, stream);
  }

  // ---- batched predictions: h_all @ Wout + bout, masked rows skipped ----
  { EpiParams ep{}; ep.out0 = outP; ep.bias0 = bout; ep.declen = declen;
    gemm_bt<128,128,EPI_PREDS,false,10><<<2500,256,0,stream>>>(hall, 512, woutt, 512, 512, ep); }
}

// Round 14
// 1534.483 us; speedup vs baseline: 1.8074x; 1.0361x over previous
//
#include <hip/hip_runtime.h>
#include <stdint.h>

// ---------- types / helpers ----------
typedef short s16x8 __attribute__((ext_vector_type(8)));
typedef short s16x4 __attribute__((ext_vector_type(4)));
typedef float f32x4 __attribute__((ext_vector_type(4)));
typedef unsigned short u16;
typedef unsigned int u32;

#define DEV __device__ __forceinline__

DEV float bf2f(u16 v){ union{float f; unsigned u;} x; x.u = ((unsigned)v)<<16; return x.f; }
DEV u16 f2bf(float f){ union{float f; unsigned u;} x; x.f = f; unsigned r = x.u + 0x7fffu + ((x.u>>16)&1u); return (u16)(r>>16); }
DEV float sigm(float x){ return 1.f/(1.f + __expf(-x)); }

// coherence-point (L2-bypassing) accessors: RELAXED atomics at agent scope
DEV u32  aL(const u32* p){ return __hip_atomic_load(p, __ATOMIC_RELAXED, __HIP_MEMORY_SCOPE_AGENT); }
DEV void aS(u32* p, u32 v){ __hip_atomic_store(p, v, __ATOMIC_RELAXED, __HIP_MEMORY_SCOPE_AGENT); }
DEV float aLf(const float* p){ return __hip_atomic_load(p, __ATOMIC_RELAXED, __HIP_MEMORY_SCOPE_AGENT); }
DEV void aSf(float* p, float v){ __hip_atomic_store(p, v, __ATOMIC_RELAXED, __HIP_MEMORY_SCOPE_AGENT); }

// B=64, P=196, D=2048, E=512, H=512, A=512, V=32000, S=22, T=20

enum { EPI_F32=0, EPI_BF16=1, EPI_H0C0=2, EPI_PREDS=3 };

struct EpiParams {
  float* out0; long ldo;
  u16* outb;
  const float* bias0;
  const int* declen;
  float* c; u16* xh;
};

// ---------- generic MFMA GEMM: C[M][N] = A[M][K](bf16) * B[N][K](bf16)^T ----------
template<int BM, int BN, int EPI, bool SWAPXY, int SWZM>
__global__ __launch_bounds__(256) void gemm_bt(
    const u16* __restrict__ A, long lda,
    const u16* __restrict__ B, long ldb,
    int K, EpiParams ep)
{
  constexpr int MF = BM/64;
  constexpr int NF = BN/16;
  constexpr int CHA = BM*8, CH = CHA + BN*8;
  constexpr int NST = CH/256;
  __shared__ char smem[(BM+BN)*128];
  const int tid = threadIdx.x;
  const int w = tid>>6, lane = tid&63;

  long arow0, brow0;
  if constexpr (SWZM > 0) {
    int id = blockIdx.x, tot = gridDim.x;
    int q = tot>>3, r = tot&7, xcd = id&7, idx = id>>3;
    int cid = (xcd<r) ? xcd*(q+1)+idx : r*(q+1)+(xcd-r)*q+idx;
    arow0 = (long)(cid % SWZM)*BM; brow0 = (long)(cid / SWZM)*BN;
  } else if constexpr (SWAPXY) { arow0 = (long)blockIdx.x*BM; brow0 = (long)blockIdx.y*BN; }
  else { arow0 = (long)blockIdx.y*BM; brow0 = (long)blockIdx.x*BN; }

  const u16* gsrc[NST]; int ldst[NST];
  #pragma unroll
  for (int i=0;i<NST;++i){
    int c = i*256 + tid;
    if (i*256 < CHA){
      int row = c>>3, k16 = c&7;
      gsrc[i] = A + (arow0+row)*lda + k16*8;
      ldst[i] = row*128 + ((k16*16) ^ ((row&7)<<4));
    } else {
      int cb = c - CHA; int row = cb>>3, k16 = cb&7;
      gsrc[i] = B + (brow0+row)*ldb + k16*8;
      ldst[i] = BM*128 + row*128 + ((k16*16) ^ ((row&7)<<4));
    }
  }

  f32x4 acc[MF][NF];
  #pragma unroll
  for (int i=0;i<MF;++i)
    #pragma unroll
    for (int j=0;j<NF;++j) acc[i][j] = (f32x4){0.f,0.f,0.f,0.f};

  const int KT = K >> 6;
  s16x8 st[NST];
  #pragma unroll
  for (int i=0;i<NST;++i) st[i] = *(const s16x8*)(gsrc[i]);

  char* Al = smem;
  for (int kk=0; kk<KT; ++kk){
    #pragma unroll
    for (int i=0;i<NST;++i) *(s16x8*)(smem + ldst[i]) = st[i];
    __syncthreads();
    if (kk+1 < KT){
      long kb = (long)(kk+1)*64;
      #pragma unroll
      for (int i=0;i<NST;++i) st[i] = *(const s16x8*)(gsrc[i] + kb);
    }
    #pragma unroll
    for (int ks = 0; ks < 2; ++ks) {
      s16x8 af[MF], bfr[NF];
      const int kboff = ks*64 + ((lane>>4)<<4);
      #pragma unroll
      for (int mf=0; mf<MF; ++mf) {
        int r = w*(16*MF) + mf*16 + (lane&15);
        af[mf] = *(const s16x8*)(Al + r*128 + (kboff ^ ((r&7)<<4)));
      }
      #pragma unroll
      for (int nf=0; nf<NF; ++nf) {
        int r = nf*16 + (lane&15);
        bfr[nf] = *(const s16x8*)(Al + BM*128 + r*128 + (kboff ^ ((r&7)<<4)));
      }
      #pragma unroll
      for (int mf=0; mf<MF; ++mf)
        #pragma unroll
        for (int nf=0; nf<NF; ++nf)
          acc[mf][nf] = __builtin_amdgcn_mfma_f32_16x16x32_bf16(bfr[nf], af[mf], acc[mf][nf], 0,0,0);
    }
    __syncthreads();
  }

  #pragma unroll
  for (int mf=0; mf<MF; ++mf)
    #pragma unroll
    for (int nf=0; nf<NF; ++nf){
      long m = arow0 + w*(16*MF) + mf*16 + (lane&15);
      long n0 = brow0 + nf*16 + ((lane>>4)<<2);
      f32x4 bv = *(const f32x4*)&ep.bias0[n0];
      f32x4 v = acc[mf][nf] + bv;
      if constexpr (EPI == EPI_F32) {
        *(f32x4*)&ep.out0[m*ep.ldo + n0] = v;
      } else if constexpr (EPI == EPI_BF16) {
        u16 o[4];
        #pragma unroll
        for (int r=0;r<4;++r) o[r] = f2bf(v[r]);
        *(s16x4*)&ep.outb[m*ep.ldo + n0] = *(s16x4*)o;
      } else if constexpr (EPI == EPI_H0C0) {
        if (n0 < 512){
          u16 o[4];
          #pragma unroll
          for (int r=0;r<4;++r) o[r] = f2bf(v[r]);
          *(s16x4*)&ep.xh[m*2560 + 2048 + n0] = *(s16x4*)o;
        } else {
          *(f32x4*)&ep.c[m*512 + (n0-512)] = v;
        }
      } else { // EPI_PREDS: skip masked rows entirely
        int tt = (int)(m>>6), b = (int)(m&63);
        if (ep.declen[b] > tt)
          *(f32x4*)&ep.out0[(long)b*640000 + (long)tt*32000 + n0] = v;
      }
    }
}

// ---------- dataflow counters (one-hop handoff, no central barrier) ----------
DEV void wait_cnt(const u32* p, u32 tgt){
  if (threadIdx.x == 0){
    while (aL(p) < tgt) __builtin_amdgcn_s_sleep(4);
  }
  __syncthreads();
}
DEV void bump(u32* p){
  __syncthreads();     // all waves drain vmcnt -> prior stores at coherence point
  if (threadIdx.x == 0)
    __hip_atomic_fetch_add(p, 1u, __ATOMIC_RELAXED, __HIP_MEMORY_SCOPE_AGENT);
}

// ---------- fused 20-step decoder loop (cooperative, 256 blocks x 512 thr) ----------
// xh20: 21 per-step dedicated [64][2560] bf16 buffers. Producers bypass-write,
// consumers CACHED-read (first-touch-per-step addresses -> no stale L2/L1 lines).
// Sync: p1c[t](80) y0 ready ; xc[t](256) x ready ; hc[t](64) h/c ready.
struct FusedArgs {
  const u16* att1; const u16* enc;
  const u16* wmisc; const u16* wcat2;
  const float* gst; const float* wf; const float* bfp;
  const int* declen; const float* bmisc; const int* nact;
  u16* xh20; float* y0p;
  float* part; int* cnt; float* c; u16* hall;
  float* alph; u32* bar;
};

__global__ __launch_bounds__(512) void steps_fused(FusedArgs fa)
{
  __shared__ char smem[61440];
  __shared__ float wred[8];
  __shared__ int lastf;
  const int blk = blockIdx.x, tid = threadIdx.x;
  const int w = tid>>6, lane = tid&63;
  const int mstrip = w>>1, nhalf = w&1;
  u32* p1c = fa.bar;          // [20]
  u32* xc  = fa.bar + 64;     // [20]
  u32* hc  = fa.bar + 128;    // [20]

  for (int t=0; t<20; ++t){
    u16* cur = fa.xh20 + (long)t*163840;
    u16* nxt = cur + 163840;
    u32* cur32 = (u32*)cur;
    u32* nxt32 = (u32*)nxt;

    // ---- P1: y0 = h @ [Wbeta^T|Wd^T] : 80 blocks, 64x32 tile, K=512 (2 rounds) ----
    if (blk < 80){
      if (t > 0) wait_cnt(hc + (t-1), 64);
      const int brow0 = blk*32;
      f32x4 acc = {0,0,0,0};
      #pragma unroll
      for (int r=0; r<2; ++r){
        u32 sa[16];
        #pragma unroll
        for (int i=0;i<16;++i){
          int c = i*512 + tid;
          int row = c>>7, kp = c&127;
          sa[i] = *(const u32*)(cur32 + (long)row*1280 + 1024 + r*128 + kp);  // cached
        }
        s16x8 sb[2];
        #pragma unroll
        for (int i=0;i<2;++i){
          int c = i*512 + tid;
          int row = c>>5, k16 = c&31;
          sb[i] = *(const s16x8*)(fa.wmisc + (long)(brow0+row)*512 + r*256 + k16*8);
        }
        #pragma unroll
        for (int i=0;i<16;++i){
          int c = i*512 + tid;
          int row = c>>7, kp = c&127;
          *(u32*)(smem + row*512 + ((kp*4) ^ ((row&7)<<4))) = sa[i];
        }
        #pragma unroll
        for (int i=0;i<2;++i){
          int c = i*512 + tid;
          int row = c>>5, k16 = c&31;
          *(s16x8*)(smem + 32768 + row*512 + ((k16*16) ^ ((row&7)<<4))) = sb[i];
        }
        __syncthreads();
        #pragma unroll
        for (int ks=0; ks<8; ++ks){
          int kboff = ks*64 + ((lane>>4)<<4);
          int ra = mstrip*16 + (lane&15);
          s16x8 af = *(const s16x8*)(smem + ra*512 + (kboff ^ ((ra&7)<<4)));
          int rb = nhalf*16 + (lane&15);
          s16x8 bf = *(const s16x8*)(smem + 32768 + rb*512 + (kboff ^ ((rb&7)<<4)));
          acc = __builtin_amdgcn_mfma_f32_16x16x32_bf16(bf, af, acc, 0,0,0);
        }
        __syncthreads();
      }
      int m = mstrip*16 + (lane&15);
      int n0 = brow0 + nhalf*16 + ((lane>>4)<<2);
      #pragma unroll
      for (int j=0;j<4;++j)
        aSf(fa.y0p + (long)m*2560 + n0 + j, acc[j] + fa.bmisc[n0+j]);
      bump(p1c + t);
    }

    // ---- P23: b = blk&63 (XCD-consistent), s = blk>>6 ; pruned by nact[t] ----
    wait_cnt(p1c + t, 80);
    {
      const int b = blk & 63, s = blk >> 6;
      const int na = fa.nact[t];
      if (b >= na){
        if (s == 0){
          for (int i=tid; i<196; i+=512)
            fa.alph[((long)b*20 + t)*196 + i] = 0.f;
        }
      } else {
      float* att2p = (float*)smem;           // 8*72
      float* wfp   = att2p + 576;            // 8*72
      float* alps  = wfp + 576;              // 208
      float* awe_p = alps + 208;             // 8*512
      {
        int kg0 = tid>>6, j = tid&63;
        att2p[kg0*72 + j] = aLf(fa.y0p + (long)b*2560 + 2048 + tid);
        wfp[kg0*72 + j]   = fa.wf[tid];
      }
      __syncthreads();
      const float bfv = fa.bfp[0];
      const int pg = lane>>3, kg = lane&7;
      #pragma unroll
      for (int pass=0; pass<4; ++pass){
        int p = pass*64 + w*8 + pg;
        if (p < 196){
          const u16* ap = fa.att1 + (((long)(b*196 + p))<<9) + kg*64;
          float sa = 0.f;
          #pragma unroll
          for (int i=0;i<8;++i){
            s16x8 v = *(const s16x8*)(ap + i*8);
            #pragma unroll
            for (int q=0;q<8;++q){
              float x = bf2f((u16)v[q]) + att2p[kg*72 + i*8 + q];
              x = fmaxf(x, 0.f);
              sa += x * wfp[kg*72 + i*8 + q];
            }
          }
          sa += __shfl_xor(sa, 1);
          sa += __shfl_xor(sa, 2);
          sa += __shfl_xor(sa, 4);
          if (kg == 0) alps[p] = sa + bfv;
        }
      }
      __syncthreads();
      float v = (tid < 196) ? alps[tid] : -3.4e38f;
      float m8 = v;
      #pragma unroll
      for (int off=32; off; off>>=1) m8 = fmaxf(m8, __shfl_xor(m8, off));
      if (lane == 0) wred[w] = m8;
      __syncthreads();
      float mx = wred[0];
      #pragma unroll
      for (int i=1;i<8;++i) mx = fmaxf(mx, wred[i]);
      float e = (tid < 196) ? __expf(v - mx) : 0.f;
      float s8 = e;
      #pragma unroll
      for (int off=32; off; off>>=1) s8 += __shfl_xor(s8, off);
      __syncthreads();
      if (lane == 0) wred[w] = s8;
      __syncthreads();
      float den = wred[0]+wred[1]+wred[2]+wred[3]+wred[4]+wred[5]+wred[6]+wred[7];
      float inv = 1.f/den;
      if (tid < 196){
        float a = e*inv;
        alps[tid] = a;
        if (s==0) fa.alph[((long)b*20 + t)*196 + tid] = (fa.declen[b] > t) ? a : 0.f;
      }
      __syncthreads();
      // awe: 4-deep pipelined p-loop (R11 form), non-temporal enc loads
      const int d0 = s*512 + lane*8;
      const u16* ebase = fa.enc + (((long)b*196)<<11) + d0;
      float a8[8] = {0,0,0,0,0,0,0,0};
      int p = w;
      for (; p+24 < 196; p += 32){
        s16x8 e0 = __builtin_nontemporal_load((const s16x8*)(ebase + ((long)p<<11)));
        s16x8 e1 = __builtin_nontemporal_load((const s16x8*)(ebase + ((long)(p+8)<<11)));
        s16x8 e2 = __builtin_nontemporal_load((const s16x8*)(ebase + ((long)(p+16)<<11)));
        s16x8 e3 = __builtin_nontemporal_load((const s16x8*)(ebase + ((long)(p+24)<<11)));
        float a0 = alps[p], a1 = alps[p+8], a2 = alps[p+16], a3 = alps[p+24];
        #pragma unroll
        for (int q=0;q<8;++q) a8[q] += a0*bf2f((u16)e0[q]);
        #pragma unroll
        for (int q=0;q<8;++q) a8[q] += a1*bf2f((u16)e1[q]);
        #pragma unroll
        for (int q=0;q<8;++q) a8[q] += a2*bf2f((u16)e2[q]);
        #pragma unroll
        for (int q=0;q<8;++q) a8[q] += a3*bf2f((u16)e3[q]);
      }
      for (; p < 196; p += 8){
        s16x8 ev = __builtin_nontemporal_load((const s16x8*)(ebase + ((long)p<<11)));
        float a = alps[p];
        #pragma unroll
        for (int q=0;q<8;++q) a8[q] += a*bf2f((u16)ev[q]);
      }
      *(f32x4*)&awe_p[w*512 + lane*8]     = (f32x4){a8[0],a8[1],a8[2],a8[3]};
      *(f32x4*)&awe_p[w*512 + lane*8 + 4] = (f32x4){a8[4],a8[5],a8[6],a8[7]};
      __syncthreads();
      if (tid < 256){
        int c0 = 2*tid;
        float s0 = 0.f, s1 = 0.f;
        #pragma unroll
        for (int g=0; g<8; ++g){ s0 += awe_p[g*512 + c0]; s1 += awe_p[g*512 + c0 + 1]; }
        float g0 = sigm(aLf(fa.y0p + (long)b*2560 + s*512 + c0));
        float g1 = sigm(aLf(fa.y0p + (long)b*2560 + s*512 + c0 + 1));
        u32 pk = (u32)f2bf(g0*s0) | ((u32)f2bf(g1*s1) << 16);
        aS(cur32 + (long)b*1280 + s*256 + tid, pk);
      }
      }
    }
    bump(xc + t);

    // ---- P4: ntile = blk&63 (XCD-consistent), split = blk>>6 ; cached x|h reads ----
    wait_cnt(xc + t, 256);
    {
      const int ntile = blk & 63, split = blk >> 6;
      f32x4 acc = {0,0,0,0};
      #pragma unroll
      for (int r=0; r<2; ++r){
        const int kbw = split*640 + r*320;     // u16 col base
        const int kbd = split*320 + r*160;     // u32 col base
        u32 sa[20];
        #pragma unroll
        for (int i=0;i<20;++i){
          int c = i*512 + tid;
          int row = c/160, kp = c%160;
          sa[i] = *(const u32*)(cur32 + (long)row*1280 + kbd + kp);   // cached
        }
        s16x8 sb[3];
        #pragma unroll
        for (int i=0;i<3;++i){
          int c = i*512 + tid;
          if (c < 1280){
            int row = c/40, k16 = c%40;
            sb[i] = *(const s16x8*)(fa.wcat2 + (long)(ntile*32+row)*2560 + kbw + k16*8);
          }
        }
        #pragma unroll
        for (int i=0;i<20;++i){
          int c = i*512 + tid;
          int row = c/160, kp = c%160;
          *(u32*)(smem + row*640 + ((kp*4) ^ ((row&7)<<4))) = sa[i];
        }
        #pragma unroll
        for (int i=0;i<3;++i){
          int c = i*512 + tid;
          if (c < 1280){
            int row = c/40, k16 = c%40;
            *(s16x8*)(smem + 40960 + row*640 + ((k16*16) ^ ((row&7)<<4))) = sb[i];
          }
        }
        __syncthreads();
        #pragma unroll
        for (int ks=0; ks<10; ++ks){
          int kboff = ks*64 + ((lane>>4)<<4);
          int ra = mstrip*16 + (lane&15);
          s16x8 af = *(const s16x8*)(smem + ra*640 + (kboff ^ ((ra&7)<<4)));
          int rb = nhalf*16 + (lane&15);
          s16x8 bf = *(const s16x8*)(smem + 40960 + rb*640 + (kboff ^ ((rb&7)<<4)));
          acc = __builtin_amdgcn_mfma_f32_16x16x32_bf16(bf, af, acc, 0,0,0);
        }
        __syncthreads();
      }
      {
        float* PS = fa.part + (long)split*(64*2048);
        int m = mstrip*16 + (lane&15);
        int n0 = ntile*32 + nhalf*16 + ((lane>>4)<<2);
        #pragma unroll
        for (int j=0;j<4;++j) aSf(PS + (long)m*2048 + n0 + j, acc[j]);
      }
      __syncthreads();   // drains vmcnt per wave -> part stores globally visible
      if (tid==0){
        int v = __hip_atomic_fetch_add(fa.cnt + t*64 + ntile, 1,
                                       __ATOMIC_RELAXED, __HIP_MEMORY_SCOPE_AGENT);
        lastf = (v == 3);
      }
      __syncthreads();
      if (lastf && tid < 256){
        int b = tid>>2, jp = tid&3;
        u16 h2[2];
        #pragma unroll
        for (int jj=0; jj<2; ++jj){
          int jl = jp*2 + jj;
          int j = ntile*8 + jl;
          float g4[4];
          #pragma unroll
          for (int gi=0; gi<4; ++gi){
            long n = (long)ntile*32 + jl*4 + gi;
            float sg = fa.gst[((long)t*64 + b)*2048 + n];
            #pragma unroll
            for (int sp=0; sp<4; ++sp)
              sg += aLf(fa.part + (long)sp*(64*2048) + (long)b*2048 + n);
            g4[gi] = sg;
          }
          float cc = aLf(fa.c + b*512 + j);
          float cn = sigm(g4[1])*cc + sigm(g4[0])*tanhf(g4[2]);
          float hn = sigm(g4[3])*tanhf(cn);
          aSf(fa.c + b*512 + j, cn);
          h2[jj] = f2bf(hn);
        }
        u32 pk = (u32)h2[0] | ((u32)h2[1] << 16);
        aS(nxt32 + (long)b*1280 + 1024 + ntile*4 + jp, pk);
        *(u32*)&fa.hall[((long)t*64 + b)*512 + ntile*8 + jp*2] = pk;
      }
      __syncthreads();   // drain lastf h stores
      if (lastf && tid == 0)
        __hip_atomic_fetch_add(hc + t, 1u, __ATOMIC_RELAXED, __HIP_MEMORY_SCOPE_AGENT);
    }
  }
}

// ---------- transpose f32[R][C] -> bf16[C][R] ----------
__global__ __launch_bounds__(256) void transpose_bf16(
    const float* __restrict__ in, u16* __restrict__ out, int R, int C)
{
  __shared__ float t[64][65];
  const int bx = blockIdx.x*64, by = blockIdx.y*64;
  const int tx = threadIdx.x & 63, ty = threadIdx.x >> 6;
  #pragma unroll
  for (int i=0;i<16;++i){ int r = i*4+ty; t[r][tx] = in[(long)(by+r)*C + bx+tx]; }
  __syncthreads();
  #pragma unroll
  for (int i=0;i<16;++i){ int cc = i*4+ty; out[(long)(bx+cc)*R + by+tx] = f2bf(t[tx][cc]); }
}

// ---------- sort + small outputs + counter/barrier/nact init ----------
__global__ void sort_k(const int* __restrict__ cl, const int* __restrict__ captions,
                       int* __restrict__ sidx, int* __restrict__ declen,
                       float* __restrict__ outCaps, float* __restrict__ outLens,
                       float* __restrict__ outSidx, int* __restrict__ cnt,
                       u32* __restrict__ bar, int* __restrict__ nact)
{
  __shared__ int s_idx[64];
  __shared__ int s_dl[64];
  int i = threadIdx.x;
  int li = cl[i];
  int rank = 0;
  for (int j=0;j<64;++j){ int lj = cl[j]; rank += (lj>li) || (lj==li && j<i); }
  s_idx[rank] = i;
  __syncthreads();
  int src = s_idx[i];
  sidx[i] = src;
  int L = cl[src];
  declen[i] = L - 1;
  s_dl[i] = L - 1;
  outLens[i] = (float)L;
  outSidx[i] = (float)src;
  for (int s=0;s<22;++s) outCaps[i*22+s] = (float)captions[s*64 + src];
  for (int s=0;s<20;++s) cnt[s*64 + i] = 0;
  for (int s=i; s<4160; s+=64) bar[s] = 0u;
  __syncthreads();
  if (i < 20){
    int c = 0;
    for (int j=0;j<64;++j) c += (s_dl[j] > i);
    nact[i] = c;
  }
}

// ---------- gather sorted enc -> bf16 + mean (512 blocks) ----------
__global__ __launch_bounds__(256) void prep_enc(
    const float* __restrict__ features, const int* __restrict__ sidx,
    u16* __restrict__ enc, u16* __restrict__ meanb)
{
  __shared__ float red[4][256];
  int b = blockIdx.x >> 3, oct = blockIdx.x & 7;
  int lv = threadIdx.x & 63, g = threadIdx.x >> 6;
  int d0 = oct*256 + lv*4;
  const float* src = features + (long)sidx[b]*(196*2048) + d0;
  float acc[4] = {0.f,0.f,0.f,0.f};
  for (int p=g; p<196; p+=4){
    f32x4 v = *(const f32x4*)(src + (long)p*2048);
    u16 o[4];
    #pragma unroll
    for (int q=0;q<4;++q){ acc[q] += v[q]; o[q] = f2bf(v[q]); }
    *(s16x4*)(enc + ((long)b*196 + p)*2048 + d0) = *(s16x4*)o;
  }
  #pragma unroll
  for (int q=0;q<4;++q) red[g][lv*4+q] = acc[q];
  __syncthreads();
  if (threadIdx.x < 64){
    u16 mo[4];
    #pragma unroll
    for (int q=0;q<4;++q){
      float s = red[0][threadIdx.x*4+q] + red[1][threadIdx.x*4+q]
              + red[2][threadIdx.x*4+q] + red[3][threadIdx.x*4+q];
      mo[q] = f2bf(s*(1.f/196.f));
    }
    *(s16x4*)(meanb + b*2048 + oct*256 + threadIdx.x*4) = *(s16x4*)mo;
  }
}

// ---------- gather embeddings for t<20 -> bf16 [t*64+b][512] ----------
__global__ void emb_gather(const int* __restrict__ captions, const int* __restrict__ sidx,
                           const float* __restrict__ embW, u16* __restrict__ out)
{
  int idx = blockIdx.x*256 + threadIdx.x;      // 1280*64
  int row = idx >> 6; int e0 = (idx & 63)*8;
  int t = row >> 6, b = row & 63;
  int tok = captions[t*64 + sidx[b]];
  const float* s = embW + (long)tok*512 + e0;
  f32x4 v0 = *(const f32x4*)s, v1 = *(const f32x4*)(s+4);
  u16 o[8];
  #pragma unroll
  for (int q=0;q<4;++q){ o[q] = f2bf(v0[q]); o[4+q] = f2bf(v1[q]); }
  *(s16x8*)(out + (long)row*512 + e0) = *(s16x8*)o;
}

// ---------- weight packers ----------
__global__ void build_wcat2(const float* __restrict__ Wih, const float* __restrict__ Whh,
                            u16* __restrict__ out)
{
  long idx = (long)blockIdx.x*256 + threadIdx.x;   // 2048*320
  int r = (int)(idx / 320);
  int kc = (int)(idx % 320) * 8;
  int j = r>>2, g = r&3;
  int orow = g*512 + j;
  const float* s = (kc < 2048) ? (Wih + (long)orow*2560 + 512 + kc)
                               : (Whh + (long)orow*512 + (kc - 2048));
  f32x4 v0 = *(const f32x4*)s, v1 = *(const f32x4*)(s+4);
  u16 o[8];
  #pragma unroll
  for (int q=0;q<4;++q){ o[q] = f2bf(v0[q]); o[4+q] = f2bf(v1[q]); }
  *(s16x8*)(out + (long)r*2560 + kc) = *(s16x8*)o;
}

__global__ void build_wihe(const float* __restrict__ Wih, u16* __restrict__ out)
{
  int idx = blockIdx.x*256 + threadIdx.x;          // 2048*64
  int r = idx >> 6; int kc = (idx & 63)*8;
  int j = r>>2, g = r&3;
  const float* s = Wih + (long)(g*512+j)*2560 + kc;
  f32x4 v0 = *(const f32x4*)s, v1 = *(const f32x4*)(s+4);
  u16 o[8];
  #pragma unroll
  for (int q=0;q<4;++q){ o[q] = f2bf(v0[q]); o[4+q] = f2bf(v1[q]); }
  *(s16x8*)(out + (long)r*512 + kc) = *(s16x8*)o;
}

__global__ void build_bias(const float* bih, const float* bhh, const float* bbeta,
                           const float* bd, const float* bh0, const float* bc0,
                           float* bstat, float* bmisc, float* bhc)
{
  int idx = blockIdx.x*256 + threadIdx.x;
  if (idx < 2048){ int j = idx>>2, g = idx&3; bstat[idx] = bih[g*512+j] + bhh[g*512+j]; }
  else if (idx < 4608){ int k = idx-2048; bmisc[k] = (k<2048) ? bbeta[k] : bd[k-2048]; }
  else if (idx < 5632){ int k = idx-4608; bhc[k] = (k<512) ? bh0[k] : bc0[k-512]; }
}

// ---------- workspace layout (bytes) ----------
static constexpr long OFF_ENC   = 0;                 // 64*196*2048 bf16
static constexpr long OFF_ATT1  = 51380224;          // 12544*512 bf16
static constexpr long OFF_WOUTT = 64225280;          // 32000*512 bf16
static constexpr long OFF_WET   = 96993280;          // 512*2048 bf16
static constexpr long OFF_WMISC = 99090432;          // 2560*512 bf16 (Wbeta^T ; Wd^T)
static constexpr long OFF_WHC   = 101711872;         // 1024*2048 bf16 -- REUSED as PART
static constexpr long OFF_WCAT2 = 105906176;         // 2048*2560 bf16 (perm [Wih_a|Whh])
static constexpr long OFF_WIHE  = 116391936;         // 2048*512 bf16 (perm Wih_e)
static constexpr long OFF_EMBB  = 118489088;         // 1280*512 bf16
static constexpr long OFF_GST   = 119799808;         // 1280*2048 f32
static constexpr long OFF_HALL  = 130285568;         // 1280*512 bf16
static constexpr long OFF_MEANB = 131596288;         // 64*2048 bf16
static constexpr long OFF_C     = 132513792;         // 64*512 f32
static constexpr long OFF_Y0P   = 132644864;         // 64*2560 f32
static constexpr long OFF_BSTAT = 133955584;         // 2048 f32
static constexpr long OFF_BMISC = 133963776;         // 2560 f32
static constexpr long OFF_BHC   = 133974016;         // 1024 f32
static constexpr long OFF_SIDX  = 133978112;         // 64 int
static constexpr long OFF_DECL  = 133978368;         // 64 int
static constexpr long OFF_CNT   = 133978624;         // 20*64 int
static constexpr long OFF_BAR   = 133983744;         // 4160 u32 (counters)
static constexpr long OFF_NACT  = 134000384;         // 20 int
static constexpr long OFF_XH20  = 134017024;         // 21 * 64*2560 bf16 (6.88 MB)
static constexpr long OFF_PART  = OFF_WHC;           // 4*64*2048 f32 (2 MB, after setup)

extern "C" void kernel_launch(void* const* d_in, const int* in_sizes, int n_in,
                              void* d_out, int out_size, void* d_ws, size_t ws_size,
                              hipStream_t stream)
{
  (void)in_sizes; (void)n_in; (void)out_size; (void)ws_size;
  const float* features = (const float*)d_in[0];
  const int*   captions = (const int*)d_in[1];
  const int*   caplen   = (const int*)d_in[2];
  const float* embW     = (const float*)d_in[3];
  const float* We       = (const float*)d_in[4];
  const float* be       = (const float*)d_in[5];
  const float* Wd       = (const float*)d_in[6];
  const float* bd       = (const float*)d_in[7];
  const float* wf       = (const float*)d_in[8];
  const float* bfp      = (const float*)d_in[9];
  const float* Wih      = (const float*)d_in[10];
  const float* Whh      = (const float*)d_in[11];
  const float* bih      = (const float*)d_in[12];
  const float* bhh      = (const float*)d_in[13];
  const float* Wh0      = (const float*)d_in[14];
  const float* bh0      = (const float*)d_in[15];
  const float* Wc0      = (const float*)d_in[16];
  const float* bc0      = (const float*)d_in[17];
  const float* Wbeta    = (const float*)d_in[18];
  const float* bbeta    = (const float*)d_in[19];
  const float* Wout     = (const float*)d_in[20];
  const float* bout     = (const float*)d_in[21];

  char* ws = (char*)d_ws;
  u16*   enc   = (u16*)(ws + OFF_ENC);
  u16*   att1  = (u16*)(ws + OFF_ATT1);
  u16*   woutt = (u16*)(ws + OFF_WOUTT);
  u16*   wet   = (u16*)(ws + OFF_WET);
  u16*   wmisc = (u16*)(ws + OFF_WMISC);
  u16*   whc   = (u16*)(ws + OFF_WHC);
  u16*   wcat2 = (u16*)(ws + OFF_WCAT2);
  u16*   wihe  = (u16*)(ws + OFF_WIHE);
  u16*   embb  = (u16*)(ws + OFF_EMBB);
  float* gst   = (float*)(ws + OFF_GST);
  u16*   hall  = (u16*)(ws + OFF_HALL);
  u16*   meanb = (u16*)(ws + OFF_MEANB);
  float* cbuf  = (float*)(ws + OFF_C);
  float* y0p   = (float*)(ws + OFF_Y0P);
  float* bstat = (float*)(ws + OFF_BSTAT);
  float* bmisc = (float*)(ws + OFF_BMISC);
  float* bhc   = (float*)(ws + OFF_BHC);
  int*   sidx  = (int*)(ws + OFF_SIDX);
  int*   declen= (int*)(ws + OFF_DECL);
  int*   cnt   = (int*)(ws + OFF_CNT);
  u32*   bar   = (u32*)(ws + OFF_BAR);
  int*   nact  = (int*)(ws + OFF_NACT);
  u16*   xh20  = (u16*)(ws + OFF_XH20);
  float* part  = (float*)(ws + OFF_PART);

  float* outP    = (float*)d_out;            // [64][20][32000]
  float* outCaps = outP + 40960000;          // [64][22]
  float* outLens = outCaps + 1408;           // [64]
  float* outAlph = outLens + 64;             // [64][20][196]
  float* outSidx = outAlph + 250880;         // [64]

  // ---- setup ----
  sort_k<<<1,64,0,stream>>>(caplen, captions, sidx, declen, outCaps, outLens, outSidx, cnt, bar, nact);
  prep_enc<<<512,256,0,stream>>>(features, sidx, enc, meanb);
  emb_gather<<<320,256,0,stream>>>(captions, sidx, embW, embb);
  transpose_bf16<<<dim3(8,32),256,0,stream>>>(We,    wet,              2048, 512);
  transpose_bf16<<<dim3(32,8),256,0,stream>>>(Wbeta, wmisc,            512, 2048);
  transpose_bf16<<<dim3(8,8), 256,0,stream>>>(Wd,    wmisc + 2048*512, 512, 512);
  transpose_bf16<<<dim3(8,32),256,0,stream>>>(Wh0,   whc,              2048, 512);
  transpose_bf16<<<dim3(8,32),256,0,stream>>>(Wc0,   whc + 512*2048,   2048, 512);
  transpose_bf16<<<dim3(500,8),256,0,stream>>>(Wout, woutt,            512, 32000);
  build_wcat2<<<2560,256,0,stream>>>(Wih, Whh, wcat2);
  build_wihe<<<512,256,0,stream>>>(Wih, wihe);
  build_bias<<<22,256,0,stream>>>(bih,bhh,bbeta,bd,bh0,bc0,bstat,bmisc,bhc);

  // h0/c0 : mean @ [Wh0|Wc0] -> xh20[0] h-half + c (flushed at kernel end)
  { EpiParams ep{}; ep.bias0 = bhc; ep.xh = xh20; ep.c = cbuf;
    gemm_bt<64,64,EPI_H0C0,false,0><<<dim3(16,1),256,0,stream>>>(meanb, 2048, whc, 2048, 2048, ep); }
  // att1 = enc @ We + be  (bf16 out)
  { EpiParams ep{}; ep.outb = att1; ep.ldo = 512; ep.bias0 = be;
    gemm_bt<128,128,EPI_BF16,true,0><<<dim3(98,4),256,0,stream>>>(enc, 2048, wet, 2048, 2048, ep); }
  // g_static = emb @ Wih_e^T + bih + bhh (permuted cols)
  { EpiParams ep{}; ep.out0 = gst; ep.ldo = 2048; ep.bias0 = bstat;
    gemm_bt<128,64,EPI_F32,false,0><<<dim3(32,10),256,0,stream>>>(embb, 512, wihe, 512, 512, ep); }

  // ---- 20 fused sequential steps (cooperative, 256 blocks x 512 thr) ----
  {
    FusedArgs fa;
    fa.att1 = att1; fa.enc = enc; fa.wmisc = wmisc; fa.wcat2 = wcat2;
    fa.gst = gst; fa.wf = wf; fa.bfp = bfp; fa.declen = declen; fa.bmisc = bmisc;
    fa.nact = nact;
    fa.xh20 = xh20; fa.y0p = y0p;
    fa.part = part; fa.cnt = cnt; fa.c = cbuf; fa.hall = hall;
    fa.alph = outAlph; fa.bar = bar;
    void* kargs[1] = { &fa };
    hipLaunchCooperativeKernel((const void*)steps_fused, dim3(256), dim3(512),
                               kargs, 0, stream);
  }

  // ---- batched predictions: h_all @ Wout + bout, masked rows skipped ----
  { EpiParams ep{}; ep.out0 = outP; ep.bias0 = bout; ep.declen = declen;
    gemm_bt<128,128,EPI_PREDS,false,10><<<2500,256,0,stream>>>(hall, 512, woutt, 512, 512, ep); }
}

// Round 15
// 1285.579 us; speedup vs baseline: 2.1574x; 1.1936x over previous
//
#include <hip/hip_runtime.h>
#include <stdint.h>

// ---------- types / helpers ----------
typedef short s16x8 __attribute__((ext_vector_type(8)));
typedef short s16x4 __attribute__((ext_vector_type(4)));
typedef float f32x4 __attribute__((ext_vector_type(4)));
typedef unsigned short u16;
typedef unsigned int u32;

#define DEV __device__ __forceinline__

DEV float bf2f(u16 v){ union{float f; unsigned u;} x; x.u = ((unsigned)v)<<16; return x.f; }
DEV u16 f2bf(float f){ union{float f; unsigned u;} x; x.f = f; unsigned r = x.u + 0x7fffu + ((x.u>>16)&1u); return (u16)(r>>16); }
DEV float sigm(float x){ return 1.f/(1.f + __expf(-x)); }

// coherence-point (L2-bypassing) accessors: RELAXED atomics at agent scope
DEV u32  aL(const u32* p){ return __hip_atomic_load(p, __ATOMIC_RELAXED, __HIP_MEMORY_SCOPE_AGENT); }
DEV void aS(u32* p, u32 v){ __hip_atomic_store(p, v, __ATOMIC_RELAXED, __HIP_MEMORY_SCOPE_AGENT); }
DEV float aLf(const float* p){ return __hip_atomic_load(p, __ATOMIC_RELAXED, __HIP_MEMORY_SCOPE_AGENT); }
DEV void aSf(float* p, float v){ __hip_atomic_store(p, v, __ATOMIC_RELAXED, __HIP_MEMORY_SCOPE_AGENT); }

// B=64, P=196, D=2048, E=512, H=512, A=512, V=32000, S=22, T=20

enum { EPI_F32=0, EPI_BF16=1, EPI_H0C0=2, EPI_PREDS=3 };

struct EpiParams {
  float* out0; long ldo;
  u16* outb;
  const float* bias0;
  const int* declen;
  float* c; u16* xh;
};

// ---------- generic MFMA GEMM: C[M][N] = A[M][K](bf16) * B[N][K](bf16)^T ----------
template<int BM, int BN, int EPI, bool SWAPXY, int SWZM>
__global__ __launch_bounds__(256) void gemm_bt(
    const u16* __restrict__ A, long lda,
    const u16* __restrict__ B, long ldb,
    int K, EpiParams ep)
{
  constexpr int MF = BM/64;
  constexpr int NF = BN/16;
  constexpr int CHA = BM*8, CH = CHA + BN*8;
  constexpr int NST = CH/256;
  __shared__ char smem[(BM+BN)*128];
  const int tid = threadIdx.x;
  const int w = tid>>6, lane = tid&63;

  long arow0, brow0;
  if constexpr (SWZM > 0) {
    int id = blockIdx.x, tot = gridDim.x;
    int q = tot>>3, r = tot&7, xcd = id&7, idx = id>>3;
    int cid = (xcd<r) ? xcd*(q+1)+idx : r*(q+1)+(xcd-r)*q+idx;
    arow0 = (long)(cid % SWZM)*BM; brow0 = (long)(cid / SWZM)*BN;
  } else if constexpr (SWAPXY) { arow0 = (long)blockIdx.x*BM; brow0 = (long)blockIdx.y*BN; }
  else { arow0 = (long)blockIdx.y*BM; brow0 = (long)blockIdx.x*BN; }

  const u16* gsrc[NST]; int ldst[NST];
  #pragma unroll
  for (int i=0;i<NST;++i){
    int c = i*256 + tid;
    if (i*256 < CHA){
      int row = c>>3, k16 = c&7;
      gsrc[i] = A + (arow0+row)*lda + k16*8;
      ldst[i] = row*128 + ((k16*16) ^ ((row&7)<<4));
    } else {
      int cb = c - CHA; int row = cb>>3, k16 = cb&7;
      gsrc[i] = B + (brow0+row)*ldb + k16*8;
      ldst[i] = BM*128 + row*128 + ((k16*16) ^ ((row&7)<<4));
    }
  }

  f32x4 acc[MF][NF];
  #pragma unroll
  for (int i=0;i<MF;++i)
    #pragma unroll
    for (int j=0;j<NF;++j) acc[i][j] = (f32x4){0.f,0.f,0.f,0.f};

  const int KT = K >> 6;
  s16x8 st[NST];
  #pragma unroll
  for (int i=0;i<NST;++i) st[i] = *(const s16x8*)(gsrc[i]);

  char* Al = smem;
  for (int kk=0; kk<KT; ++kk){
    #pragma unroll
    for (int i=0;i<NST;++i) *(s16x8*)(smem + ldst[i]) = st[i];
    __syncthreads();
    if (kk+1 < KT){
      long kb = (long)(kk+1)*64;
      #pragma unroll
      for (int i=0;i<NST;++i) st[i] = *(const s16x8*)(gsrc[i] + kb);
    }
    #pragma unroll
    for (int ks = 0; ks < 2; ++ks) {
      s16x8 af[MF], bfr[NF];
      const int kboff = ks*64 + ((lane>>4)<<4);
      #pragma unroll
      for (int mf=0; mf<MF; ++mf) {
        int r = w*(16*MF) + mf*16 + (lane&15);
        af[mf] = *(const s16x8*)(Al + r*128 + (kboff ^ ((r&7)<<4)));
      }
      #pragma unroll
      for (int nf=0; nf<NF; ++nf) {
        int r = nf*16 + (lane&15);
        bfr[nf] = *(const s16x8*)(Al + BM*128 + r*128 + (kboff ^ ((r&7)<<4)));
      }
      #pragma unroll
      for (int mf=0; mf<MF; ++mf)
        #pragma unroll
        for (int nf=0; nf<NF; ++nf)
          acc[mf][nf] = __builtin_amdgcn_mfma_f32_16x16x32_bf16(bfr[nf], af[mf], acc[mf][nf], 0,0,0);
    }
    __syncthreads();
  }

  #pragma unroll
  for (int mf=0; mf<MF; ++mf)
    #pragma unroll
    for (int nf=0; nf<NF; ++nf){
      long m = arow0 + w*(16*MF) + mf*16 + (lane&15);
      long n0 = brow0 + nf*16 + ((lane>>4)<<2);
      f32x4 bv = *(const f32x4*)&ep.bias0[n0];
      f32x4 v = acc[mf][nf] + bv;
      if constexpr (EPI == EPI_F32) {
        *(f32x4*)&ep.out0[m*ep.ldo + n0] = v;
      } else if constexpr (EPI == EPI_BF16) {
        u16 o[4];
        #pragma unroll
        for (int r=0;r<4;++r) o[r] = f2bf(v[r]);
        *(s16x4*)&ep.outb[m*ep.ldo + n0] = *(s16x4*)o;
      } else if constexpr (EPI == EPI_H0C0) {
        if (n0 < 512){
          u16 o[4];
          #pragma unroll
          for (int r=0;r<4;++r) o[r] = f2bf(v[r]);
          *(s16x4*)&ep.xh[m*2560 + 2048 + n0] = *(s16x4*)o;
        } else {
          *(f32x4*)&ep.c[m*512 + (n0-512)] = v;
        }
      } else { // EPI_PREDS: skip masked rows entirely
        int tt = (int)(m>>6), b = (int)(m&63);
        if (ep.declen[b] > tt)
          *(f32x4*)&ep.out0[(long)b*640000 + (long)tt*32000 + n0] = v;
      }
    }
}

// ---------- fence-free grid barrier (256 blocks) ----------
DEV void gsync(u32* flags, u32* epochw, u32 ep, int blk, int tid){
  __syncthreads();
  if (blk == 0){
    if (tid == 0) aS(flags, ep);
    if (tid < 256){
      while (aL(flags + tid*16) < ep) __builtin_amdgcn_s_sleep(4);
    }
    __syncthreads();
    if (tid == 0) aS(epochw, ep);
  } else {
    if (tid == 0){
      aS(flags + blk*16, ep);
      while (aL(epochw) < ep) __builtin_amdgcn_s_sleep(8);
    }
    __syncthreads();
  }
}

// ---------- fused 20-step decoder loop (cooperative, 256 blocks x 512 thr) ----------
// EXACT Round-11 configuration (best measured: ~1060 us).
struct FusedArgs {
  const u16* att1; const u16* enc;
  const u16* wmisc; const u16* wcat2;
  const float* gst; const float* wf; const float* bfp;
  const int* declen; const float* bmisc; const int* nact;
  u16* xh20; float* y0p;
  float* part; int* cnt; float* c; u16* hall;
  float* alph; u32* bar;
};

__global__ __launch_bounds__(512) void steps_fused(FusedArgs fa)
{
  __shared__ char smem[61440];
  __shared__ float wred[8];
  __shared__ int lastf;
  const int blk = blockIdx.x, tid = threadIdx.x;
  const int w = tid>>6, lane = tid&63;
  const int mstrip = w>>1, nhalf = w&1;
  u32* flags = fa.bar;
  u32* epochw = fa.bar + 4096;
  u32 ep = 0;

  for (int t=0; t<20; ++t){
    u16* cur = fa.xh20 + (long)t*163840;
    u16* nxt = cur + 163840;
    u32* cur32 = (u32*)cur;
    u32* nxt32 = (u32*)nxt;

    // ---- P1: y0 = h @ [Wbeta^T|Wd^T] : 80 blocks, 64x32 tile, K=512 (2 rounds) ----
    if (blk < 80){
      const int brow0 = blk*32;
      f32x4 acc = {0,0,0,0};
      #pragma unroll
      for (int r=0; r<2; ++r){
        u32 sa[16];
        #pragma unroll
        for (int i=0;i<16;++i){
          int c = i*512 + tid;
          int row = c>>7, kp = c&127;
          sa[i] = *(const u32*)(cur32 + (long)row*1280 + 1024 + r*128 + kp);  // cached
        }
        s16x8 sb[2];
        #pragma unroll
        for (int i=0;i<2;++i){
          int c = i*512 + tid;
          int row = c>>5, k16 = c&31;
          sb[i] = *(const s16x8*)(fa.wmisc + (long)(brow0+row)*512 + r*256 + k16*8);
        }
        #pragma unroll
        for (int i=0;i<16;++i){
          int c = i*512 + tid;
          int row = c>>7, kp = c&127;
          *(u32*)(smem + row*512 + ((kp*4) ^ ((row&7)<<4))) = sa[i];
        }
        #pragma unroll
        for (int i=0;i<2;++i){
          int c = i*512 + tid;
          int row = c>>5, k16 = c&31;
          *(s16x8*)(smem + 32768 + row*512 + ((k16*16) ^ ((row&7)<<4))) = sb[i];
        }
        __syncthreads();
        #pragma unroll
        for (int ks=0; ks<8; ++ks){
          int kboff = ks*64 + ((lane>>4)<<4);
          int ra = mstrip*16 + (lane&15);
          s16x8 af = *(const s16x8*)(smem + ra*512 + (kboff ^ ((ra&7)<<4)));
          int rb = nhalf*16 + (lane&15);
          s16x8 bf = *(const s16x8*)(smem + 32768 + rb*512 + (kboff ^ ((rb&7)<<4)));
          acc = __builtin_amdgcn_mfma_f32_16x16x32_bf16(bf, af, acc, 0,0,0);
        }
        __syncthreads();
      }
      int m = mstrip*16 + (lane&15);
      int n0 = brow0 + nhalf*16 + ((lane>>4)<<2);
      #pragma unroll
      for (int j=0;j<4;++j)
        aSf(fa.y0p + (long)m*2560 + n0 + j, acc[j] + fa.bmisc[n0+j]);
    }
    gsync(flags, epochw, ++ep, blk, tid);

    // ---- P23: b = blk&63 (XCD-consistent), s = blk>>6 ; pruned by nact[t] ----
    {
      const int b = blk & 63, s = blk >> 6;
      const int na = fa.nact[t];
      if (b >= na){
        if (s == 0){
          for (int i=tid; i<196; i+=512)
            fa.alph[((long)b*20 + t)*196 + i] = 0.f;
        }
      } else {
      float* att2p = (float*)smem;           // 8*72
      float* wfp   = att2p + 576;            // 8*72
      float* alps  = wfp + 576;              // 208
      float* awe_p = alps + 208;             // 8*512
      {
        int kg0 = tid>>6, j = tid&63;
        att2p[kg0*72 + j] = aLf(fa.y0p + (long)b*2560 + 2048 + tid);
        wfp[kg0*72 + j]   = fa.wf[tid];
      }
      __syncthreads();
      const float bfv = fa.bfp[0];
      const int pg = lane>>3, kg = lane&7;
      #pragma unroll
      for (int pass=0; pass<4; ++pass){
        int p = pass*64 + w*8 + pg;
        if (p < 196){
          const u16* ap = fa.att1 + (((long)(b*196 + p))<<9) + kg*64;
          float sa = 0.f;
          #pragma unroll
          for (int i=0;i<8;++i){
            s16x8 v = *(const s16x8*)(ap + i*8);
            #pragma unroll
            for (int q=0;q<8;++q){
              float x = bf2f((u16)v[q]) + att2p[kg*72 + i*8 + q];
              x = fmaxf(x, 0.f);
              sa += x * wfp[kg*72 + i*8 + q];
            }
          }
          sa += __shfl_xor(sa, 1);
          sa += __shfl_xor(sa, 2);
          sa += __shfl_xor(sa, 4);
          if (kg == 0) alps[p] = sa + bfv;
        }
      }
      __syncthreads();
      float v = (tid < 196) ? alps[tid] : -3.4e38f;
      float m8 = v;
      #pragma unroll
      for (int off=32; off; off>>=1) m8 = fmaxf(m8, __shfl_xor(m8, off));
      if (lane == 0) wred[w] = m8;
      __syncthreads();
      float mx = wred[0];
      #pragma unroll
      for (int i=1;i<8;++i) mx = fmaxf(mx, wred[i]);
      float e = (tid < 196) ? __expf(v - mx) : 0.f;
      float s8 = e;
      #pragma unroll
      for (int off=32; off; off>>=1) s8 += __shfl_xor(s8, off);
      __syncthreads();
      if (lane == 0) wred[w] = s8;
      __syncthreads();
      float den = wred[0]+wred[1]+wred[2]+wred[3]+wred[4]+wred[5]+wred[6]+wred[7];
      float inv = 1.f/den;
      if (tid < 196){
        float a = e*inv;
        alps[tid] = a;
        if (s==0) fa.alph[((long)b*20 + t)*196 + tid] = (fa.declen[b] > t) ? a : 0.f;
      }
      __syncthreads();
      // awe: 4-deep pipelined, NON-TEMPORAL enc loads
      const int d0 = s*512 + lane*8;
      const u16* ebase = fa.enc + (((long)b*196)<<11) + d0;
      float a8[8] = {0,0,0,0,0,0,0,0};
      int p = w;
      for (; p+24 < 196; p += 32){
        s16x8 e0 = __builtin_nontemporal_load((const s16x8*)(ebase + ((long)p<<11)));
        s16x8 e1 = __builtin_nontemporal_load((const s16x8*)(ebase + ((long)(p+8)<<11)));
        s16x8 e2 = __builtin_nontemporal_load((const s16x8*)(ebase + ((long)(p+16)<<11)));
        s16x8 e3 = __builtin_nontemporal_load((const s16x8*)(ebase + ((long)(p+24)<<11)));
        float a0 = alps[p], a1 = alps[p+8], a2 = alps[p+16], a3 = alps[p+24];
        #pragma unroll
        for (int q=0;q<8;++q) a8[q] += a0*bf2f((u16)e0[q]);
        #pragma unroll
        for (int q=0;q<8;++q) a8[q] += a1*bf2f((u16)e1[q]);
        #pragma unroll
        for (int q=0;q<8;++q) a8[q] += a2*bf2f((u16)e2[q]);
        #pragma unroll
        for (int q=0;q<8;++q) a8[q] += a3*bf2f((u16)e3[q]);
      }
      for (; p < 196; p += 8){
        s16x8 ev = __builtin_nontemporal_load((const s16x8*)(ebase + ((long)p<<11)));
        float a = alps[p];
        #pragma unroll
        for (int q=0;q<8;++q) a8[q] += a*bf2f((u16)ev[q]);
      }
      *(f32x4*)&awe_p[w*512 + lane*8]     = (f32x4){a8[0],a8[1],a8[2],a8[3]};
      *(f32x4*)&awe_p[w*512 + lane*8 + 4] = (f32x4){a8[4],a8[5],a8[6],a8[7]};
      __syncthreads();
      if (tid < 256){
        int c0 = 2*tid;
        float s0 = 0.f, s1 = 0.f;
        #pragma unroll
        for (int g=0; g<8; ++g){ s0 += awe_p[g*512 + c0]; s1 += awe_p[g*512 + c0 + 1]; }
        float g0 = sigm(aLf(fa.y0p + (long)b*2560 + s*512 + c0));
        float g1 = sigm(aLf(fa.y0p + (long)b*2560 + s*512 + c0 + 1));
        u32 pk = (u32)f2bf(g0*s0) | ((u32)f2bf(g1*s1) << 16);
        aS(cur32 + (long)b*1280 + s*256 + tid, pk);
      }
      __syncthreads();
      }
    }
    gsync(flags, epochw, ++ep, blk, tid);

    // ---- P4: ntile = blk&63 (XCD-consistent), split = blk>>6 ; cached x|h reads ----
    {
      const int ntile = blk & 63, split = blk >> 6;
      f32x4 acc = {0,0,0,0};
      #pragma unroll
      for (int r=0; r<2; ++r){
        const int kbw = split*640 + r*320;     // u16 col base
        const int kbd = split*320 + r*160;     // u32 col base
        u32 sa[20];
        #pragma unroll
        for (int i=0;i<20;++i){
          int c = i*512 + tid;
          int row = c/160, kp = c%160;
          sa[i] = *(const u32*)(cur32 + (long)row*1280 + kbd + kp);   // cached
        }
        s16x8 sb[3];
        #pragma unroll
        for (int i=0;i<3;++i){
          int c = i*512 + tid;
          if (c < 1280){
            int row = c/40, k16 = c%40;
            sb[i] = *(const s16x8*)(fa.wcat2 + (long)(ntile*32+row)*2560 + kbw + k16*8);
          }
        }
        #pragma unroll
        for (int i=0;i<20;++i){
          int c = i*512 + tid;
          int row = c/160, kp = c%160;
          *(u32*)(smem + row*640 + ((kp*4) ^ ((row&7)<<4))) = sa[i];
        }
        #pragma unroll
        for (int i=0;i<3;++i){
          int c = i*512 + tid;
          if (c < 1280){
            int row = c/40, k16 = c%40;
            *(s16x8*)(smem + 40960 + row*640 + ((k16*16) ^ ((row&7)<<4))) = sb[i];
          }
        }
        __syncthreads();
        #pragma unroll
        for (int ks=0; ks<10; ++ks){
          int kboff = ks*64 + ((lane>>4)<<4);
          int ra = mstrip*16 + (lane&15);
          s16x8 af = *(const s16x8*)(smem + ra*640 + (kboff ^ ((ra&7)<<4)));
          int rb = nhalf*16 + (lane&15);
          s16x8 bf = *(const s16x8*)(smem + 40960 + rb*640 + (kboff ^ ((rb&7)<<4)));
          acc = __builtin_amdgcn_mfma_f32_16x16x32_bf16(bf, af, acc, 0,0,0);
        }
        __syncthreads();
      }
      {
        float* PS = fa.part + (long)split*(64*2048);
        int m = mstrip*16 + (lane&15);
        int n0 = ntile*32 + nhalf*16 + ((lane>>4)<<2);
        #pragma unroll
        for (int j=0;j<4;++j) aSf(PS + (long)m*2048 + n0 + j, acc[j]);
      }
      __syncthreads();   // drains vmcnt per wave -> part stores globally visible
      if (tid==0){
        int v = __hip_atomic_fetch_add(fa.cnt + t*64 + ntile, 1,
                                       __ATOMIC_RELAXED, __HIP_MEMORY_SCOPE_AGENT);
        lastf = (v == 3);
      }
      __syncthreads();
      if (lastf && tid < 256){
        int b = tid>>2, jp = tid&3;
        u16 h2[2];
        #pragma unroll
        for (int jj=0; jj<2; ++jj){
          int jl = jp*2 + jj;
          int j = ntile*8 + jl;
          float g4[4];
          #pragma unroll
          for (int gi=0; gi<4; ++gi){
            long n = (long)ntile*32 + jl*4 + gi;
            float sg = fa.gst[((long)t*64 + b)*2048 + n];
            #pragma unroll
            for (int sp=0; sp<4; ++sp)
              sg += aLf(fa.part + (long)sp*(64*2048) + (long)b*2048 + n);
            g4[gi] = sg;
          }
          float cc = aLf(fa.c + b*512 + j);
          float cn = sigm(g4[1])*cc + sigm(g4[0])*tanhf(g4[2]);
          float hn = sigm(g4[3])*tanhf(cn);
          aSf(fa.c + b*512 + j, cn);
          h2[jj] = f2bf(hn);
        }
        u32 pk = (u32)h2[0] | ((u32)h2[1] << 16);
        aS(nxt32 + (long)b*1280 + 1024 + ntile*4 + jp, pk);
        *(u32*)&fa.hall[((long)t*64 + b)*512 + ntile*8 + jp*2] = pk;
      }
    }
    if (t < 19) gsync(flags, epochw, ++ep, blk, tid);
  }
}

// ---------- sort + small outputs + counter/barrier/nact init ----------
__global__ void sort_k(const int* __restrict__ cl, const int* __restrict__ captions,
                       int* __restrict__ sidx, int* __restrict__ declen,
                       float* __restrict__ outCaps, float* __restrict__ outLens,
                       float* __restrict__ outSidx, int* __restrict__ cnt,
                       u32* __restrict__ bar, int* __restrict__ nact)
{
  __shared__ int s_idx[64];
  __shared__ int s_dl[64];
  int i = threadIdx.x;
  int li = cl[i];
  int rank = 0;
  for (int j=0;j<64;++j){ int lj = cl[j]; rank += (lj>li) || (lj==li && j<i); }
  s_idx[rank] = i;
  __syncthreads();
  int src = s_idx[i];
  sidx[i] = src;
  int L = cl[src];
  declen[i] = L - 1;
  s_dl[i] = L - 1;
  outLens[i] = (float)L;
  outSidx[i] = (float)src;
  for (int s=0;s<22;++s) outCaps[i*22+s] = (float)captions[s*64 + src];
  for (int s=0;s<20;++s) cnt[s*64 + i] = 0;
  for (int s=i; s<4160; s+=64) bar[s] = 0u;
  __syncthreads();
  if (i < 20){
    int c = 0;
    for (int j=0;j<64;++j) c += (s_dl[j] > i);
    nact[i] = c;
  }
}

// ---------- merged setup: prep_enc + emb_gather + 6 transposes + builds + bias ----------
struct PrepArgs {
  const float* features; const int* captions; const int* sidx;
  const float* embW;
  const float* We; const float* Wbeta; const float* Wd;
  const float* Wh0; const float* Wc0; const float* Wout;
  const float* Wih; const float* Whh;
  const float* bih; const float* bhh; const float* bbeta;
  const float* bd; const float* bh0; const float* bc0;
  u16* enc; u16* meanb; u16* embb;
  u16* wet; u16* wmisc; u16* whc; u16* woutt; u16* wcat2; u16* wihe;
  float* bstat; float* bmisc; float* bhc;
};

DEV void tpose_tile(const float* __restrict__ in, u16* __restrict__ out,
                    int R, int C, int rel, int gx, float (*t)[65], int tid)
{
  const int bx = (rel % gx)*64, by = (rel / gx)*64;
  const int tx = tid & 63, ty = tid >> 6;
  #pragma unroll
  for (int i=0;i<16;++i){ int r = i*4+ty; t[r][tx] = in[(long)(by+r)*C + bx+tx]; }
  __syncthreads();
  #pragma unroll
  for (int i=0;i<16;++i){ int cc = i*4+ty; out[(long)(bx+cc)*R + by+tx] = f2bf(t[tx][cc]); }
}

__global__ __launch_bounds__(256) void mega_prep(PrepArgs pa)
{
  __shared__ float tls[64][65];
  __shared__ float red[4][256];
  const int blk = blockIdx.x, tid = threadIdx.x;

  if (blk < 512){
    // prep_enc: gather sorted enc -> bf16 + per-(b,d) mean
    int b = blk >> 3, oct = blk & 7;
    int lv = tid & 63, g = tid >> 6;
    int d0 = oct*256 + lv*4;
    const float* src = pa.features + (long)pa.sidx[b]*(196*2048) + d0;
    float acc[4] = {0.f,0.f,0.f,0.f};
    for (int p=g; p<196; p+=4){
      f32x4 v = *(const f32x4*)(src + (long)p*2048);
      u16 o[4];
      #pragma unroll
      for (int q=0;q<4;++q){ acc[q] += v[q]; o[q] = f2bf(v[q]); }
      *(s16x4*)(pa.enc + ((long)b*196 + p)*2048 + d0) = *(s16x4*)o;
    }
    #pragma unroll
    for (int q=0;q<4;++q) red[g][lv*4+q] = acc[q];
    __syncthreads();
    if (tid < 64){
      u16 mo[4];
      #pragma unroll
      for (int q=0;q<4;++q){
        float s = red[0][tid*4+q] + red[1][tid*4+q] + red[2][tid*4+q] + red[3][tid*4+q];
        mo[q] = f2bf(s*(1.f/196.f));
      }
      *(s16x4*)(pa.meanb + b*2048 + oct*256 + tid*4) = *(s16x4*)mo;
    }
  } else if (blk < 832){
    // emb_gather
    int idx = (blk-512)*256 + tid;
    int row = idx >> 6; int e0 = (idx & 63)*8;
    int t = row >> 6, b = row & 63;
    int tok = pa.captions[t*64 + pa.sidx[b]];
    const float* s = pa.embW + (long)tok*512 + e0;
    f32x4 v0 = *(const f32x4*)s, v1 = *(const f32x4*)(s+4);
    u16 o[8];
    #pragma unroll
    for (int q=0;q<4;++q){ o[q] = f2bf(v0[q]); o[4+q] = f2bf(v1[q]); }
    *(s16x8*)(pa.embb + (long)row*512 + e0) = *(s16x8*)o;
  } else if (blk < 4832){
    tpose_tile(pa.Wout, pa.woutt, 512, 32000, blk-832, 500, tls, tid);
  } else if (blk < 5088){
    tpose_tile(pa.We, pa.wet, 2048, 512, blk-4832, 8, tls, tid);
  } else if (blk < 5344){
    tpose_tile(pa.Wbeta, pa.wmisc, 512, 2048, blk-5088, 32, tls, tid);
  } else if (blk < 5408){
    tpose_tile(pa.Wd, pa.wmisc + 2048*512, 512, 512, blk-5344, 8, tls, tid);
  } else if (blk < 5664){
    tpose_tile(pa.Wh0, pa.whc, 2048, 512, blk-5408, 8, tls, tid);
  } else if (blk < 5920){
    tpose_tile(pa.Wc0, pa.whc + 512*2048, 2048, 512, blk-5664, 8, tls, tid);
  } else if (blk < 8480){
    // build_wcat2: perm [Wih_a | Whh]
    long idx = (long)(blk-5920)*256 + tid;
    int r = (int)(idx / 320);
    int kc = (int)(idx % 320) * 8;
    int j = r>>2, g = r&3;
    int orow = g*512 + j;
    const float* s = (kc < 2048) ? (pa.Wih + (long)orow*2560 + 512 + kc)
                                 : (pa.Whh + (long)orow*512 + (kc - 2048));
    f32x4 v0 = *(const f32x4*)s, v1 = *(const f32x4*)(s+4);
    u16 o[8];
    #pragma unroll
    for (int q=0;q<4;++q){ o[q] = f2bf(v0[q]); o[4+q] = f2bf(v1[q]); }
    *(s16x8*)(pa.wcat2 + (long)r*2560 + kc) = *(s16x8*)o;
  } else if (blk < 8992){
    // build_wihe
    int idx = (blk-8480)*256 + tid;
    int r = idx >> 6; int kc = (idx & 63)*8;
    int j = r>>2, g = r&3;
    const float* s = pa.Wih + (long)(g*512+j)*2560 + kc;
    f32x4 v0 = *(const f32x4*)s, v1 = *(const f32x4*)(s+4);
    u16 o[8];
    #pragma unroll
    for (int q=0;q<4;++q){ o[q] = f2bf(v0[q]); o[4+q] = f2bf(v1[q]); }
    *(s16x8*)(pa.wihe + (long)r*512 + kc) = *(s16x8*)o;
  } else {
    // build_bias
    int idx = (blk-8992)*256 + tid;
    if (idx < 2048){ int j = idx>>2, g = idx&3; pa.bstat[idx] = pa.bih[g*512+j] + pa.bhh[g*512+j]; }
    else if (idx < 4608){ int k = idx-2048; pa.bmisc[k] = (k<2048) ? pa.bbeta[k] : pa.bd[k-2048]; }
    else if (idx < 5632){ int k = idx-4608; pa.bhc[k] = (k<512) ? pa.bh0[k] : pa.bc0[k-512]; }
  }
}

// ---------- workspace layout (bytes) ----------
static constexpr long OFF_ENC   = 0;                 // 64*196*2048 bf16
static constexpr long OFF_ATT1  = 51380224;          // 12544*512 bf16
static constexpr long OFF_WOUTT = 64225280;          // 32000*512 bf16
static constexpr long OFF_WET   = 96993280;          // 512*2048 bf16
static constexpr long OFF_WMISC = 99090432;          // 2560*512 bf16 (Wbeta^T ; Wd^T)
static constexpr long OFF_WHC   = 101711872;         // 1024*2048 bf16 -- REUSED as PART
static constexpr long OFF_WCAT2 = 105906176;         // 2048*2560 bf16 (perm [Wih_a|Whh])
static constexpr long OFF_WIHE  = 116391936;         // 2048*512 bf16 (perm Wih_e)
static constexpr long OFF_EMBB  = 118489088;         // 1280*512 bf16
static constexpr long OFF_GST   = 119799808;         // 1280*2048 f32
static constexpr long OFF_HALL  = 130285568;         // 1280*512 bf16
static constexpr long OFF_MEANB = 131596288;         // 64*2048 bf16
static constexpr long OFF_C     = 132513792;         // 64*512 f32
static constexpr long OFF_Y0P   = 132644864;         // 64*2560 f32
static constexpr long OFF_BSTAT = 133955584;         // 2048 f32
static constexpr long OFF_BMISC = 133963776;         // 2560 f32
static constexpr long OFF_BHC   = 133974016;         // 1024 f32
static constexpr long OFF_SIDX  = 133978112;         // 64 int
static constexpr long OFF_DECL  = 133978368;         // 64 int
static constexpr long OFF_CNT   = 133978624;         // 20*64 int
static constexpr long OFF_BAR   = 133983744;         // 4160 u32
static constexpr long OFF_NACT  = 134000384;         // 20 int
static constexpr long OFF_XH20  = 134017024;         // 21 * 64*2560 bf16 (6.88 MB)
static constexpr long OFF_PART  = OFF_WHC;           // 4*64*2048 f32 (2 MB, after setup)

extern "C" void kernel_launch(void* const* d_in, const int* in_sizes, int n_in,
                              void* d_out, int out_size, void* d_ws, size_t ws_size,
                              hipStream_t stream)
{
  (void)in_sizes; (void)n_in; (void)out_size; (void)ws_size;
  const float* features = (const float*)d_in[0];
  const int*   captions = (const int*)d_in[1];
  const int*   caplen   = (const int*)d_in[2];
  const float* embW     = (const float*)d_in[3];
  const float* We       = (const float*)d_in[4];
  const float* be       = (const float*)d_in[5];
  const float* Wd       = (const float*)d_in[6];
  const float* bd       = (const float*)d_in[7];
  const float* wf       = (const float*)d_in[8];
  const float* bfp      = (const float*)d_in[9];
  const float* Wih      = (const float*)d_in[10];
  const float* Whh      = (const float*)d_in[11];
  const float* bih      = (const float*)d_in[12];
  const float* bhh      = (const float*)d_in[13];
  const float* Wh0      = (const float*)d_in[14];
  const float* bh0      = (const float*)d_in[15];
  const float* Wc0      = (const float*)d_in[16];
  const float* bc0      = (const float*)d_in[17];
  const float* Wbeta    = (const float*)d_in[18];
  const float* bbeta    = (const float*)d_in[19];
  const float* Wout     = (const float*)d_in[20];
  const float* bout     = (const float*)d_in[21];

  char* ws = (char*)d_ws;
  u16*   enc   = (u16*)(ws + OFF_ENC);
  u16*   att1  = (u16*)(ws + OFF_ATT1);
  u16*   woutt = (u16*)(ws + OFF_WOUTT);
  u16*   wet   = (u16*)(ws + OFF_WET);
  u16*   wmisc = (u16*)(ws + OFF_WMISC);
  u16*   whc   = (u16*)(ws + OFF_WHC);
  u16*   wcat2 = (u16*)(ws + OFF_WCAT2);
  u16*   wihe  = (u16*)(ws + OFF_WIHE);
  u16*   embb  = (u16*)(ws + OFF_EMBB);
  float* gst   = (float*)(ws + OFF_GST);
  u16*   hall  = (u16*)(ws + OFF_HALL);
  u16*   meanb = (u16*)(ws + OFF_MEANB);
  float* cbuf  = (float*)(ws + OFF_C);
  float* y0p   = (float*)(ws + OFF_Y0P);
  float* bstat = (float*)(ws + OFF_BSTAT);
  float* bmisc = (float*)(ws + OFF_BMISC);
  float* bhc   = (float*)(ws + OFF_BHC);
  int*   sidx  = (int*)(ws + OFF_SIDX);
  int*   declen= (int*)(ws + OFF_DECL);
  int*   cnt   = (int*)(ws + OFF_CNT);
  u32*   bar   = (u32*)(ws + OFF_BAR);
  int*   nact  = (int*)(ws + OFF_NACT);
  u16*   xh20  = (u16*)(ws + OFF_XH20);
  float* part  = (float*)(ws + OFF_PART);

  float* outP    = (float*)d_out;            // [64][20][32000]
  float* outCaps = outP + 40960000;          // [64][22]
  float* outLens = outCaps + 1408;           // [64]
  float* outAlph = outLens + 64;             // [64][20][196]
  float* outSidx = outAlph + 250880;         // [64]

  // ---- setup: sort, then ONE merged prep kernel ----
  sort_k<<<1,64,0,stream>>>(caplen, captions, sidx, declen, outCaps, outLens, outSidx, cnt, bar, nact);
  {
    PrepArgs pa;
    pa.features = features; pa.captions = captions; pa.sidx = sidx;
    pa.embW = embW;
    pa.We = We; pa.Wbeta = Wbeta; pa.Wd = Wd; pa.Wh0 = Wh0; pa.Wc0 = Wc0; pa.Wout = Wout;
    pa.Wih = Wih; pa.Whh = Whh;
    pa.bih = bih; pa.bhh = bhh; pa.bbeta = bbeta; pa.bd = bd; pa.bh0 = bh0; pa.bc0 = bc0;
    pa.enc = enc; pa.meanb = meanb; pa.embb = embb;
    pa.wet = wet; pa.wmisc = wmisc; pa.whc = whc; pa.woutt = woutt;
    pa.wcat2 = wcat2; pa.wihe = wihe;
    pa.bstat = bstat; pa.bmisc = bmisc; pa.bhc = bhc;
    mega_prep<<<9014,256,0,stream>>>(pa);
  }

  // h0/c0 : mean @ [Wh0|Wc0] -> xh20[0] h-half + c
  { EpiParams ep{}; ep.bias0 = bhc; ep.xh = xh20; ep.c = cbuf;
    gemm_bt<64,64,EPI_H0C0,false,0><<<dim3(16,1),256,0,stream>>>(meanb, 2048, whc, 2048, 2048, ep); }
  // att1 = enc @ We + be  (bf16 out)
  { EpiParams ep{}; ep.outb = att1; ep.ldo = 512; ep.bias0 = be;
    gemm_bt<128,128,EPI_BF16,true,0><<<dim3(98,4),256,0,stream>>>(enc, 2048, wet, 2048, 2048, ep); }
  // g_static = emb @ Wih_e^T + bih + bhh (permuted cols)
  { EpiParams ep{}; ep.out0 = gst; ep.ldo = 2048; ep.bias0 = bstat;
    gemm_bt<128,64,EPI_F32,false,0><<<dim3(32,10),256,0,stream>>>(embb, 512, wihe, 512, 512, ep); }

  // ---- 20 fused sequential steps (cooperative, 256 blocks x 512 thr) ----
  {
    FusedArgs fa;
    fa.att1 = att1; fa.enc = enc; fa.wmisc = wmisc; fa.wcat2 = wcat2;
    fa.gst = gst; fa.wf = wf; fa.bfp = bfp; fa.declen = declen; fa.bmisc = bmisc;
    fa.nact = nact;
    fa.xh20 = xh20; fa.y0p = y0p;
    fa.part = part; fa.cnt = cnt; fa.c = cbuf; fa.hall = hall;
    fa.alph = outAlph; fa.bar = bar;
    void* kargs[1] = { &fa };
    hipLaunchCooperativeKernel((const void*)steps_fused, dim3(256), dim3(512),
                               kargs, 0, stream);
  }

  // ---- batched predictions: h_all @ Wout + bout, masked rows skipped ----
  { EpiParams ep{}; ep.out0 = outP; ep.bias0 = bout; ep.declen = declen;
    gemm_bt<128,128,EPI_PREDS,false,10><<<2500,256,0,stream>>>(hall, 512, woutt, 512, 512, ep); }
}

// Round 16
// 1262.189 us; speedup vs baseline: 2.1974x; 1.0185x over previous
//
#include <hip/hip_runtime.h>
#include <stdint.h>

// ---------- types / helpers ----------
typedef short s16x8 __attribute__((ext_vector_type(8)));
typedef short s16x4 __attribute__((ext_vector_type(4)));
typedef float f32x4 __attribute__((ext_vector_type(4)));
typedef unsigned short u16;
typedef unsigned int u32;

#define DEV __device__ __forceinline__

DEV float bf2f(u16 v){ union{float f; unsigned u;} x; x.u = ((unsigned)v)<<16; return x.f; }
DEV u16 f2bf(float f){ union{float f; unsigned u;} x; x.f = f; unsigned r = x.u + 0x7fffu + ((x.u>>16)&1u); return (u16)(r>>16); }
DEV float sigm(float x){ return 1.f/(1.f + __expf(-x)); }

// coherence-point (L2-bypassing) accessors: RELAXED atomics at agent scope
DEV u32  aL(const u32* p){ return __hip_atomic_load(p, __ATOMIC_RELAXED, __HIP_MEMORY_SCOPE_AGENT); }
DEV void aS(u32* p, u32 v){ __hip_atomic_store(p, v, __ATOMIC_RELAXED, __HIP_MEMORY_SCOPE_AGENT); }
DEV float aLf(const float* p){ return __hip_atomic_load(p, __ATOMIC_RELAXED, __HIP_MEMORY_SCOPE_AGENT); }
DEV void aSf(float* p, float v){ __hip_atomic_store(p, v, __ATOMIC_RELAXED, __HIP_MEMORY_SCOPE_AGENT); }

// B=64, P=196, D=2048, E=512, H=512, A=512, V=32000, S=22, T=20

enum { EPI_F32=0, EPI_BF16=1, EPI_H0C0=2, EPI_PREDS=3 };

struct EpiParams {
  float* out0; long ldo;
  u16* outb;
  const float* bias0;
  const int* declen;
  float* c; u16* xh;
};

// ---------- GEMM core: C[M][N] = A[M][K](bf16) * B[N][K](bf16)^T ----------
template<int BM, int BN, int EPI>
DEV void gemm_core(const u16* __restrict__ A, long lda,
                   const u16* __restrict__ B, long ldb,
                   int K, EpiParams& ep, long arow0, long brow0,
                   char* smem, int tid)
{
  constexpr int MF = BM/64;
  constexpr int NF = BN/16;
  constexpr int CHA = BM*8, CH = CHA + BN*8;
  constexpr int NST = CH/256;
  const int w = tid>>6, lane = tid&63;

  const u16* gsrc[NST]; int ldst[NST];
  #pragma unroll
  for (int i=0;i<NST;++i){
    int c = i*256 + tid;
    if (i*256 < CHA){
      int row = c>>3, k16 = c&7;
      gsrc[i] = A + (arow0+row)*lda + k16*8;
      ldst[i] = row*128 + ((k16*16) ^ ((row&7)<<4));
    } else {
      int cb = c - CHA; int row = cb>>3, k16 = cb&7;
      gsrc[i] = B + (brow0+row)*ldb + k16*8;
      ldst[i] = BM*128 + row*128 + ((k16*16) ^ ((row&7)<<4));
    }
  }

  f32x4 acc[MF][NF];
  #pragma unroll
  for (int i=0;i<MF;++i)
    #pragma unroll
    for (int j=0;j<NF;++j) acc[i][j] = (f32x4){0.f,0.f,0.f,0.f};

  const int KT = K >> 6;
  s16x8 st[NST];
  #pragma unroll
  for (int i=0;i<NST;++i) st[i] = *(const s16x8*)(gsrc[i]);

  char* Al = smem;
  for (int kk=0; kk<KT; ++kk){
    #pragma unroll
    for (int i=0;i<NST;++i) *(s16x8*)(smem + ldst[i]) = st[i];
    __syncthreads();
    if (kk+1 < KT){
      long kb = (long)(kk+1)*64;
      #pragma unroll
      for (int i=0;i<NST;++i) st[i] = *(const s16x8*)(gsrc[i] + kb);
    }
    #pragma unroll
    for (int ks = 0; ks < 2; ++ks) {
      s16x8 af[MF], bfr[NF];
      const int kboff = ks*64 + ((lane>>4)<<4);
      #pragma unroll
      for (int mf=0; mf<MF; ++mf) {
        int r = w*(16*MF) + mf*16 + (lane&15);
        af[mf] = *(const s16x8*)(Al + r*128 + (kboff ^ ((r&7)<<4)));
      }
      #pragma unroll
      for (int nf=0; nf<NF; ++nf) {
        int r = nf*16 + (lane&15);
        bfr[nf] = *(const s16x8*)(Al + BM*128 + r*128 + (kboff ^ ((r&7)<<4)));
      }
      #pragma unroll
      for (int mf=0; mf<MF; ++mf)
        #pragma unroll
        for (int nf=0; nf<NF; ++nf)
          acc[mf][nf] = __builtin_amdgcn_mfma_f32_16x16x32_bf16(bfr[nf], af[mf], acc[mf][nf], 0,0,0);
    }
    __syncthreads();
  }

  #pragma unroll
  for (int mf=0; mf<MF; ++mf)
    #pragma unroll
    for (int nf=0; nf<NF; ++nf){
      long m = arow0 + w*(16*MF) + mf*16 + (lane&15);
      long n0 = brow0 + nf*16 + ((lane>>4)<<2);
      f32x4 bv = *(const f32x4*)&ep.bias0[n0];
      f32x4 v = acc[mf][nf] + bv;
      if constexpr (EPI == EPI_F32) {
        *(f32x4*)&ep.out0[m*ep.ldo + n0] = v;
      } else if constexpr (EPI == EPI_BF16) {
        u16 o[4];
        #pragma unroll
        for (int r=0;r<4;++r) o[r] = f2bf(v[r]);
        *(s16x4*)&ep.outb[m*ep.ldo + n0] = *(s16x4*)o;
      } else if constexpr (EPI == EPI_H0C0) {
        if (n0 < 512){
          u16 o[4];
          #pragma unroll
          for (int r=0;r<4;++r) o[r] = f2bf(v[r]);
          *(s16x4*)&ep.xh[m*2560 + 2048 + n0] = *(s16x4*)o;
        } else {
          *(f32x4*)&ep.c[m*512 + (n0-512)] = v;
        }
      } else { // EPI_PREDS: skip masked rows entirely
        int tt = (int)(m>>6), b = (int)(m&63);
        if (ep.declen[b] > tt)
          *(f32x4*)&ep.out0[(long)b*640000 + (long)tt*32000 + n0] = v;
      }
    }
}

// ---------- preds GEMM kernel (XCD-chunked swizzle) ----------
template<int BM, int BN, int EPI, int SWZM>
__global__ __launch_bounds__(256) void gemm_bt(
    const u16* __restrict__ A, long lda,
    const u16* __restrict__ B, long ldb,
    int K, EpiParams ep)
{
  __shared__ char smem[(BM+BN)*128];
  int id = blockIdx.x, tot = gridDim.x;
  int q = tot>>3, r = tot&7, xcd = id&7, idx = id>>3;
  int cid = (xcd<r) ? xcd*(q+1)+idx : r*(q+1)+(xcd-r)*q+idx;
  long arow0 = (long)(cid % SWZM)*BM, brow0 = (long)(cid / SWZM)*BN;
  gemm_core<BM,BN,EPI>(A, lda, B, ldb, K, ep, arow0, brow0, smem, threadIdx.x);
}

// ---------- merged setup GEMMs: h0c0(16) + att1(392) + gst(320) ----------
__global__ __launch_bounds__(256) void setup_gemms(
    const u16* meanb, const u16* whc,
    const u16* enc, const u16* wet,
    const u16* embb, const u16* wihe,
    u16* xh20, float* cbuf, const float* bhc,
    u16* att1, const float* be,
    float* gst, const float* bstat)
{
  __shared__ char smem[32768];
  const int blk = blockIdx.x, tid = threadIdx.x;
  if (blk < 16){
    EpiParams ep{}; ep.bias0 = bhc; ep.xh = xh20; ep.c = cbuf;
    gemm_core<64,64,EPI_H0C0>(meanb, 2048, whc, 2048, 2048, ep, 0, (long)blk*64, smem, tid);
  } else if (blk < 408){
    int rel = blk - 16;
    EpiParams ep{}; ep.outb = att1; ep.ldo = 512; ep.bias0 = be;
    gemm_core<128,128,EPI_BF16>(enc, 2048, wet, 2048, 2048, ep,
                                (long)(rel % 98)*128, (long)(rel / 98)*128, smem, tid);
  } else {
    int rel = blk - 408;
    EpiParams ep{}; ep.out0 = gst; ep.ldo = 2048; ep.bias0 = bstat;
    gemm_core<128,64,EPI_F32>(embb, 512, wihe, 512, 512, ep,
                              (long)(rel / 32)*128, (long)(rel % 32)*64, smem, tid);
  }
}

// ---------- fence-free grid barrier (256 blocks) ----------
DEV void gsync(u32* flags, u32* epochw, u32 ep, int blk, int tid){
  __syncthreads();
  if (blk == 0){
    if (tid == 0) aS(flags, ep);
    if (tid < 256){
      while (aL(flags + tid*16) < ep) __builtin_amdgcn_s_sleep(4);
    }
    __syncthreads();
    if (tid == 0) aS(epochw, ep);
  } else {
    if (tid == 0){
      aS(flags + blk*16, ep);
      while (aL(epochw) < ep) __builtin_amdgcn_s_sleep(8);
    }
    __syncthreads();
  }
}

// ---------- 512-thread f32->bf16 transpose tile (64x64) ----------
DEV void tpose512(const float* __restrict__ in, u16* __restrict__ out,
                  int R, int C, int rel, int gx, float (*t)[65], int tid)
{
  const int bx = (rel % gx)*64, by = (rel / gx)*64;
  const int tx = tid & 63, ty = tid >> 6;   // ty in [0,8)
  #pragma unroll
  for (int i=0;i<8;++i){ int r = i*8+ty; t[r][tx] = in[(long)(by+r)*C + bx+tx]; }
  __syncthreads();
  #pragma unroll
  for (int i=0;i<8;++i){ int cc = i*8+ty; out[(long)(bx+cc)*R + by+tx] = f2bf(t[tx][cc]); }
  __syncthreads();
}

// ---------- fused 20-step decoder loop (cooperative, 256 blocks x 512 thr) ----------
// EXACT Round-11 step structure; idle P1 blocks (80-255) opportunistically
// transpose Wout tiles (4000 total, done by t~11) in barrier slack.
struct FusedArgs {
  const u16* att1; const u16* enc;
  const u16* wmisc; const u16* wcat2;
  const float* gst; const float* wf; const float* bfp;
  const int* declen; const float* bmisc; const int* nact;
  const float* wout; u16* woutt;
  u16* xh20; float* y0p;
  float* part; int* cnt; float* c; u16* hall;
  float* alph; u32* bar;
};

__global__ __launch_bounds__(512) void steps_fused(FusedArgs fa)
{
  __shared__ char smem[61440];
  __shared__ float wred[8];
  __shared__ int lastf;
  const int blk = blockIdx.x, tid = threadIdx.x;
  const int w = tid>>6, lane = tid&63;
  const int mstrip = w>>1, nhalf = w&1;
  u32* flags = fa.bar;
  u32* epochw = fa.bar + 4096;
  u32 ep = 0;

  for (int t=0; t<20; ++t){
    u16* cur = fa.xh20 + (long)t*163840;
    u16* nxt = cur + 163840;
    u32* cur32 = (u32*)cur;
    u32* nxt32 = (u32*)nxt;

    // ---- P1: y0 = h @ [Wbeta^T|Wd^T] : 80 blocks ; others: Wout transpose ----
    if (blk < 80){
      const int brow0 = blk*32;
      f32x4 acc = {0,0,0,0};
      #pragma unroll
      for (int r=0; r<2; ++r){
        u32 sa[16];
        #pragma unroll
        for (int i=0;i<16;++i){
          int c = i*512 + tid;
          int row = c>>7, kp = c&127;
          sa[i] = *(const u32*)(cur32 + (long)row*1280 + 1024 + r*128 + kp);  // cached
        }
        s16x8 sb[2];
        #pragma unroll
        for (int i=0;i<2;++i){
          int c = i*512 + tid;
          int row = c>>5, k16 = c&31;
          sb[i] = *(const s16x8*)(fa.wmisc + (long)(brow0+row)*512 + r*256 + k16*8);
        }
        #pragma unroll
        for (int i=0;i<16;++i){
          int c = i*512 + tid;
          int row = c>>7, kp = c&127;
          *(u32*)(smem + row*512 + ((kp*4) ^ ((row&7)<<4))) = sa[i];
        }
        #pragma unroll
        for (int i=0;i<2;++i){
          int c = i*512 + tid;
          int row = c>>5, k16 = c&31;
          *(s16x8*)(smem + 32768 + row*512 + ((k16*16) ^ ((row&7)<<4))) = sb[i];
        }
        __syncthreads();
        #pragma unroll
        for (int ks=0; ks<8; ++ks){
          int kboff = ks*64 + ((lane>>4)<<4);
          int ra = mstrip*16 + (lane&15);
          s16x8 af = *(const s16x8*)(smem + ra*512 + (kboff ^ ((ra&7)<<4)));
          int rb = nhalf*16 + (lane&15);
          s16x8 bf = *(const s16x8*)(smem + 32768 + rb*512 + (kboff ^ ((rb&7)<<4)));
          acc = __builtin_amdgcn_mfma_f32_16x16x32_bf16(bf, af, acc, 0,0,0);
        }
        __syncthreads();
      }
      int m = mstrip*16 + (lane&15);
      int n0 = brow0 + nhalf*16 + ((lane>>4)<<2);
      #pragma unroll
      for (int j=0;j<4;++j)
        aSf(fa.y0p + (long)m*2560 + n0 + j, acc[j] + fa.bmisc[n0+j]);
    } else {
      // opportunistic Wout transpose (4000 tiles of 64x64; gx=500)
      float (*tls)[65] = (float(*)[65])smem;
      int base = t*352 + (blk-80)*2;
      #pragma unroll
      for (int k2=0;k2<2;++k2){
        int rel = base + k2;
        if (rel < 4000) tpose512(fa.wout, fa.woutt, 512, 32000, rel, 500, tls, tid);
      }
    }
    gsync(flags, epochw, ++ep, blk, tid);

    // ---- P23: b = blk&63 (XCD-consistent), s = blk>>6 ; pruned by nact[t] ----
    {
      const int b = blk & 63, s = blk >> 6;
      const int na = fa.nact[t];
      if (b >= na){
        if (s == 0){
          for (int i=tid; i<196; i+=512)
            fa.alph[((long)b*20 + t)*196 + i] = 0.f;
        }
      } else {
      float* att2p = (float*)smem;           // 8*72
      float* wfp   = att2p + 576;            // 8*72
      float* alps  = wfp + 576;              // 208
      float* awe_p = alps + 208;             // 8*512
      {
        int kg0 = tid>>6, j = tid&63;
        att2p[kg0*72 + j] = aLf(fa.y0p + (long)b*2560 + 2048 + tid);
        wfp[kg0*72 + j]   = fa.wf[tid];
      }
      __syncthreads();
      const float bfv = fa.bfp[0];
      const int pg = lane>>3, kg = lane&7;
      #pragma unroll
      for (int pass=0; pass<4; ++pass){
        int p = pass*64 + w*8 + pg;
        if (p < 196){
          const u16* ap = fa.att1 + (((long)(b*196 + p))<<9) + kg*64;
          float sa = 0.f;
          #pragma unroll
          for (int i=0;i<8;++i){
            s16x8 v = *(const s16x8*)(ap + i*8);
            #pragma unroll
            for (int q=0;q<8;++q){
              float x = bf2f((u16)v[q]) + att2p[kg*72 + i*8 + q];
              x = fmaxf(x, 0.f);
              sa += x * wfp[kg*72 + i*8 + q];
            }
          }
          sa += __shfl_xor(sa, 1);
          sa += __shfl_xor(sa, 2);
          sa += __shfl_xor(sa, 4);
          if (kg == 0) alps[p] = sa + bfv;
        }
      }
      __syncthreads();
      float v = (tid < 196) ? alps[tid] : -3.4e38f;
      float m8 = v;
      #pragma unroll
      for (int off=32; off; off>>=1) m8 = fmaxf(m8, __shfl_xor(m8, off));
      if (lane == 0) wred[w] = m8;
      __syncthreads();
      float mx = wred[0];
      #pragma unroll
      for (int i=1;i<8;++i) mx = fmaxf(mx, wred[i]);
      float e = (tid < 196) ? __expf(v - mx) : 0.f;
      float s8 = e;
      #pragma unroll
      for (int off=32; off; off>>=1) s8 += __shfl_xor(s8, off);
      __syncthreads();
      if (lane == 0) wred[w] = s8;
      __syncthreads();
      float den = wred[0]+wred[1]+wred[2]+wred[3]+wred[4]+wred[5]+wred[6]+wred[7];
      float inv = 1.f/den;
      if (tid < 196){
        float a = e*inv;
        alps[tid] = a;
        if (s==0) fa.alph[((long)b*20 + t)*196 + tid] = (fa.declen[b] > t) ? a : 0.f;
      }
      __syncthreads();
      // awe: 4-deep pipelined, NON-TEMPORAL enc loads
      const int d0 = s*512 + lane*8;
      const u16* ebase = fa.enc + (((long)b*196)<<11) + d0;
      float a8[8] = {0,0,0,0,0,0,0,0};
      int p = w;
      for (; p+24 < 196; p += 32){
        s16x8 e0 = __builtin_nontemporal_load((const s16x8*)(ebase + ((long)p<<11)));
        s16x8 e1 = __builtin_nontemporal_load((const s16x8*)(ebase + ((long)(p+8)<<11)));
        s16x8 e2 = __builtin_nontemporal_load((const s16x8*)(ebase + ((long)(p+16)<<11)));
        s16x8 e3 = __builtin_nontemporal_load((const s16x8*)(ebase + ((long)(p+24)<<11)));
        float a0 = alps[p], a1 = alps[p+8], a2 = alps[p+16], a3 = alps[p+24];
        #pragma unroll
        for (int q=0;q<8;++q) a8[q] += a0*bf2f((u16)e0[q]);
        #pragma unroll
        for (int q=0;q<8;++q) a8[q] += a1*bf2f((u16)e1[q]);
        #pragma unroll
        for (int q=0;q<8;++q) a8[q] += a2*bf2f((u16)e2[q]);
        #pragma unroll
        for (int q=0;q<8;++q) a8[q] += a3*bf2f((u16)e3[q]);
      }
      for (; p < 196; p += 8){
        s16x8 ev = __builtin_nontemporal_load((const s16x8*)(ebase + ((long)p<<11)));
        float a = alps[p];
        #pragma unroll
        for (int q=0;q<8;++q) a8[q] += a*bf2f((u16)ev[q]);
      }
      *(f32x4*)&awe_p[w*512 + lane*8]     = (f32x4){a8[0],a8[1],a8[2],a8[3]};
      *(f32x4*)&awe_p[w*512 + lane*8 + 4] = (f32x4){a8[4],a8[5],a8[6],a8[7]};
      __syncthreads();
      if (tid < 256){
        int c0 = 2*tid;
        float s0 = 0.f, s1 = 0.f;
        #pragma unroll
        for (int g=0; g<8; ++g){ s0 += awe_p[g*512 + c0]; s1 += awe_p[g*512 + c0 + 1]; }
        float g0 = sigm(aLf(fa.y0p + (long)b*2560 + s*512 + c0));
        float g1 = sigm(aLf(fa.y0p + (long)b*2560 + s*512 + c0 + 1));
        u32 pk = (u32)f2bf(g0*s0) | ((u32)f2bf(g1*s1) << 16);
        aS(cur32 + (long)b*1280 + s*256 + tid, pk);
      }
      __syncthreads();
      }
    }
    gsync(flags, epochw, ++ep, blk, tid);

    // ---- P4: ntile = blk&63 (XCD-consistent), split = blk>>6 ; cached x|h reads ----
    {
      const int ntile = blk & 63, split = blk >> 6;
      f32x4 acc = {0,0,0,0};
      #pragma unroll
      for (int r=0; r<2; ++r){
        const int kbw = split*640 + r*320;     // u16 col base
        const int kbd = split*320 + r*160;     // u32 col base
        u32 sa[20];
        #pragma unroll
        for (int i=0;i<20;++i){
          int c = i*512 + tid;
          int row = c/160, kp = c%160;
          sa[i] = *(const u32*)(cur32 + (long)row*1280 + kbd + kp);   // cached
        }
        s16x8 sb[3];
        #pragma unroll
        for (int i=0;i<3;++i){
          int c = i*512 + tid;
          if (c < 1280){
            int row = c/40, k16 = c%40;
            sb[i] = *(const s16x8*)(fa.wcat2 + (long)(ntile*32+row)*2560 + kbw + k16*8);
          }
        }
        #pragma unroll
        for (int i=0;i<20;++i){
          int c = i*512 + tid;
          int row = c/160, kp = c%160;
          *(u32*)(smem + row*640 + ((kp*4) ^ ((row&7)<<4))) = sa[i];
        }
        #pragma unroll
        for (int i=0;i<3;++i){
          int c = i*512 + tid;
          if (c < 1280){
            int row = c/40, k16 = c%40;
            *(s16x8*)(smem + 40960 + row*640 + ((k16*16) ^ ((row&7)<<4))) = sb[i];
          }
        }
        __syncthreads();
        #pragma unroll
        for (int ks=0; ks<10; ++ks){
          int kboff = ks*64 + ((lane>>4)<<4);
          int ra = mstrip*16 + (lane&15);
          s16x8 af = *(const s16x8*)(smem + ra*640 + (kboff ^ ((ra&7)<<4)));
          int rb = nhalf*16 + (lane&15);
          s16x8 bf = *(const s16x8*)(smem + 40960 + rb*640 + (kboff ^ ((rb&7)<<4)));
          acc = __builtin_amdgcn_mfma_f32_16x16x32_bf16(bf, af, acc, 0,0,0);
        }
        __syncthreads();
      }
      {
        float* PS = fa.part + (long)split*(64*2048);
        int m = mstrip*16 + (lane&15);
        int n0 = ntile*32 + nhalf*16 + ((lane>>4)<<2);
        #pragma unroll
        for (int j=0;j<4;++j) aSf(PS + (long)m*2048 + n0 + j, acc[j]);
      }
      __syncthreads();   // drains vmcnt per wave -> part stores globally visible
      if (tid==0){
        int v = __hip_atomic_fetch_add(fa.cnt + t*64 + ntile, 1,
                                       __ATOMIC_RELAXED, __HIP_MEMORY_SCOPE_AGENT);
        lastf = (v == 3);
      }
      __syncthreads();
      if (lastf && tid < 256){
        int b = tid>>2, jp = tid&3;
        u16 h2[2];
        #pragma unroll
        for (int jj=0; jj<2; ++jj){
          int jl = jp*2 + jj;
          int j = ntile*8 + jl;
          float g4[4];
          #pragma unroll
          for (int gi=0; gi<4; ++gi){
            long n = (long)ntile*32 + jl*4 + gi;
            float sg = fa.gst[((long)t*64 + b)*2048 + n];
            #pragma unroll
            for (int sp=0; sp<4; ++sp)
              sg += aLf(fa.part + (long)sp*(64*2048) + (long)b*2048 + n);
            g4[gi] = sg;
          }
          float cc = aLf(fa.c + b*512 + j);
          float cn = sigm(g4[1])*cc + sigm(g4[0])*tanhf(g4[2]);
          float hn = sigm(g4[3])*tanhf(cn);
          aSf(fa.c + b*512 + j, cn);
          h2[jj] = f2bf(hn);
        }
        u32 pk = (u32)h2[0] | ((u32)h2[1] << 16);
        aS(nxt32 + (long)b*1280 + 1024 + ntile*4 + jp, pk);
        *(u32*)&fa.hall[((long)t*64 + b)*512 + ntile*8 + jp*2] = pk;
      }
    }
    if (t < 19) gsync(flags, epochw, ++ep, blk, tid);
  }
}

// ---------- sort + small outputs + counter/barrier/nact init ----------
__global__ void sort_k(const int* __restrict__ cl, const int* __restrict__ captions,
                       int* __restrict__ sidx, int* __restrict__ declen,
                       float* __restrict__ outCaps, float* __restrict__ outLens,
                       float* __restrict__ outSidx, int* __restrict__ cnt,
                       u32* __restrict__ bar, int* __restrict__ nact)
{
  __shared__ int s_idx[64];
  __shared__ int s_dl[64];
  int i = threadIdx.x;
  int li = cl[i];
  int rank = 0;
  for (int j=0;j<64;++j){ int lj = cl[j]; rank += (lj>li) || (lj==li && j<i); }
  s_idx[rank] = i;
  __syncthreads();
  int src = s_idx[i];
  sidx[i] = src;
  int L = cl[src];
  declen[i] = L - 1;
  s_dl[i] = L - 1;
  outLens[i] = (float)L;
  outSidx[i] = (float)src;
  for (int s=0;s<22;++s) outCaps[i*22+s] = (float)captions[s*64 + src];
  for (int s=0;s<20;++s) cnt[s*64 + i] = 0;
  for (int s=i; s<4160; s+=64) bar[s] = 0u;
  __syncthreads();
  if (i < 20){
    int c = 0;
    for (int j=0;j<64;++j) c += (s_dl[j] > i);
    nact[i] = c;
  }
}

// ---------- merged setup (minus Wout transpose): 5014 blocks ----------
struct PrepArgs {
  const float* features; const int* captions; const int* sidx;
  const float* embW;
  const float* We; const float* Wbeta; const float* Wd;
  const float* Wh0; const float* Wc0;
  const float* Wih; const float* Whh;
  const float* bih; const float* bhh; const float* bbeta;
  const float* bd; const float* bh0; const float* bc0;
  u16* enc; u16* meanb; u16* embb;
  u16* wet; u16* wmisc; u16* whc; u16* wcat2; u16* wihe;
  float* bstat; float* bmisc; float* bhc;
};

DEV void tpose_tile(const float* __restrict__ in, u16* __restrict__ out,
                    int R, int C, int rel, int gx, float (*t)[65], int tid)
{
  const int bx = (rel % gx)*64, by = (rel / gx)*64;
  const int tx = tid & 63, ty = tid >> 6;
  #pragma unroll
  for (int i=0;i<16;++i){ int r = i*4+ty; t[r][tx] = in[(long)(by+r)*C + bx+tx]; }
  __syncthreads();
  #pragma unroll
  for (int i=0;i<16;++i){ int cc = i*4+ty; out[(long)(bx+cc)*R + by+tx] = f2bf(t[tx][cc]); }
}

__global__ __launch_bounds__(256) void mega_prep(PrepArgs pa)
{
  __shared__ float tls[64][65];
  __shared__ float red[4][256];
  const int blk = blockIdx.x, tid = threadIdx.x;

  if (blk < 512){
    int b = blk >> 3, oct = blk & 7;
    int lv = tid & 63, g = tid >> 6;
    int d0 = oct*256 + lv*4;
    const float* src = pa.features + (long)pa.sidx[b]*(196*2048) + d0;
    float acc[4] = {0.f,0.f,0.f,0.f};
    for (int p=g; p<196; p+=4){
      f32x4 v = *(const f32x4*)(src + (long)p*2048);
      u16 o[4];
      #pragma unroll
      for (int q=0;q<4;++q){ acc[q] += v[q]; o[q] = f2bf(v[q]); }
      *(s16x4*)(pa.enc + ((long)b*196 + p)*2048 + d0) = *(s16x4*)o;
    }
    #pragma unroll
    for (int q=0;q<4;++q) red[g][lv*4+q] = acc[q];
    __syncthreads();
    if (tid < 64){
      u16 mo[4];
      #pragma unroll
      for (int q=0;q<4;++q){
        float s = red[0][tid*4+q] + red[1][tid*4+q] + red[2][tid*4+q] + red[3][tid*4+q];
        mo[q] = f2bf(s*(1.f/196.f));
      }
      *(s16x4*)(pa.meanb + b*2048 + oct*256 + tid*4) = *(s16x4*)mo;
    }
  } else if (blk < 832){
    int idx = (blk-512)*256 + tid;
    int row = idx >> 6; int e0 = (idx & 63)*8;
    int t = row >> 6, b = row & 63;
    int tok = pa.captions[t*64 + pa.sidx[b]];
    const float* s = pa.embW + (long)tok*512 + e0;
    f32x4 v0 = *(const f32x4*)s, v1 = *(const f32x4*)(s+4);
    u16 o[8];
    #pragma unroll
    for (int q=0;q<4;++q){ o[q] = f2bf(v0[q]); o[4+q] = f2bf(v1[q]); }
    *(s16x8*)(pa.embb + (long)row*512 + e0) = *(s16x8*)o;
  } else if (blk < 1088){
    tpose_tile(pa.We, pa.wet, 2048, 512, blk-832, 8, tls, tid);
  } else if (blk < 1344){
    tpose_tile(pa.Wbeta, pa.wmisc, 512, 2048, blk-1088, 32, tls, tid);
  } else if (blk < 1408){
    tpose_tile(pa.Wd, pa.wmisc + 2048*512, 512, 512, blk-1344, 8, tls, tid);
  } else if (blk < 1664){
    tpose_tile(pa.Wh0, pa.whc, 2048, 512, blk-1408, 8, tls, tid);
  } else if (blk < 1920){
    tpose_tile(pa.Wc0, pa.whc + 512*2048, 2048, 512, blk-1664, 8, tls, tid);
  } else if (blk < 4480){
    long idx = (long)(blk-1920)*256 + tid;
    int r = (int)(idx / 320);
    int kc = (int)(idx % 320) * 8;
    int j = r>>2, g = r&3;
    int orow = g*512 + j;
    const float* s = (kc < 2048) ? (pa.Wih + (long)orow*2560 + 512 + kc)
                                 : (pa.Whh + (long)orow*512 + (kc - 2048));
    f32x4 v0 = *(const f32x4*)s, v1 = *(const f32x4*)(s+4);
    u16 o[8];
    #pragma unroll
    for (int q=0;q<4;++q){ o[q] = f2bf(v0[q]); o[4+q] = f2bf(v1[q]); }
    *(s16x8*)(pa.wcat2 + (long)r*2560 + kc) = *(s16x8*)o;
  } else if (blk < 4992){
    int idx = (blk-4480)*256 + tid;
    int r = idx >> 6; int kc = (idx & 63)*8;
    int j = r>>2, g = r&3;
    const float* s = pa.Wih + (long)(g*512+j)*2560 + kc;
    f32x4 v0 = *(const f32x4*)s, v1 = *(const f32x4*)(s+4);
    u16 o[8];
    #pragma unroll
    for (int q=0;q<4;++q){ o[q] = f2bf(v0[q]); o[4+q] = f2bf(v1[q]); }
    *(s16x8*)(pa.wihe + (long)r*512 + kc) = *(s16x8*)o;
  } else {
    int idx = (blk-4992)*256 + tid;
    if (idx < 2048){ int j = idx>>2, g = idx&3; pa.bstat[idx] = pa.bih[g*512+j] + pa.bhh[g*512+j]; }
    else if (idx < 4608){ int k = idx-2048; pa.bmisc[k] = (k<2048) ? pa.bbeta[k] : pa.bd[k-2048]; }
    else if (idx < 5632){ int k = idx-4608; pa.bhc[k] = (k<512) ? pa.bh0[k] : pa.bc0[k-512]; }
  }
}

// ---------- workspace layout (bytes) ----------
static constexpr long OFF_ENC   = 0;                 // 64*196*2048 bf16
static constexpr long OFF_ATT1  = 51380224;          // 12544*512 bf16
static constexpr long OFF_WOUTT = 64225280;          // 32000*512 bf16
static constexpr long OFF_WET   = 96993280;          // 512*2048 bf16
static constexpr long OFF_WMISC = 99090432;          // 2560*512 bf16 (Wbeta^T ; Wd^T)
static constexpr long OFF_WHC   = 101711872;         // 1024*2048 bf16 -- REUSED as PART
static constexpr long OFF_WCAT2 = 105906176;         // 2048*2560 bf16 (perm [Wih_a|Whh])
static constexpr long OFF_WIHE  = 116391936;         // 2048*512 bf16 (perm Wih_e)
static constexpr long OFF_EMBB  = 118489088;         // 1280*512 bf16
static constexpr long OFF_GST   = 119799808;         // 1280*2048 f32
static constexpr long OFF_HALL  = 130285568;         // 1280*512 bf16
static constexpr long OFF_MEANB = 131596288;         // 64*2048 bf16
static constexpr long OFF_C     = 132513792;         // 64*512 f32
static constexpr long OFF_Y0P   = 132644864;         // 64*2560 f32
static constexpr long OFF_BSTAT = 133955584;         // 2048 f32
static constexpr long OFF_BMISC = 133963776;         // 2560 f32
static constexpr long OFF_BHC   = 133974016;         // 1024 f32
static constexpr long OFF_SIDX  = 133978112;         // 64 int
static constexpr long OFF_DECL  = 133978368;         // 64 int
static constexpr long OFF_CNT   = 133978624;         // 20*64 int
static constexpr long OFF_BAR   = 133983744;         // 4160 u32
static constexpr long OFF_NACT  = 134000384;         // 20 int
static constexpr long OFF_XH20  = 134017024;         // 21 * 64*2560 bf16 (6.88 MB)
static constexpr long OFF_PART  = OFF_WHC;           // 4*64*2048 f32 (2 MB, after setup)

extern "C" void kernel_launch(void* const* d_in, const int* in_sizes, int n_in,
                              void* d_out, int out_size, void* d_ws, size_t ws_size,
                              hipStream_t stream)
{
  (void)in_sizes; (void)n_in; (void)out_size; (void)ws_size;
  const float* features = (const float*)d_in[0];
  const int*   captions = (const int*)d_in[1];
  const int*   caplen   = (const int*)d_in[2];
  const float* embW     = (const float*)d_in[3];
  const float* We       = (const float*)d_in[4];
  const float* be       = (const float*)d_in[5];
  const float* Wd       = (const float*)d_in[6];
  const float* bd       = (const float*)d_in[7];
  const float* wf       = (const float*)d_in[8];
  const float* bfp      = (const float*)d_in[9];
  const float* Wih      = (const float*)d_in[10];
  const float* Whh      = (const float*)d_in[11];
  const float* bih      = (const float*)d_in[12];
  const float* bhh      = (const float*)d_in[13];
  const float* Wh0      = (const float*)d_in[14];
  const float* bh0      = (const float*)d_in[15];
  const float* Wc0      = (const float*)d_in[16];
  const float* bc0      = (const float*)d_in[17];
  const float* Wbeta    = (const float*)d_in[18];
  const float* bbeta    = (const float*)d_in[19];
  const float* Wout     = (const float*)d_in[20];
  const float* bout     = (const float*)d_in[21];

  char* ws = (char*)d_ws;
  u16*   enc   = (u16*)(ws + OFF_ENC);
  u16*   att1  = (u16*)(ws + OFF_ATT1);
  u16*   woutt = (u16*)(ws + OFF_WOUTT);
  u16*   wet   = (u16*)(ws + OFF_WET);
  u16*   wmisc = (u16*)(ws + OFF_WMISC);
  u16*   whc   = (u16*)(ws + OFF_WHC);
  u16*   wcat2 = (u16*)(ws + OFF_WCAT2);
  u16*   wihe  = (u16*)(ws + OFF_WIHE);
  u16*   embb  = (u16*)(ws + OFF_EMBB);
  float* gst   = (float*)(ws + OFF_GST);
  u16*   hall  = (u16*)(ws + OFF_HALL);
  u16*   meanb = (u16*)(ws + OFF_MEANB);
  float* cbuf  = (float*)(ws + OFF_C);
  float* y0p   = (float*)(ws + OFF_Y0P);
  float* bstat = (float*)(ws + OFF_BSTAT);
  float* bmisc = (float*)(ws + OFF_BMISC);
  float* bhc   = (float*)(ws + OFF_BHC);
  int*   sidx  = (int*)(ws + OFF_SIDX);
  int*   declen= (int*)(ws + OFF_DECL);
  int*   cnt   = (int*)(ws + OFF_CNT);
  u32*   bar   = (u32*)(ws + OFF_BAR);
  int*   nact  = (int*)(ws + OFF_NACT);
  u16*   xh20  = (u16*)(ws + OFF_XH20);
  float* part  = (float*)(ws + OFF_PART);

  float* outP    = (float*)d_out;            // [64][20][32000]
  float* outCaps = outP + 40960000;          // [64][22]
  float* outLens = outCaps + 1408;           // [64]
  float* outAlph = outLens + 64;             // [64][20][196]
  float* outSidx = outAlph + 250880;         // [64]

  // ---- setup: sort, merged prep (no Wout transpose), merged GEMMs ----
  sort_k<<<1,64,0,stream>>>(caplen, captions, sidx, declen, outCaps, outLens, outSidx, cnt, bar, nact);
  {
    PrepArgs pa;
    pa.features = features; pa.captions = captions; pa.sidx = sidx;
    pa.embW = embW;
    pa.We = We; pa.Wbeta = Wbeta; pa.Wd = Wd; pa.Wh0 = Wh0; pa.Wc0 = Wc0;
    pa.Wih = Wih; pa.Whh = Whh;
    pa.bih = bih; pa.bhh = bhh; pa.bbeta = bbeta; pa.bd = bd; pa.bh0 = bh0; pa.bc0 = bc0;
    pa.enc = enc; pa.meanb = meanb; pa.embb = embb;
    pa.wet = wet; pa.wmisc = wmisc; pa.whc = whc;
    pa.wcat2 = wcat2; pa.wihe = wihe;
    pa.bstat = bstat; pa.bmisc = bmisc; pa.bhc = bhc;
    mega_prep<<<5014,256,0,stream>>>(pa);
  }
  setup_gemms<<<728,256,0,stream>>>(meanb, whc, enc, wet, embb, wihe,
                                    xh20, cbuf, bhc, att1, be, gst, bstat);

  // ---- 20 fused sequential steps (cooperative, 256 blocks x 512 thr) ----
  {
    FusedArgs fa;
    fa.att1 = att1; fa.enc = enc; fa.wmisc = wmisc; fa.wcat2 = wcat2;
    fa.gst = gst; fa.wf = wf; fa.bfp = bfp; fa.declen = declen; fa.bmisc = bmisc;
    fa.nact = nact;
    fa.wout = Wout; fa.woutt = woutt;
    fa.xh20 = xh20; fa.y0p = y0p;
    fa.part = part; fa.cnt = cnt; fa.c = cbuf; fa.hall = hall;
    fa.alph = outAlph; fa.bar = bar;
    void* kargs[1] = { &fa };
    hipLaunchCooperativeKernel((const void*)steps_fused, dim3(256), dim3(512),
                               kargs, 0, stream);
  }

  // ---- batched predictions: h_all @ Wout + bout, masked rows skipped ----
  { EpiParams ep{}; ep.out0 = outP; ep.bias0 = bout; ep.declen = declen;
    gemm_bt<128,128,EPI_PREDS,10><<<2500,256,0,stream>>>(hall, 512, woutt, 512, 512, ep); }
}

// Round 17
// 1252.944 us; speedup vs baseline: 2.2136x; 1.0074x over previous
//
#include <hip/hip_runtime.h>
#include <stdint.h>

// ---------- types / helpers ----------
typedef short s16x8 __attribute__((ext_vector_type(8)));
typedef short s16x4 __attribute__((ext_vector_type(4)));
typedef float f32x4 __attribute__((ext_vector_type(4)));
typedef unsigned short u16;
typedef unsigned int u32;

#define DEV __device__ __forceinline__

DEV float bf2f(u16 v){ union{float f; unsigned u;} x; x.u = ((unsigned)v)<<16; return x.f; }
DEV u16 f2bf(float f){ union{float f; unsigned u;} x; x.f = f; unsigned r = x.u + 0x7fffu + ((x.u>>16)&1u); return (u16)(r>>16); }
DEV float sigm(float x){ return 1.f/(1.f + __expf(-x)); }

// coherence-point (L2-bypassing) accessors: RELAXED atomics at agent scope
DEV u32  aL(const u32* p){ return __hip_atomic_load(p, __ATOMIC_RELAXED, __HIP_MEMORY_SCOPE_AGENT); }
DEV void aS(u32* p, u32 v){ __hip_atomic_store(p, v, __ATOMIC_RELAXED, __HIP_MEMORY_SCOPE_AGENT); }
DEV float aLf(const float* p){ return __hip_atomic_load(p, __ATOMIC_RELAXED, __HIP_MEMORY_SCOPE_AGENT); }
DEV void aSf(float* p, float v){ __hip_atomic_store(p, v, __ATOMIC_RELAXED, __HIP_MEMORY_SCOPE_AGENT); }

// B=64, P=196, D=2048, E=512, H=512, A=512, V=32000, S=22, T=20

enum { EPI_F32=0, EPI_BF16=1, EPI_H0C0=2, EPI_PREDS=3 };

struct EpiParams {
  float* out0; long ldo;
  u16* outb;
  const float* bias0;
  const int* declen;
  float* c; u16* xh;
  const int* revt; const int* revb;
};

// ---------- GEMM core: C[M][N] = A[M][K](bf16) * B[N][K](bf16)^T ----------
template<int BM, int BN, int EPI>
DEV void gemm_core(const u16* __restrict__ A, long lda,
                   const u16* __restrict__ B, long ldb,
                   int K, EpiParams& ep, long arow0, long brow0,
                   char* smem, int tid)
{
  constexpr int MF = BM/64;
  constexpr int NF = BN/16;
  constexpr int CHA = BM*8, CH = CHA + BN*8;
  constexpr int NST = CH/256;
  const int w = tid>>6, lane = tid&63;

  const u16* gsrc[NST]; int ldst[NST];
  #pragma unroll
  for (int i=0;i<NST;++i){
    int c = i*256 + tid;
    if (i*256 < CHA){
      int row = c>>3, k16 = c&7;
      gsrc[i] = A + (arow0+row)*lda + k16*8;
      ldst[i] = row*128 + ((k16*16) ^ ((row&7)<<4));
    } else {
      int cb = c - CHA; int row = cb>>3, k16 = cb&7;
      gsrc[i] = B + (brow0+row)*ldb + k16*8;
      ldst[i] = BM*128 + row*128 + ((k16*16) ^ ((row&7)<<4));
    }
  }

  f32x4 acc[MF][NF];
  #pragma unroll
  for (int i=0;i<MF;++i)
    #pragma unroll
    for (int j=0;j<NF;++j) acc[i][j] = (f32x4){0.f,0.f,0.f,0.f};

  const int KT = K >> 6;
  s16x8 st[NST];
  #pragma unroll
  for (int i=0;i<NST;++i) st[i] = *(const s16x8*)(gsrc[i]);

  char* Al = smem;
  for (int kk=0; kk<KT; ++kk){
    #pragma unroll
    for (int i=0;i<NST;++i) *(s16x8*)(smem + ldst[i]) = st[i];
    __syncthreads();
    if (kk+1 < KT){
      long kb = (long)(kk+1)*64;
      #pragma unroll
      for (int i=0;i<NST;++i) st[i] = *(const s16x8*)(gsrc[i] + kb);
    }
    #pragma unroll
    for (int ks = 0; ks < 2; ++ks) {
      s16x8 af[MF], bfr[NF];
      const int kboff = ks*64 + ((lane>>4)<<4);
      #pragma unroll
      for (int mf=0; mf<MF; ++mf) {
        int r = w*(16*MF) + mf*16 + (lane&15);
        af[mf] = *(const s16x8*)(Al + r*128 + (kboff ^ ((r&7)<<4)));
      }
      #pragma unroll
      for (int nf=0; nf<NF; ++nf) {
        int r = nf*16 + (lane&15);
        bfr[nf] = *(const s16x8*)(Al + BM*128 + r*128 + (kboff ^ ((r&7)<<4)));
      }
      #pragma unroll
      for (int mf=0; mf<MF; ++mf)
        #pragma unroll
        for (int nf=0; nf<NF; ++nf)
          acc[mf][nf] = __builtin_amdgcn_mfma_f32_16x16x32_bf16(bfr[nf], af[mf], acc[mf][nf], 0,0,0);
    }
    __syncthreads();
  }

  #pragma unroll
  for (int mf=0; mf<MF; ++mf)
    #pragma unroll
    for (int nf=0; nf<NF; ++nf){
      long m = arow0 + w*(16*MF) + mf*16 + (lane&15);
      long n0 = brow0 + nf*16 + ((lane>>4)<<2);
      f32x4 bv = *(const f32x4*)&ep.bias0[n0];
      f32x4 v = acc[mf][nf] + bv;
      if constexpr (EPI == EPI_F32) {
        *(f32x4*)&ep.out0[m*ep.ldo + n0] = v;
      } else if constexpr (EPI == EPI_BF16) {
        u16 o[4];
        #pragma unroll
        for (int r=0;r<4;++r) o[r] = f2bf(v[r]);
        *(s16x4*)&ep.outb[m*ep.ldo + n0] = *(s16x4*)o;
      } else if constexpr (EPI == EPI_H0C0) {
        if (n0 < 512){
          u16 o[4];
          #pragma unroll
          for (int r=0;r<4;++r) o[r] = f2bf(v[r]);
          *(s16x4*)&ep.xh[m*2560 + 2048 + n0] = *(s16x4*)o;
        } else {
          *(f32x4*)&ep.c[m*512 + (n0-512)] = v;
        }
      } else { // EPI_PREDS: packed rows; scatter via revt/revb, pads skipped
        int tt = ep.revt[m];
        if (tt >= 0){
          int b = ep.revb[m];
          *(f32x4*)&ep.out0[(long)b*640000 + (long)tt*32000 + n0] = v;
        }
      }
    }
}

// ---------- preds GEMM kernel (XCD-chunked swizzle) ----------
template<int BM, int BN, int EPI, int SWZM>
__global__ __launch_bounds__(256) void gemm_bt(
    const u16* __restrict__ A, long lda,
    const u16* __restrict__ B, long ldb,
    int K, EpiParams ep)
{
  __shared__ char smem[(BM+BN)*128];
  int id = blockIdx.x, tot = gridDim.x;
  int q = tot>>3, r = tot&7, xcd = id&7, idx = id>>3;
  int cid = (xcd<r) ? xcd*(q+1)+idx : r*(q+1)+(xcd-r)*q+idx;
  long arow0 = (long)(cid % SWZM)*BM, brow0 = (long)(cid / SWZM)*BN;
  gemm_core<BM,BN,EPI>(A, lda, B, ldb, K, ep, arow0, brow0, smem, threadIdx.x);
}

// ---------- merged setup GEMMs: h0c0(16) + att1(392) + gst(320) ----------
__global__ __launch_bounds__(256) void setup_gemms(
    const u16* meanb, const u16* whc,
    const u16* enc, const u16* wet,
    const u16* embb, const u16* wihe,
    u16* xh20, float* cbuf, const float* bhc,
    u16* att1, const float* be,
    float* gst, const float* bstat)
{
  __shared__ char smem[32768];
  const int blk = blockIdx.x, tid = threadIdx.x;
  if (blk < 16){
    EpiParams ep{}; ep.bias0 = bhc; ep.xh = xh20; ep.c = cbuf;
    gemm_core<64,64,EPI_H0C0>(meanb, 2048, whc, 2048, 2048, ep, 0, (long)blk*64, smem, tid);
  } else if (blk < 408){
    int rel = blk - 16;
    EpiParams ep{}; ep.outb = att1; ep.ldo = 512; ep.bias0 = be;
    gemm_core<128,128,EPI_BF16>(enc, 2048, wet, 2048, 2048, ep,
                                (long)(rel % 98)*128, (long)(rel / 98)*128, smem, tid);
  } else {
    int rel = blk - 408;
    EpiParams ep{}; ep.out0 = gst; ep.ldo = 2048; ep.bias0 = bstat;
    gemm_core<128,64,EPI_F32>(embb, 512, wihe, 512, 512, ep,
                              (long)(rel / 32)*128, (long)(rel % 32)*64, smem, tid);
  }
}

// ---------- fence-free grid barrier (256 blocks) ----------
DEV void gsync(u32* flags, u32* epochw, u32 ep, int blk, int tid){
  __syncthreads();
  if (blk == 0){
    if (tid == 0) aS(flags, ep);
    if (tid < 256){
      while (aL(flags + tid*16) < ep) __builtin_amdgcn_s_sleep(2);
    }
    __syncthreads();
    if (tid == 0) aS(epochw, ep);
  } else {
    if (tid == 0){
      aS(flags + blk*16, ep);
      while (aL(epochw) < ep) __builtin_amdgcn_s_sleep(4);
    }
    __syncthreads();
  }
}

// ---------- 512-thread f32->bf16 transpose tile (64x64) ----------
DEV void tpose512(const float* __restrict__ in, u16* __restrict__ out,
                  int R, int C, int rel, int gx, float (*t)[65], int tid)
{
  const int bx = (rel % gx)*64, by = (rel / gx)*64;
  const int tx = tid & 63, ty = tid >> 6;   // ty in [0,8)
  #pragma unroll
  for (int i=0;i<8;++i){ int r = i*8+ty; t[r][tx] = in[(long)(by+r)*C + bx+tx]; }
  __syncthreads();
  #pragma unroll
  for (int i=0;i<8;++i){ int cc = i*8+ty; out[(long)(bx+cc)*R + by+tx] = f2bf(t[tx][cc]); }
  __syncthreads();
}

// ---------- fused 20-step decoder loop (cooperative, 256 blocks x 512 thr) ----------
// R11 step structure; idle P1 blocks transpose Wout tiles in barrier slack;
// hall written PACKED (row = pref[t]+b for active (t,b) only).
struct FusedArgs {
  const u16* att1; const u16* enc;
  const u16* wmisc; const u16* wcat2;
  const float* gst; const float* wf; const float* bfp;
  const int* declen; const float* bmisc; const int* nact; const int* pref;
  const float* wout; u16* woutt;
  u16* xh20; float* y0p;
  float* part; int* cnt; float* c; u16* hall;
  float* alph; u32* bar;
};

__global__ __launch_bounds__(512) void steps_fused(FusedArgs fa)
{
  __shared__ char smem[61440];
  __shared__ float wred[8];
  __shared__ int lastf;
  const int blk = blockIdx.x, tid = threadIdx.x;
  const int w = tid>>6, lane = tid&63;
  const int mstrip = w>>1, nhalf = w&1;
  u32* flags = fa.bar;
  u32* epochw = fa.bar + 4096;
  u32 ep = 0;

  for (int t=0; t<20; ++t){
    u16* cur = fa.xh20 + (long)t*163840;
    u16* nxt = cur + 163840;
    u32* cur32 = (u32*)cur;
    u32* nxt32 = (u32*)nxt;

    // ---- P1: y0 = h @ [Wbeta^T|Wd^T] : 80 blocks ; others: Wout transpose ----
    if (blk < 80){
      const int brow0 = blk*32;
      f32x4 acc = {0,0,0,0};
      #pragma unroll
      for (int r=0; r<2; ++r){
        u32 sa[16];
        #pragma unroll
        for (int i=0;i<16;++i){
          int c = i*512 + tid;
          int row = c>>7, kp = c&127;
          sa[i] = *(const u32*)(cur32 + (long)row*1280 + 1024 + r*128 + kp);  // cached
        }
        s16x8 sb[2];
        #pragma unroll
        for (int i=0;i<2;++i){
          int c = i*512 + tid;
          int row = c>>5, k16 = c&31;
          sb[i] = *(const s16x8*)(fa.wmisc + (long)(brow0+row)*512 + r*256 + k16*8);
        }
        #pragma unroll
        for (int i=0;i<16;++i){
          int c = i*512 + tid;
          int row = c>>7, kp = c&127;
          *(u32*)(smem + row*512 + ((kp*4) ^ ((row&7)<<4))) = sa[i];
        }
        #pragma unroll
        for (int i=0;i<2;++i){
          int c = i*512 + tid;
          int row = c>>5, k16 = c&31;
          *(s16x8*)(smem + 32768 + row*512 + ((k16*16) ^ ((row&7)<<4))) = sb[i];
        }
        __syncthreads();
        #pragma unroll
        for (int ks=0; ks<8; ++ks){
          int kboff = ks*64 + ((lane>>4)<<4);
          int ra = mstrip*16 + (lane&15);
          s16x8 af = *(const s16x8*)(smem + ra*512 + (kboff ^ ((ra&7)<<4)));
          int rb = nhalf*16 + (lane&15);
          s16x8 bf = *(const s16x8*)(smem + 32768 + rb*512 + (kboff ^ ((rb&7)<<4)));
          acc = __builtin_amdgcn_mfma_f32_16x16x32_bf16(bf, af, acc, 0,0,0);
        }
        __syncthreads();
      }
      int m = mstrip*16 + (lane&15);
      int n0 = brow0 + nhalf*16 + ((lane>>4)<<2);
      #pragma unroll
      for (int j=0;j<4;++j)
        aSf(fa.y0p + (long)m*2560 + n0 + j, acc[j] + fa.bmisc[n0+j]);
    } else {
      // opportunistic Wout transpose (4000 tiles of 64x64; gx=500)
      float (*tls)[65] = (float(*)[65])smem;
      int base = t*352 + (blk-80)*2;
      #pragma unroll
      for (int k2=0;k2<2;++k2){
        int rel = base + k2;
        if (rel < 4000) tpose512(fa.wout, fa.woutt, 512, 32000, rel, 500, tls, tid);
      }
    }
    gsync(flags, epochw, ++ep, blk, tid);

    // ---- P23: b = blk&63 (XCD-consistent), s = blk>>6 ; pruned by nact[t] ----
    {
      const int b = blk & 63, s = blk >> 6;
      const int na = fa.nact[t];
      if (b >= na){
        if (s == 0){
          for (int i=tid; i<196; i+=512)
            fa.alph[((long)b*20 + t)*196 + i] = 0.f;
        }
      } else {
      float* att2p = (float*)smem;           // 8*72
      float* wfp   = att2p + 576;            // 8*72
      float* alps  = wfp + 576;              // 208
      float* awe_p = alps + 208;             // 8*512
      {
        int kg0 = tid>>6, j = tid&63;
        att2p[kg0*72 + j] = aLf(fa.y0p + (long)b*2560 + 2048 + tid);
        wfp[kg0*72 + j]   = fa.wf[tid];
      }
      __syncthreads();
      const float bfv = fa.bfp[0];
      const int pg = lane>>3, kg = lane&7;
      #pragma unroll
      for (int pass=0; pass<4; ++pass){
        int p = pass*64 + w*8 + pg;
        if (p < 196){
          const u16* ap = fa.att1 + (((long)(b*196 + p))<<9) + kg*64;
          float sa = 0.f;
          #pragma unroll
          for (int i=0;i<8;++i){
            s16x8 v = *(const s16x8*)(ap + i*8);
            #pragma unroll
            for (int q=0;q<8;++q){
              float x = bf2f((u16)v[q]) + att2p[kg*72 + i*8 + q];
              x = fmaxf(x, 0.f);
              sa += x * wfp[kg*72 + i*8 + q];
            }
          }
          sa += __shfl_xor(sa, 1);
          sa += __shfl_xor(sa, 2);
          sa += __shfl_xor(sa, 4);
          if (kg == 0) alps[p] = sa + bfv;
        }
      }
      __syncthreads();
      float v = (tid < 196) ? alps[tid] : -3.4e38f;
      float m8 = v;
      #pragma unroll
      for (int off=32; off; off>>=1) m8 = fmaxf(m8, __shfl_xor(m8, off));
      if (lane == 0) wred[w] = m8;
      __syncthreads();
      float mx = wred[0];
      #pragma unroll
      for (int i=1;i<8;++i) mx = fmaxf(mx, wred[i]);
      float e = (tid < 196) ? __expf(v - mx) : 0.f;
      float s8 = e;
      #pragma unroll
      for (int off=32; off; off>>=1) s8 += __shfl_xor(s8, off);
      __syncthreads();
      if (lane == 0) wred[w] = s8;
      __syncthreads();
      float den = wred[0]+wred[1]+wred[2]+wred[3]+wred[4]+wred[5]+wred[6]+wred[7];
      float inv = 1.f/den;
      if (tid < 196){
        float a = e*inv;
        alps[tid] = a;
        if (s==0) fa.alph[((long)b*20 + t)*196 + tid] = (fa.declen[b] > t) ? a : 0.f;
      }
      __syncthreads();
      // awe: 4-deep pipelined, NON-TEMPORAL enc loads
      const int d0 = s*512 + lane*8;
      const u16* ebase = fa.enc + (((long)b*196)<<11) + d0;
      float a8[8] = {0,0,0,0,0,0,0,0};
      int p = w;
      for (; p+24 < 196; p += 32){
        s16x8 e0 = __builtin_nontemporal_load((const s16x8*)(ebase + ((long)p<<11)));
        s16x8 e1 = __builtin_nontemporal_load((const s16x8*)(ebase + ((long)(p+8)<<11)));
        s16x8 e2 = __builtin_nontemporal_load((const s16x8*)(ebase + ((long)(p+16)<<11)));
        s16x8 e3 = __builtin_nontemporal_load((const s16x8*)(ebase + ((long)(p+24)<<11)));
        float a0 = alps[p], a1 = alps[p+8], a2 = alps[p+16], a3 = alps[p+24];
        #pragma unroll
        for (int q=0;q<8;++q) a8[q] += a0*bf2f((u16)e0[q]);
        #pragma unroll
        for (int q=0;q<8;++q) a8[q] += a1*bf2f((u16)e1[q]);
        #pragma unroll
        for (int q=0;q<8;++q) a8[q] += a2*bf2f((u16)e2[q]);
        #pragma unroll
        for (int q=0;q<8;++q) a8[q] += a3*bf2f((u16)e3[q]);
      }
      for (; p < 196; p += 8){
        s16x8 ev = __builtin_nontemporal_load((const s16x8*)(ebase + ((long)p<<11)));
        float a = alps[p];
        #pragma unroll
        for (int q=0;q<8;++q) a8[q] += a*bf2f((u16)ev[q]);
      }
      *(f32x4*)&awe_p[w*512 + lane*8]     = (f32x4){a8[0],a8[1],a8[2],a8[3]};
      *(f32x4*)&awe_p[w*512 + lane*8 + 4] = (f32x4){a8[4],a8[5],a8[6],a8[7]};
      __syncthreads();
      if (tid < 256){
        int c0 = 2*tid;
        float s0 = 0.f, s1 = 0.f;
        #pragma unroll
        for (int g=0; g<8; ++g){ s0 += awe_p[g*512 + c0]; s1 += awe_p[g*512 + c0 + 1]; }
        float g0 = sigm(aLf(fa.y0p + (long)b*2560 + s*512 + c0));
        float g1 = sigm(aLf(fa.y0p + (long)b*2560 + s*512 + c0 + 1));
        u32 pk = (u32)f2bf(g0*s0) | ((u32)f2bf(g1*s1) << 16);
        aS(cur32 + (long)b*1280 + s*256 + tid, pk);
      }
      __syncthreads();
      }
    }
    gsync(flags, epochw, ++ep, blk, tid);

    // ---- P4: ntile = blk&63 (XCD-consistent), split = blk>>6 ; cached x|h reads ----
    {
      const int ntile = blk & 63, split = blk >> 6;
      f32x4 acc = {0,0,0,0};
      #pragma unroll
      for (int r=0; r<2; ++r){
        const int kbw = split*640 + r*320;     // u16 col base
        const int kbd = split*320 + r*160;     // u32 col base
        u32 sa[20];
        #pragma unroll
        for (int i=0;i<20;++i){
          int c = i*512 + tid;
          int row = c/160, kp = c%160;
          sa[i] = *(const u32*)(cur32 + (long)row*1280 + kbd + kp);   // cached
        }
        s16x8 sb[3];
        #pragma unroll
        for (int i=0;i<3;++i){
          int c = i*512 + tid;
          if (c < 1280){
            int row = c/40, k16 = c%40;
            sb[i] = *(const s16x8*)(fa.wcat2 + (long)(ntile*32+row)*2560 + kbw + k16*8);
          }
        }
        #pragma unroll
        for (int i=0;i<20;++i){
          int c = i*512 + tid;
          int row = c/160, kp = c%160;
          *(u32*)(smem + row*640 + ((kp*4) ^ ((row&7)<<4))) = sa[i];
        }
        #pragma unroll
        for (int i=0;i<3;++i){
          int c = i*512 + tid;
          if (c < 1280){
            int row = c/40, k16 = c%40;
            *(s16x8*)(smem + 40960 + row*640 + ((k16*16) ^ ((row&7)<<4))) = sb[i];
          }
        }
        __syncthreads();
        #pragma unroll
        for (int ks=0; ks<10; ++ks){
          int kboff = ks*64 + ((lane>>4)<<4);
          int ra = mstrip*16 + (lane&15);
          s16x8 af = *(const s16x8*)(smem + ra*640 + (kboff ^ ((ra&7)<<4)));
          int rb = nhalf*16 + (lane&15);
          s16x8 bf = *(const s16x8*)(smem + 40960 + rb*640 + (kboff ^ ((rb&7)<<4)));
          acc = __builtin_amdgcn_mfma_f32_16x16x32_bf16(bf, af, acc, 0,0,0);
        }
        __syncthreads();
      }
      {
        float* PS = fa.part + (long)split*(64*2048);
        int m = mstrip*16 + (lane&15);
        int n0 = ntile*32 + nhalf*16 + ((lane>>4)<<2);
        #pragma unroll
        for (int j=0;j<4;++j) aSf(PS + (long)m*2048 + n0 + j, acc[j]);
      }
      __syncthreads();   // drains vmcnt per wave -> part stores globally visible
      if (tid==0){
        int v = __hip_atomic_fetch_add(fa.cnt + t*64 + ntile, 1,
                                       __ATOMIC_RELAXED, __HIP_MEMORY_SCOPE_AGENT);
        lastf = (v == 3);
      }
      __syncthreads();
      if (lastf && tid < 256){
        int b = tid>>2, jp = tid&3;
        u16 h2[2];
        #pragma unroll
        for (int jj=0; jj<2; ++jj){
          int jl = jp*2 + jj;
          int j = ntile*8 + jl;
          float g4[4];
          #pragma unroll
          for (int gi=0; gi<4; ++gi){
            long n = (long)ntile*32 + jl*4 + gi;
            float sg = fa.gst[((long)t*64 + b)*2048 + n];
            #pragma unroll
            for (int sp=0; sp<4; ++sp)
              sg += aLf(fa.part + (long)sp*(64*2048) + (long)b*2048 + n);
            g4[gi] = sg;
          }
          float cc = aLf(fa.c + b*512 + j);
          float cn = sigm(g4[1])*cc + sigm(g4[0])*tanhf(g4[2]);
          float hn = sigm(g4[3])*tanhf(cn);
          aSf(fa.c + b*512 + j, cn);
          h2[jj] = f2bf(hn);
        }
        u32 pk = (u32)h2[0] | ((u32)h2[1] << 16);
        aS(nxt32 + (long)b*1280 + 1024 + ntile*4 + jp, pk);
        if (b < fa.nact[t]){
          long prow = fa.pref[t] + b;
          *(u32*)&fa.hall[prow*512 + ntile*8 + jp*2] = pk;
        }
      }
    }
    if (t < 19) gsync(flags, epochw, ++ep, blk, tid);
  }
}

// ---------- sort + small outputs + counter/barrier/nact/pack-map init ----------
__global__ void sort_k(const int* __restrict__ cl, const int* __restrict__ captions,
                       int* __restrict__ sidx, int* __restrict__ declen,
                       float* __restrict__ outCaps, float* __restrict__ outLens,
                       float* __restrict__ outSidx, int* __restrict__ cnt,
                       u32* __restrict__ bar, int* __restrict__ nact,
                       int* __restrict__ pref, int* __restrict__ revt,
                       int* __restrict__ revb)
{
  __shared__ int s_idx[64];
  __shared__ int s_dl[64];
  __shared__ int s_na[20];
  int i = threadIdx.x;
  int li = cl[i];
  int rank = 0;
  for (int j=0;j<64;++j){ int lj = cl[j]; rank += (lj>li) || (lj==li && j<i); }
  s_idx[rank] = i;
  __syncthreads();
  int src = s_idx[i];
  sidx[i] = src;
  int L = cl[src];
  declen[i] = L - 1;
  s_dl[i] = L - 1;
  outLens[i] = (float)L;
  outSidx[i] = (float)src;
  for (int s=0;s<22;++s) outCaps[i*22+s] = (float)captions[s*64 + src];
  for (int s=0;s<20;++s) cnt[s*64 + i] = 0;
  for (int s=i; s<4160; s+=64) bar[s] = 0u;
  for (int r=i; r<1024; r+=64){ revt[r] = -1; revb[r] = 0; }
  __syncthreads();
  if (i < 20){
    int c = 0;
    for (int j=0;j<64;++j) c += (s_dl[j] > i);
    nact[i] = c;
    s_na[i] = c;
  }
  __syncthreads();
  if (i == 0){
    int acc = 0;
    for (int t=0;t<20;++t){ pref[t] = acc; acc += s_na[t]; }
  }
  __syncthreads();
  // pack maps: b=i
  {
    int acc = 0;
    for (int t=0;t<20;++t){
      if (i < s_na[t]){ revt[acc + i] = t; revb[acc + i] = i; }
      acc += s_na[t];
    }
  }
}

// ---------- merged setup (minus Wout transpose): 5014 blocks ----------
struct PrepArgs {
  const float* features; const int* captions; const int* sidx;
  const float* embW;
  const float* We; const float* Wbeta; const float* Wd;
  const float* Wh0; const float* Wc0;
  const float* Wih; const float* Whh;
  const float* bih; const float* bhh; const float* bbeta;
  const float* bd; const float* bh0; const float* bc0;
  u16* enc; u16* meanb; u16* embb;
  u16* wet; u16* wmisc; u16* whc; u16* wcat2; u16* wihe;
  float* bstat; float* bmisc; float* bhc;
};

DEV void tpose_tile(const float* __restrict__ in, u16* __restrict__ out,
                    int R, int C, int rel, int gx, float (*t)[65], int tid)
{
  const int bx = (rel % gx)*64, by = (rel / gx)*64;
  const int tx = tid & 63, ty = tid >> 6;
  #pragma unroll
  for (int i=0;i<16;++i){ int r = i*4+ty; t[r][tx] = in[(long)(by+r)*C + bx+tx]; }
  __syncthreads();
  #pragma unroll
  for (int i=0;i<16;++i){ int cc = i*4+ty; out[(long)(bx+cc)*R + by+tx] = f2bf(t[tx][cc]); }
}

__global__ __launch_bounds__(256) void mega_prep(PrepArgs pa)
{
  __shared__ float tls[64][65];
  __shared__ float red[4][256];
  const int blk = blockIdx.x, tid = threadIdx.x;

  if (blk < 512){
    int b = blk >> 3, oct = blk & 7;
    int lv = tid & 63, g = tid >> 6;
    int d0 = oct*256 + lv*4;
    const float* src = pa.features + (long)pa.sidx[b]*(196*2048) + d0;
    float acc[4] = {0.f,0.f,0.f,0.f};
    for (int p=g; p<196; p+=4){
      f32x4 v = *(const f32x4*)(src + (long)p*2048);
      u16 o[4];
      #pragma unroll
      for (int q=0;q<4;++q){ acc[q] += v[q]; o[q] = f2bf(v[q]); }
      *(s16x4*)(pa.enc + ((long)b*196 + p)*2048 + d0) = *(s16x4*)o;
    }
    #pragma unroll
    for (int q=0;q<4;++q) red[g][lv*4+q] = acc[q];
    __syncthreads();
    if (tid < 64){
      u16 mo[4];
      #pragma unroll
      for (int q=0;q<4;++q){
        float s = red[0][tid*4+q] + red[1][tid*4+q] + red[2][tid*4+q] + red[3][tid*4+q];
        mo[q] = f2bf(s*(1.f/196.f));
      }
      *(s16x4*)(pa.meanb + b*2048 + oct*256 + tid*4) = *(s16x4*)mo;
    }
  } else if (blk < 832){
    int idx = (blk-512)*256 + tid;
    int row = idx >> 6; int e0 = (idx & 63)*8;
    int t = row >> 6, b = row & 63;
    int tok = pa.captions[t*64 + pa.sidx[b]];
    const float* s = pa.embW + (long)tok*512 + e0;
    f32x4 v0 = *(const f32x4*)s, v1 = *(const f32x4*)(s+4);
    u16 o[8];
    #pragma unroll
    for (int q=0;q<4;++q){ o[q] = f2bf(v0[q]); o[4+q] = f2bf(v1[q]); }
    *(s16x8*)(pa.embb + (long)row*512 + e0) = *(s16x8*)o;
  } else if (blk < 1088){
    tpose_tile(pa.We, pa.wet, 2048, 512, blk-832, 8, tls, tid);
  } else if (blk < 1344){
    tpose_tile(pa.Wbeta, pa.wmisc, 512, 2048, blk-1088, 32, tls, tid);
  } else if (blk < 1408){
    tpose_tile(pa.Wd, pa.wmisc + 2048*512, 512, 512, blk-1344, 8, tls, tid);
  } else if (blk < 1664){
    tpose_tile(pa.Wh0, pa.whc, 2048, 512, blk-1408, 8, tls, tid);
  } else if (blk < 1920){
    tpose_tile(pa.Wc0, pa.whc + 512*2048, 2048, 512, blk-1664, 8, tls, tid);
  } else if (blk < 4480){
    long idx = (long)(blk-1920)*256 + tid;
    int r = (int)(idx / 320);
    int kc = (int)(idx % 320) * 8;
    int j = r>>2, g = r&3;
    int orow = g*512 + j;
    const float* s = (kc < 2048) ? (pa.Wih + (long)orow*2560 + 512 + kc)
                                 : (pa.Whh + (long)orow*512 + (kc - 2048));
    f32x4 v0 = *(const f32x4*)s, v1 = *(const f32x4*)(s+4);
    u16 o[8];
    #pragma unroll
    for (int q=0;q<4;++q){ o[q] = f2bf(v0[q]); o[4+q] = f2bf(v1[q]); }
    *(s16x8*)(pa.wcat2 + (long)r*2560 + kc) = *(s16x8*)o;
  } else if (blk < 4992){
    int idx = (blk-4480)*256 + tid;
    int r = idx >> 6; int kc = (idx & 63)*8;
    int j = r>>2, g = r&3;
    const float* s = pa.Wih + (long)(g*512+j)*2560 + kc;
    f32x4 v0 = *(const f32x4*)s, v1 = *(const f32x4*)(s+4);
    u16 o[8];
    #pragma unroll
    for (int q=0;q<4;++q){ o[q] = f2bf(v0[q]); o[4+q] = f2bf(v1[q]); }
    *(s16x8*)(pa.wihe + (long)r*512 + kc) = *(s16x8*)o;
  } else {
    int idx = (blk-4992)*256 + tid;
    if (idx < 2048){ int j = idx>>2, g = idx&3; pa.bstat[idx] = pa.bih[g*512+j] + pa.bhh[g*512+j]; }
    else if (idx < 4608){ int k = idx-2048; pa.bmisc[k] = (k<2048) ? pa.bbeta[k] : pa.bd[k-2048]; }
    else if (idx < 5632){ int k = idx-4608; pa.bhc[k] = (k<512) ? pa.bh0[k] : pa.bc0[k-512]; }
  }
}

// ---------- workspace layout (bytes) ----------
static constexpr long OFF_ENC   = 0;                 // 64*196*2048 bf16
static constexpr long OFF_ATT1  = 51380224;          // 12544*512 bf16
static constexpr long OFF_WOUTT = 64225280;          // 32000*512 bf16
static constexpr long OFF_WET   = 96993280;          // 512*2048 bf16
static constexpr long OFF_WMISC = 99090432;          // 2560*512 bf16 (Wbeta^T ; Wd^T)
static constexpr long OFF_WHC   = 101711872;         // 1024*2048 bf16 -- REUSED as PART
static constexpr long OFF_WCAT2 = 105906176;         // 2048*2560 bf16 (perm [Wih_a|Whh])
static constexpr long OFF_WIHE  = 116391936;         // 2048*512 bf16 (perm Wih_e)
static constexpr long OFF_EMBB  = 118489088;         // 1280*512 bf16
static constexpr long OFF_GST   = 119799808;         // 1280*2048 f32
static constexpr long OFF_HALL  = 130285568;         // 1280*512 bf16 (packed rows used)
static constexpr long OFF_MEANB = 131596288;         // 64*2048 bf16
static constexpr long OFF_C     = 132513792;         // 64*512 f32
static constexpr long OFF_Y0P   = 132644864;         // 64*2560 f32
static constexpr long OFF_BSTAT = 133955584;         // 2048 f32
static constexpr long OFF_BMISC = 133963776;         // 2560 f32
static constexpr long OFF_BHC   = 133974016;         // 1024 f32
static constexpr long OFF_SIDX  = 133978112;         // 64 int
static constexpr long OFF_DECL  = 133978368;         // 64 int
static constexpr long OFF_CNT   = 133978624;         // 20*64 int
static constexpr long OFF_BAR   = 133983744;         // 4160 u32
static constexpr long OFF_NACT  = 134000384;         // 20 int
static constexpr long OFF_PREF  = 134000512;         // 20 int
static constexpr long OFF_REVT  = 134000768;         // 1024 int
static constexpr long OFF_REVB  = 134004864;         // 1024 int
static constexpr long OFF_XH20  = 134017024;         // 21 * 64*2560 bf16 (6.88 MB)
static constexpr long OFF_PART  = OFF_WHC;           // 4*64*2048 f32 (2 MB, after setup)

extern "C" void kernel_launch(void* const* d_in, const int* in_sizes, int n_in,
                              void* d_out, int out_size, void* d_ws, size_t ws_size,
                              hipStream_t stream)
{
  (void)in_sizes; (void)n_in; (void)out_size; (void)ws_size;
  const float* features = (const float*)d_in[0];
  const int*   captions = (const int*)d_in[1];
  const int*   caplen   = (const int*)d_in[2];
  const float* embW     = (const float*)d_in[3];
  const float* We       = (const float*)d_in[4];
  const float* be       = (const float*)d_in[5];
  const float* Wd       = (const float*)d_in[6];
  const float* bd       = (const float*)d_in[7];
  const float* wf       = (const float*)d_in[8];
  const float* bfp      = (const float*)d_in[9];
  const float* Wih      = (const float*)d_in[10];
  const float* Whh      = (const float*)d_in[11];
  const float* bih      = (const float*)d_in[12];
  const float* bhh      = (const float*)d_in[13];
  const float* Wh0      = (const float*)d_in[14];
  const float* bh0      = (const float*)d_in[15];
  const float* Wc0      = (const float*)d_in[16];
  const float* bc0      = (const float*)d_in[17];
  const float* Wbeta    = (const float*)d_in[18];
  const float* bbeta    = (const float*)d_in[19];
  const float* Wout     = (const float*)d_in[20];
  const float* bout     = (const float*)d_in[21];

  char* ws = (char*)d_ws;
  u16*   enc   = (u16*)(ws + OFF_ENC);
  u16*   att1  = (u16*)(ws + OFF_ATT1);
  u16*   woutt = (u16*)(ws + OFF_WOUTT);
  u16*   wet   = (u16*)(ws + OFF_WET);
  u16*   wmisc = (u16*)(ws + OFF_WMISC);
  u16*   whc   = (u16*)(ws + OFF_WHC);
  u16*   wcat2 = (u16*)(ws + OFF_WCAT2);
  u16*   wihe  = (u16*)(ws + OFF_WIHE);
  u16*   embb  = (u16*)(ws + OFF_EMBB);
  float* gst   = (float*)(ws + OFF_GST);
  u16*   hall  = (u16*)(ws + OFF_HALL);
  u16*   meanb = (u16*)(ws + OFF_MEANB);
  float* cbuf  = (float*)(ws + OFF_C);
  float* y0p   = (float*)(ws + OFF_Y0P);
  float* bstat = (float*)(ws + OFF_BSTAT);
  float* bmisc = (float*)(ws + OFF_BMISC);
  float* bhc   = (float*)(ws + OFF_BHC);
  int*   sidx  = (int*)(ws + OFF_SIDX);
  int*   declen= (int*)(ws + OFF_DECL);
  int*   cnt   = (int*)(ws + OFF_CNT);
  u32*   bar   = (u32*)(ws + OFF_BAR);
  int*   nact  = (int*)(ws + OFF_NACT);
  int*   pref  = (int*)(ws + OFF_PREF);
  int*   revt  = (int*)(ws + OFF_REVT);
  int*   revb  = (int*)(ws + OFF_REVB);
  u16*   xh20  = (u16*)(ws + OFF_XH20);
  float* part  = (float*)(ws + OFF_PART);

  float* outP    = (float*)d_out;            // [64][20][32000]
  float* outCaps = outP + 40960000;          // [64][22]
  float* outLens = outCaps + 1408;           // [64]
  float* outAlph = outLens + 64;             // [64][20][196]
  float* outSidx = outAlph + 250880;         // [64]

  // ---- setup: sort(+pack maps), merged prep, merged GEMMs ----
  sort_k<<<1,64,0,stream>>>(caplen, captions, sidx, declen, outCaps, outLens, outSidx,
                            cnt, bar, nact, pref, revt, revb);
  {
    PrepArgs pa;
    pa.features = features; pa.captions = captions; pa.sidx = sidx;
    pa.embW = embW;
    pa.We = We; pa.Wbeta = Wbeta; pa.Wd = Wd; pa.Wh0 = Wh0; pa.Wc0 = Wc0;
    pa.Wih = Wih; pa.Whh = Whh;
    pa.bih = bih; pa.bhh = bhh; pa.bbeta = bbeta; pa.bd = bd; pa.bh0 = bh0; pa.bc0 = bc0;
    pa.enc = enc; pa.meanb = meanb; pa.embb = embb;
    pa.wet = wet; pa.wmisc = wmisc; pa.whc = whc;
    pa.wcat2 = wcat2; pa.wihe = wihe;
    pa.bstat = bstat; pa.bmisc = bmisc; pa.bhc = bhc;
    mega_prep<<<5014,256,0,stream>>>(pa);
  }
  setup_gemms<<<728,256,0,stream>>>(meanb, whc, enc, wet, embb, wihe,
                                    xh20, cbuf, bhc, att1, be, gst, bstat);

  // ---- 20 fused sequential steps (cooperative, 256 blocks x 512 thr) ----
  {
    FusedArgs fa;
    fa.att1 = att1; fa.enc = enc; fa.wmisc = wmisc; fa.wcat2 = wcat2;
    fa.gst = gst; fa.wf = wf; fa.bfp = bfp; fa.declen = declen; fa.bmisc = bmisc;
    fa.nact = nact; fa.pref = pref;
    fa.wout = Wout; fa.woutt = woutt;
    fa.xh20 = xh20; fa.y0p = y0p;
    fa.part = part; fa.cnt = cnt; fa.c = cbuf; fa.hall = hall;
    fa.alph = outAlph; fa.bar = bar;
    void* kargs[1] = { &fa };
    hipLaunchCooperativeKernel((const void*)steps_fused, dim3(256), dim3(512),
                               kargs, 0, stream);
  }

  // ---- batched predictions on PACKED rows (8 m-tiles = 1024 rows), scatter ----
  { EpiParams ep{}; ep.out0 = outP; ep.bias0 = bout; ep.declen = declen;
    ep.revt = revt; ep.revb = revb;
    gemm_bt<128,128,EPI_PREDS,8><<<2000,256,0,stream>>>(hall, 512, woutt, 512, 512, ep); }
}